// Round 14
// baseline (1794.146 us; speedup 1.0000x reference)
//
#include <hip/hip_runtime.h>
#include <hip/hip_bf16.h>

__device__ __forceinline__ float tanh_fast(float x){
    float e = __expf(2.0f*x);
    return 1.0f - 2.0f/(e + 1.0f);
}

// 16 FMAs of one weight float4 against 4 per-electron scalars
#define FMA16(W_, A_, B_, C_, D_) do{                       \
    acc[0][0] += (A_)*(W_).x; acc[0][1] += (A_)*(W_).y;     \
    acc[0][2] += (A_)*(W_).z; acc[0][3] += (A_)*(W_).w;     \
    acc[1][0] += (B_)*(W_).x; acc[1][1] += (B_)*(W_).y;     \
    acc[1][2] += (B_)*(W_).z; acc[1][3] += (B_)*(W_).w;     \
    acc[2][0] += (C_)*(W_).x; acc[2][1] += (C_)*(W_).y;     \
    acc[2][2] += (C_)*(W_).z; acc[2][3] += (C_)*(W_).w;     \
    acc[3][0] += (D_)*(W_).x; acc[3][1] += (D_)*(W_).y;     \
    acc[3][2] += (D_)*(W_).z; acc[3][3] += (D_)*(W_).w;     \
}while(0)

// 4 consecutive K-rows of W (256-wide), activations given as float4 per electron
#define G4(Wb, R0, sA4, sB4, sC4, sD4) do{                                                        \
    float4 w_;                                                                                     \
    w_ = *(const float4*)((Wb) + (R0)*256 + n0);       FMA16(w_, (sA4).x,(sB4).x,(sC4).x,(sD4).x); \
    w_ = *(const float4*)((Wb) + ((R0)+1)*256 + n0);   FMA16(w_, (sA4).y,(sB4).y,(sC4).y,(sD4).y); \
    w_ = *(const float4*)((Wb) + ((R0)+2)*256 + n0);   FMA16(w_, (sA4).z,(sB4).z,(sC4).z,(sD4).z); \
    w_ = *(const float4*)((Wb) + ((R0)+3)*256 + n0);   FMA16(w_, (sA4).w,(sB4).w,(sC4).w,(sD4).w); \
}while(0)

// pair-stream residual update: px = tanh(px @ wp + b) + px   (all f32, registers)
// k-loop unroll capped at 4: limits in-flight LDS weight loads (round-8 spill fix)
__device__ __forceinline__ void pair_update(float (&px)[32], const float (*wp)[32], const float* bpb){
    float a2[32];
#pragma unroll
    for (int f=0;f<32;f++) a2[f] = bpb[f];
#pragma unroll 4
    for (int k=0;k<32;k++){
        float xk = px[k];
        const float4* wr = (const float4*)wp[k];
#pragma unroll
        for (int c=0;c<8;c++){
            float4 w = wr[c];
            a2[c*4+0] += xk*w.x; a2[c*4+1] += xk*w.y;
            a2[c*4+2] += xk*w.z; a2[c*4+3] += xk*w.w;
        }
    }
#pragma unroll
    for (int f=0;f<32;f++) px[f] = tanh_fast(a2[f]) + px[f];
}

// ---------------- prep: Wcu = Wu@Wwu, bcu = bu@Wwu+bwu; same for down spin ----
// ws layout (floats): [0,4096) Wcu  [4096,4112) bcu  [4112,8208) Wcd  [8208,8224) bcd
__global__ __launch_bounds__(512) void fermi_prep(
    const float* __restrict__ Wu, const float* __restrict__ bu,
    const float* __restrict__ Wd, const float* __restrict__ bd,
    const float* __restrict__ Wwu, const float* __restrict__ bwu,
    const float* __restrict__ Wwd, const float* __restrict__ bwd,
    float* __restrict__ ws)
{
    const int t = threadIdx.x;
    const int m = t & 255;
    const int half = t >> 8;
    const float* Wbig = half ? Wd : Wu;
    const float* Wsm  = half ? Wwd : Wwu;
    float acc[16];
#pragma unroll
    for (int k=0;k<16;k++) acc[k]=0.f;
    for (int h=0; h<128; h++){
        float wv = Wbig[m*128+h];
        const float4* wr = (const float4*)(Wsm + h*16);
        float4 a0=wr[0], a1=wr[1], a2=wr[2], a3=wr[3];
        acc[0]+=wv*a0.x; acc[1]+=wv*a0.y; acc[2]+=wv*a0.z; acc[3]+=wv*a0.w;
        acc[4]+=wv*a1.x; acc[5]+=wv*a1.y; acc[6]+=wv*a1.z; acc[7]+=wv*a1.w;
        acc[8]+=wv*a2.x; acc[9]+=wv*a2.y; acc[10]+=wv*a2.z; acc[11]+=wv*a2.w;
        acc[12]+=wv*a3.x; acc[13]+=wv*a3.y; acc[14]+=wv*a3.z; acc[15]+=wv*a3.w;
    }
    float* dst = ws + half*4112;
#pragma unroll
    for (int k=0;k<16;k++) dst[m*16+k]=acc[k];
    if (m < 16){
        const float* bbig = half ? bd : bu;
        float b2 = half ? bwd[m] : bwu[m];
        for (int h=0;h<128;h++) b2 += bbig[h]*Wsm[h*16+m];
        dst[4096+m] = b2;
    }
}

// ---------------- main: one walker per 512-thread block ----------------------
// waves_per_eu(2,4): min=2 keeps the allocator's 128-VGPR choice (cap 256);
// max=4 LIFTS the residency cap that (2,2) imposed — rounds 8-13 were pinned
// at 2 waves/EU by our own attribute (round-12's 2x78KB co-residency proves
// LDS fits 2 blocks; m69's 2048-VGPR/CU pool allows 16 waves at 128 VGPR).
// LDS 78KB -> 2 blocks/CU -> 16 waves/CU expected.
__global__ __launch_bounds__(512) __attribute__((amdgpu_waves_per_eu(2,4))) void fermi_main(
    const float* __restrict__ r,   const float* __restrict__ A,
    const float* __restrict__ Ws0, const float* __restrict__ bs0,
    const float* __restrict__ Wp0, const float* __restrict__ bp0,
    const float* __restrict__ Ws1, const float* __restrict__ bs1,
    const float* __restrict__ Wp1, const float* __restrict__ bp1,
    const float* __restrict__ Ws2, const float* __restrict__ bs2,
    const float* __restrict__ Wp2, const float* __restrict__ bp2,
    const float* __restrict__ Ws3, const float* __restrict__ bs3,
    const float* __restrict__ Wc,  float* __restrict__ out)
{
    __shared__ __align__(16) float sv[32][256];        // 32 KB single stream
    __shared__ __align__(16) float pmu[3][32][32];     // 12 KB pair means (u)
    __shared__ __align__(16) float pmd[3][32][32];     // 12 KB pair means (d)
    __shared__ float su[256], sd[256];
    __shared__ __align__(16) float cpart[2][256];
    __shared__ __align__(16) float csh[256];
    __shared__ __align__(16) float wp0s[4][32];
    __shared__ __align__(16) float wp1s[32][32];
    __shared__ __align__(16) float wp2s[32][32];
    __shared__ __align__(16) float bp0s[32], bp1s[32], bp2s[32];
    __shared__ float rs[32][3];
    __shared__ __align__(16) float s0[32][16];
    __shared__ float ralen[32][4];
    __shared__ float envs[32];
    __shared__ __align__(16) float pu0[32][4];
    __shared__ __align__(16) float pd0[32][4];
    __shared__ float su0[16], sd0[16];
    __shared__ float rbar[2][3];
    __shared__ float orb[2][16][17];
    __shared__ float red[2];

    const int t = threadIdx.x;
    const int b = blockIdx.x;

    const int cg = t & 63;       // column group: cols n0..n0+3
    const int jg = t >> 6;       // electron group: electrons j0..j0+3
    const int n0 = cg * 4;
    const int j0 = jg * 4;

    // ---- A1: load r, stage ALL pair weights/biases ----
    if (t < 96) rs[t/3][t%3] = r[(size_t)b*96 + t];
    if (t < 128) (&wp0s[0][0])[t] = Wp0[t];
    {
        float* w1 = &wp1s[0][0];
        w1[t]     = Wp1[t];
        w1[t+512] = Wp1[t+512];
        float* w2 = &wp2s[0][0];
        w2[t]     = Wp2[t];
        w2[t+512] = Wp2[t+512];
    }
    if (t >= 128 && t < 160) bp0s[t-128] = bp0[t-128];
    else if (t >= 160 && t < 192) bp1s[t-160] = bp1[t-160];
    else if (t >= 192 && t < 224) bp2s[t-192] = bp2[t-192];
    __syncthreads();

    // ---- A2: electron-atom features ----
    if (t < 128){
        int e = t >> 2, aa = t & 3;
        float dx = rs[e][0]-A[aa*3+0];
        float dy = rs[e][1]-A[aa*3+1];
        float dz = rs[e][2]-A[aa*3+2];
        float ln = sqrtf(dx*dx+dy*dy+dz*dz);
        s0[e][aa*4+0]=dx; s0[e][aa*4+1]=dy; s0[e][aa*4+2]=dz; s0[e][aa*4+3]=ln;
        ralen[e][aa]=ln;
    }
    __syncthreads();

    // ---- A3: env, su0/sd0, rbar ----
    if (t < 32){
        envs[t] = expf(-ralen[t][0])+expf(-ralen[t][1])+expf(-ralen[t][2])+expf(-ralen[t][3]);
    } else if (t < 48){
        int k = t-32; float s=0.f;
        for (int j=0;j<16;j++) s += s0[j][k];
        su0[k] = s*(1.f/16.f);
    } else if (t < 64){
        int k = t-48; float s=0.f;
        for (int j=16;j<32;j++) s += s0[j][k];
        sd0[k] = s*(1.f/16.f);
    } else if (t < 70){
        int q = t-64; int half=q/3, c=q%3; float s=0.f;
        for (int i=half*16;i<half*16+16;i++) s += rs[i][c];
        rbar[half][c] = s*(1.f/16.f);
    }
    __syncthreads();

    // ---- A4: pu0/pd0 + layer-0 shared GEMV ----
    if (t < 64){
        int j = t & 31, half = t >> 5;
        float* dst = half ? pd0[j] : pu0[j];
        dst[0] = rs[j][0]-rbar[half][0];
        dst[1] = rs[j][1]-rbar[half][1];
        dst[2] = rs[j][2]-rbar[half][2];
        float s=0.f; int base = half*16;
        for (int i=base;i<base+16;i++){
            if (i != j){
                float dx=rs[j][0]-rs[i][0];
                float dy=rs[j][1]-rs[i][1];
                float dz=rs[j][2]-rs[i][2];
                s += sqrtf(dx*dx+dy*dy+dz*dz);
            }
        }
        dst[3] = s*(1.f/16.f);
    }
    if (t >= 128 && t < 384){
        int n = t-128;
        float a0 = bs0[n];
        for (int k=0;k<16;k++){
            a0 += su0[k]*Ws0[k*256+n] + sd0[k]*Ws0[(16+k)*256+n];
        }
        csh[n] = a0;
    }
    __syncthreads();

    // ================= PAIR PHASE (2 sequential px[32] passes) =================
#pragma unroll 1
    for (int h=0; h<2; ++h){
        float px[32];
        float (*pm)[32][32] = h ? pmd : pmu;
        const int i1 = t & 15;
        const int jj = t >> 4;       // 0..31
        const int ii = i1 + h*16;
        {
            float dx = rs[jj][0]-rs[ii][0];
            float dy = rs[jj][1]-rs[ii][1];
            float dz = rs[jj][2]-rs[ii][2];
            float ln = sqrtf(dx*dx+dy*dy+dz*dz);
#pragma unroll
            for (int c=0; c<8; c++){
                float4 w0 = ((const float4*)wp0s[0])[c];
                float4 w1 = ((const float4*)wp0s[1])[c];
                float4 w2 = ((const float4*)wp0s[2])[c];
                float4 w3 = ((const float4*)wp0s[3])[c];
                float4 bb = ((const float4*)bp0s)[c];
                px[c*4+0] = tanh_fast(bb.x + dx*w0.x + dy*w1.x + dz*w2.x + ln*w3.x);
                px[c*4+1] = tanh_fast(bb.y + dx*w0.y + dy*w1.y + dz*w2.y + ln*w3.y);
                px[c*4+2] = tanh_fast(bb.z + dx*w0.z + dy*w1.z + dz*w2.z + ln*w3.z);
                px[c*4+3] = tanh_fast(bb.w + dx*w0.w + dy*w1.w + dz*w2.w + ln*w3.w);
            }
        }
#pragma unroll 1
        for (int s=0; s<3; ++s){
#pragma unroll
            for (int f=0; f<32; f++){
                float a_ = px[f];
                a_ += __shfl_xor(a_,1); a_ += __shfl_xor(a_,2);
                a_ += __shfl_xor(a_,4); a_ += __shfl_xor(a_,8);
                if (i1 == 0) pm[s][jj][f] = a_*(1.f/16.f);
            }
            if (s == 0)      pair_update(px, wp1s, bp1s);
            else if (s == 1) pair_update(px, wp2s, bp2s);
        }
    }
    __syncthreads();

    // ================= SINGLE-STREAM PHASE =================

    // A5: layer-0 GEMM (K=24 per-electron part) -> sv
    {
        float acc[4][4];
#pragma unroll
        for (int e=0;e<4;e++)
#pragma unroll
            for (int n=0;n<4;n++) acc[e][n] = csh[n0+n];
        {
            float4 sA = *(const float4*)pu0[j0+0];
            float4 sB = *(const float4*)pu0[j0+1];
            float4 sC = *(const float4*)pu0[j0+2];
            float4 sD = *(const float4*)pu0[j0+3];
            G4(Ws0, 32, sA,sB,sC,sD);
            sA = *(const float4*)pd0[j0+0];
            sB = *(const float4*)pd0[j0+1];
            sC = *(const float4*)pd0[j0+2];
            sD = *(const float4*)pd0[j0+3];
            G4(Ws0, 36, sA,sB,sC,sD);
        }
#pragma unroll
        for (int k4=0;k4<4;k4++){
            float4 sA = ((const float4*)s0[j0+0])[k4];
            float4 sB = ((const float4*)s0[j0+1])[k4];
            float4 sC = ((const float4*)s0[j0+2])[k4];
            float4 sD = ((const float4*)s0[j0+3])[k4];
            G4(Ws0, 40+k4*4, sA,sB,sC,sD);
        }
#pragma unroll
        for (int e=0;e<4;e++)
#pragma unroll
            for (int n=0;n<4;n++) sv[j0+e][n0+n] = tanh_fast(acc[e][n]);
    }
    __syncthreads();

    // S loop: layers 1..3
#pragma unroll 1
    for (int l=1; l<=3; l++){
        const float* Wl  = (l==1)?Ws1:(l==2)?Ws2:Ws3;
        const float* bl  = (l==1)?bs1:(l==2)?bs2:bs3;
        const float* puL = &pmu[l-1][0][0];
        const float* pdL = &pmd[l-1][0][0];

        // su/sd means
        if (t < 256){
            int k = t; float s=0.f;
            for (int j=0;j<16;j++) s += sv[j][k];
            su[k] = s*(1.f/16.f);
        } else {
            int k = t-256; float s=0.f;
            for (int j=16;j<32;j++) s += sv[j][k];
            sd[k] = s*(1.f/16.f);
        }
        __syncthreads();

        // shared-part GEMV partials (unroll 8: 8 outstanding L2 loads)
        {
            int n = t & 255, h = t >> 8;
            const float* src = h ? sd : su;
            const float* Wb  = Wl + h*65536;
            float a0 = h ? 0.f : bl[n];
#pragma unroll 8
            for (int k=0;k<256;k++) a0 += src[k]*Wb[k*256+n];
            cpart[h][n] = a0;
        }
        __syncthreads();
        if (t < 256) csh[t] = cpart[0][t] + cpart[1][t];
        __syncthreads();

        // per-electron GEMM, K = 32(pu)+32(pd)+256(sv)
        float acc[4][4];
#pragma unroll
        for (int e=0;e<4;e++)
#pragma unroll
            for (int n=0;n<4;n++) acc[e][n] = csh[n0+n];
#pragma unroll
        for (int k4=0;k4<8;k4++){
            float4 sA = ((const float4*)(puL + (j0+0)*32))[k4];
            float4 sB = ((const float4*)(puL + (j0+1)*32))[k4];
            float4 sC = ((const float4*)(puL + (j0+2)*32))[k4];
            float4 sD = ((const float4*)(puL + (j0+3)*32))[k4];
            G4(Wl, 512+k4*4, sA,sB,sC,sD);
        }
#pragma unroll
        for (int k4=0;k4<8;k4++){
            float4 sA = ((const float4*)(pdL + (j0+0)*32))[k4];
            float4 sB = ((const float4*)(pdL + (j0+1)*32))[k4];
            float4 sC = ((const float4*)(pdL + (j0+2)*32))[k4];
            float4 sD = ((const float4*)(pdL + (j0+3)*32))[k4];
            G4(Wl, 544+k4*4, sA,sB,sC,sD);
        }
        // sv-part: software-pipelined weight prefetch (next 4-row group in regs)
        {
            const float* WbP = Wl + 576*256 + n0;
            float4 wn0 = *(const float4*)(WbP);
            float4 wn1 = *(const float4*)(WbP + 256);
            float4 wn2 = *(const float4*)(WbP + 512);
            float4 wn3 = *(const float4*)(WbP + 768);
#pragma unroll 1
            for (int k4=0;k4<64;k4++){
                float4 w0=wn0, w1=wn1, w2=wn2, w3=wn3;
                {
                    int kn = (k4 < 63) ? (k4+1) : 63;
                    const float* Wn = WbP + kn*1024;
                    wn0 = *(const float4*)(Wn);
                    wn1 = *(const float4*)(Wn + 256);
                    wn2 = *(const float4*)(Wn + 512);
                    wn3 = *(const float4*)(Wn + 768);
                }
                float4 sA = ((const float4*)sv[j0+0])[k4];
                float4 sB = ((const float4*)sv[j0+1])[k4];
                float4 sC = ((const float4*)sv[j0+2])[k4];
                float4 sD = ((const float4*)sv[j0+3])[k4];
                FMA16(w0, sA.x, sB.x, sC.x, sD.x);
                FMA16(w1, sA.y, sB.y, sC.y, sD.y);
                FMA16(w2, sA.z, sB.z, sC.z, sD.z);
                FMA16(w3, sA.w, sB.w, sC.w, sD.w);
            }
        }
        __syncthreads();

        // residual write of sv
#pragma unroll
        for (int e=0;e<4;e++)
#pragma unroll
            for (int n=0;n<4;n++){
                float o = sv[j0+e][n0+n];
                sv[j0+e][n0+n] = tanh_fast(acc[e][n]) + o;
            }
        __syncthreads();
    }

    // F1: orbitals via folded weights
    {
        int k16 = t & 15, il = (t>>4) & 15, half = t >> 8;
        int row = half*16 + il;
        const float* WcT = Wc + half*4112;
        float a0 = WcT[4096 + k16];
#pragma unroll 8
        for (int m=0;m<256;m++) a0 += sv[row][m]*WcT[m*16+k16];
        orb[half][il][k16] = a0 * envs[row];
    }
    __syncthreads();

    // F2: 16x16 LU with partial pivoting, one wave per matrix
    {
        int w = t >> 6;
        if (w < 2){
            int lane = t & 63;
            float* M = &orb[w][0][0];   // row stride 17
            float ld_ = 0.f;
            for (int k=0;k<16;k++){
                float v = (lane>=k && lane<16) ? fabsf(M[lane*17+k]) : -1.f;
                int idx = lane;
                for (int off=32; off; off>>=1){
                    float ov = __shfl_xor(v, off);
                    int   oi = __shfl_xor(idx, off);
                    if (ov > v || (ov == v && oi < idx)){ v=ov; idx=oi; }
                }
                int p = idx;
                if (p != k && lane >= k && lane < 16){
                    float t1 = M[k*17+lane], t2 = M[p*17+lane];
                    M[k*17+lane] = t2; M[p*17+lane] = t1;
                }
                float piv = M[k*17+k];
                ld_ += logf(fabsf(piv));
                float inv = 1.f/piv;
                float rowkj = (lane<16) ? M[k*17+lane] : 0.f;
                if (lane > k && lane < 16){
                    for (int i=k+1;i<16;i++){
                        float mik = M[i*17+k]*inv;
                        M[i*17+lane] -= mik*rowkj;
                    }
                }
            }
            if (lane == 0) red[w] = ld_;
        }
    }
    __syncthreads();
    if (t == 0) out[b] = red[0] + red[1];
}

extern "C" void kernel_launch(void* const* d_in, const int* in_sizes, int n_in,
                              void* d_out, int out_size, void* d_ws, size_t ws_size,
                              hipStream_t stream) {
    const float* r   = (const float*)d_in[0];
    const float* a   = (const float*)d_in[1];
    const float* Ws0 = (const float*)d_in[2];  const float* bs0 = (const float*)d_in[3];
    const float* Wp0 = (const float*)d_in[4];  const float* bp0 = (const float*)d_in[5];
    const float* Ws1 = (const float*)d_in[6];  const float* bs1 = (const float*)d_in[7];
    const float* Wp1 = (const float*)d_in[8];  const float* bp1 = (const float*)d_in[9];
    const float* Ws2 = (const float*)d_in[10]; const float* bs2 = (const float*)d_in[11];
    const float* Wp2 = (const float*)d_in[12]; const float* bp2 = (const float*)d_in[13];
    const float* Ws3 = (const float*)d_in[14]; const float* bs3 = (const float*)d_in[15];
    const float* Wu  = (const float*)d_in[16]; const float* bu  = (const float*)d_in[17];
    const float* Wd  = (const float*)d_in[18]; const float* bd  = (const float*)d_in[19];
    const float* Wwu = (const float*)d_in[20]; const float* bwu = (const float*)d_in[21];
    const float* Wwd = (const float*)d_in[22]; const float* bwd = (const float*)d_in[23];
    float* ws = (float*)d_ws;
    float* out = (float*)d_out;

    fermi_prep<<<1, 512, 0, stream>>>(Wu, bu, Wd, bd, Wwu, bwu, Wwd, bwd, ws);
    fermi_main<<<out_size, 512, 0, stream>>>(r, a, Ws0, bs0, Wp0, bp0,
                                             Ws1, bs1, Wp1, bp1,
                                             Ws2, bs2, Wp2, bp2,
                                             Ws3, bs3, ws, out);
}

// Round 15
// 1555.821 us; speedup vs baseline: 1.1532x; 1.1532x over previous
//
#include <hip/hip_runtime.h>
#include <hip/hip_bf16.h>

__device__ __forceinline__ float tanh_fast(float x){
    float e = __expf(2.0f*x);
    return 1.0f - 2.0f/(e + 1.0f);
}

// one GEMM row: A_ = 4 electrons (transposed activations), W_ = 4 cols; acc[e][n]
#define ROWT(ACC, A_, W_) do{                                     \
    ACC[0][0] += (A_).x*(W_).x; ACC[0][1] += (A_).x*(W_).y;       \
    ACC[0][2] += (A_).x*(W_).z; ACC[0][3] += (A_).x*(W_).w;       \
    ACC[1][0] += (A_).y*(W_).x; ACC[1][1] += (A_).y*(W_).y;       \
    ACC[1][2] += (A_).y*(W_).z; ACC[1][3] += (A_).y*(W_).w;       \
    ACC[2][0] += (A_).z*(W_).x; ACC[2][1] += (A_).z*(W_).y;       \
    ACC[2][2] += (A_).z*(W_).z; ACC[2][3] += (A_).z*(W_).w;       \
    ACC[3][0] += (A_).w*(W_).x; ACC[3][1] += (A_).w*(W_).y;       \
    ACC[3][2] += (A_).w*(W_).z; ACC[3][3] += (A_).w*(W_).w;       \
}while(0)

// ---- macros for the fused fallback (round-13 2-walker kernel) ----
#define FMA16A(ACC, W_, A_, B_, C_, D_) do{                      \
    ACC[0][0] += (A_)*(W_).x; ACC[0][1] += (A_)*(W_).y;          \
    ACC[0][2] += (A_)*(W_).z; ACC[0][3] += (A_)*(W_).w;          \
    ACC[1][0] += (B_)*(W_).x; ACC[1][1] += (B_)*(W_).y;          \
    ACC[1][2] += (B_)*(W_).z; ACC[1][3] += (B_)*(W_).w;          \
    ACC[2][0] += (C_)*(W_).x; ACC[2][1] += (C_)*(W_).y;          \
    ACC[2][2] += (C_)*(W_).z; ACC[2][3] += (C_)*(W_).w;          \
    ACC[3][0] += (D_)*(W_).x; ACC[3][1] += (D_)*(W_).y;          \
    ACC[3][2] += (D_)*(W_).z; ACC[3][3] += (D_)*(W_).w;          \
}while(0)

#define ROW2(Wb, R_, c_, A0,A1,A2,A3, B0,B1,B2,B3) do{                        \
    float4 w_ = *(const float4*)((Wb) + (R_)*256 + n0);                       \
    FMA16A(acc0, w_, (A0).c_,(A1).c_,(A2).c_,(A3).c_);                        \
    FMA16A(acc1, w_, (B0).c_,(B1).c_,(B2).c_,(B3).c_);                        \
}while(0)

#define G4D(Wb, R0, A0,A1,A2,A3, B0,B1,B2,B3) do{                \
    ROW2(Wb, (R0)+0, x, A0,A1,A2,A3, B0,B1,B2,B3);               \
    ROW2(Wb, (R0)+1, y, A0,A1,A2,A3, B0,B1,B2,B3);               \
    ROW2(Wb, (R0)+2, z, A0,A1,A2,A3, B0,B1,B2,B3);               \
    ROW2(Wb, (R0)+3, w, A0,A1,A2,A3, B0,B1,B2,B3);               \
}while(0)

#define G4P(w0,w1,w2,w3, A0,A1,A2,A3, B0,B1,B2,B3) do{                                   \
    FMA16A(acc0, w0, (A0).x,(A1).x,(A2).x,(A3).x);                                       \
    FMA16A(acc1, w0, (B0).x,(B1).x,(B2).x,(B3).x);                                       \
    FMA16A(acc0, w1, (A0).y,(A1).y,(A2).y,(A3).y);                                       \
    FMA16A(acc1, w1, (B0).y,(B1).y,(B2).y,(B3).y);                                       \
    FMA16A(acc0, w2, (A0).z,(A1).z,(A2).z,(A3).z);                                       \
    FMA16A(acc1, w2, (B0).z,(B1).z,(B2).z,(B3).z);                                       \
    FMA16A(acc0, w3, (A0).w,(A1).w,(A2).w,(A3).w);                                       \
    FMA16A(acc1, w3, (B0).w,(B1).w,(B2).w,(B3).w);                                       \
}while(0)

// pair-stream residual update: px = tanh(px @ wp + b) + px   (all f32, registers)
__device__ __forceinline__ void pair_update(float (&px)[32], const float (*wp)[32], const float* bpb){
    float a2[32];
#pragma unroll
    for (int f=0;f<32;f++) a2[f] = bpb[f];
#pragma unroll 4
    for (int k=0;k<32;k++){
        float xk = px[k];
        const float4* wr = (const float4*)wp[k];
#pragma unroll
        for (int c=0;c<8;c++){
            float4 w = wr[c];
            a2[c*4+0] += xk*w.x; a2[c*4+1] += xk*w.y;
            a2[c*4+2] += xk*w.z; a2[c*4+3] += xk*w.w;
        }
    }
#pragma unroll
    for (int f=0;f<32;f++) px[f] = tanh_fast(a2[f]) + px[f];
}

// ---------------- prep: Wcu = Wu@Wwu, bcu = bu@Wwu+bwu; same for down spin ----
// ws layout (floats): [0,4096) Wcu  [4096,4112) bcu  [4112,8208) Wcd  [8208,8224) bcd
__global__ __launch_bounds__(512) void fermi_prep(
    const float* __restrict__ Wu, const float* __restrict__ bu,
    const float* __restrict__ Wd, const float* __restrict__ bd,
    const float* __restrict__ Wwu, const float* __restrict__ bwu,
    const float* __restrict__ Wwd, const float* __restrict__ bwd,
    float* __restrict__ ws)
{
    const int t = threadIdx.x;
    const int m = t & 255;
    const int half = t >> 8;
    const float* Wbig = half ? Wd : Wu;
    const float* Wsm  = half ? Wwd : Wwu;
    float acc[16];
#pragma unroll
    for (int k=0;k<16;k++) acc[k]=0.f;
    for (int h=0; h<128; h++){
        float wv = Wbig[m*128+h];
        const float4* wr = (const float4*)(Wsm + h*16);
        float4 a0=wr[0], a1=wr[1], a2=wr[2], a3=wr[3];
        acc[0]+=wv*a0.x; acc[1]+=wv*a0.y; acc[2]+=wv*a0.z; acc[3]+=wv*a0.w;
        acc[4]+=wv*a1.x; acc[5]+=wv*a1.y; acc[6]+=wv*a1.z; acc[7]+=wv*a1.w;
        acc[8]+=wv*a2.x; acc[9]+=wv*a2.y; acc[10]+=wv*a2.z; acc[11]+=wv*a2.w;
        acc[12]+=wv*a3.x; acc[13]+=wv*a3.y; acc[14]+=wv*a3.z; acc[15]+=wv*a3.w;
    }
    float* dst = ws + half*4112;
#pragma unroll
    for (int k=0;k<16;k++) dst[m*16+k]=acc[k];
    if (m < 16){
        const float* bbig = half ? bd : bu;
        float b2 = half ? bwd[m] : bwu[m];
        for (int h=0;h<128;h++) b2 += bbig[h]*Wsm[h*16+m];
        dst[4096+m] = b2;
    }
}

// ---------------- kernel 1: features + pair phase (128 VGPR, 8 waves) -------
// per-walker ws block (stride 7232 floats, base 8224 + b*7232):
//  +0 pmuT[3][32][32]  +3072 pmdT[3][32][32]  +6144 csh[256]  +6400 s0T[16][32]
//  +6912 pu0T[4][32]   +7040 pd0T[4][32]      +7168 envs[32]
__global__ __launch_bounds__(512) __attribute__((amdgpu_waves_per_eu(2,4)))
void fermi_pair(const float* __restrict__ r,   const float* __restrict__ A,
                const float* __restrict__ Ws0, const float* __restrict__ bs0,
                const float* __restrict__ Wp0, const float* __restrict__ bp0,
                const float* __restrict__ Wp1, const float* __restrict__ bp1,
                const float* __restrict__ Wp2, const float* __restrict__ bp2,
                float* __restrict__ ws)
{
    __shared__ __align__(16) float wp0s[4][32];
    __shared__ __align__(16) float wp1s[32][32];
    __shared__ __align__(16) float wp2s[32][32];
    __shared__ __align__(16) float bp0s[32], bp1s[32], bp2s[32];
    __shared__ float rs[32][3];
    __shared__ __align__(16) float s0T[16][32];
    __shared__ float ralen[32][4];
    __shared__ __align__(16) float pu0T[4][32];
    __shared__ __align__(16) float pd0T[4][32];
    __shared__ float su0[16], sd0[16];
    __shared__ float rbar[2][3];

    const int t = threadIdx.x;
    const int b = blockIdx.x;
    float* wsw = ws + 8224 + (size_t)b*7232;

    if (t < 96) rs[t/3][t%3] = r[(size_t)b*96 + t];
    if (t < 128) (&wp0s[0][0])[t] = Wp0[t];
    {
        float* w1 = &wp1s[0][0];
        w1[t]     = Wp1[t];
        w1[t+512] = Wp1[t+512];
        float* w2 = &wp2s[0][0];
        w2[t]     = Wp2[t];
        w2[t+512] = Wp2[t+512];
    }
    if (t >= 128 && t < 160) bp0s[t-128] = bp0[t-128];
    else if (t >= 160 && t < 192) bp1s[t-160] = bp1[t-160];
    else if (t >= 192 && t < 224) bp2s[t-192] = bp2[t-192];
    __syncthreads();

    if (t < 128){
        int e = t >> 2, aa = t & 3;
        float dx = rs[e][0]-A[aa*3+0];
        float dy = rs[e][1]-A[aa*3+1];
        float dz = rs[e][2]-A[aa*3+2];
        float ln = sqrtf(dx*dx+dy*dy+dz*dz);
        s0T[aa*4+0][e]=dx; s0T[aa*4+1][e]=dy;
        s0T[aa*4+2][e]=dz; s0T[aa*4+3][e]=ln;
        ralen[e][aa]=ln;
    }
    __syncthreads();

    if (t < 32){
        wsw[7168+t] = expf(-ralen[t][0])+expf(-ralen[t][1])+expf(-ralen[t][2])+expf(-ralen[t][3]);
    } else if (t < 48){
        int k = t-32; float s=0.f;
        for (int j=0;j<16;j++) s += s0T[k][j];
        su0[k] = s*(1.f/16.f);
    } else if (t < 64){
        int k = t-48; float s=0.f;
        for (int j=16;j<32;j++) s += s0T[k][j];
        sd0[k] = s*(1.f/16.f);
    } else if (t < 70){
        int q = t-64; int half=q/3, c=q%3; float s=0.f;
        for (int i=half*16;i<half*16+16;i++) s += rs[i][c];
        rbar[half][c] = s*(1.f/16.f);
    }
    __syncthreads();

    if (t < 64){
        int j = t & 31, half = t >> 5;
        float vx = rs[j][0]-rbar[half][0];
        float vy = rs[j][1]-rbar[half][1];
        float vz = rs[j][2]-rbar[half][2];
        float s=0.f; int base = half*16;
        for (int i=base;i<base+16;i++){
            if (i != j){
                float dx=rs[j][0]-rs[i][0];
                float dy=rs[j][1]-rs[i][1];
                float dz=rs[j][2]-rs[i][2];
                s += sqrtf(dx*dx+dy*dy+dz*dz);
            }
        }
        float (*dst)[32] = half ? pd0T : pu0T;
        dst[0][j]=vx; dst[1][j]=vy; dst[2][j]=vz; dst[3][j]=s*(1.f/16.f);
    }
    if (t >= 128 && t < 384){
        int n = t-128;
        float a0 = bs0[n];
        for (int k=0;k<16;k++){
            a0 += su0[k]*Ws0[k*256+n] + sd0[k]*Ws0[(16+k)*256+n];
        }
        wsw[6144+n] = a0;
    }
    __syncthreads();

    // copy-out transposed feature blocks
    wsw[6400+t] = (&s0T[0][0])[t];
    if (t < 128) wsw[6912+t] = (&pu0T[0][0])[t];
    else if (t < 256) wsw[7040+(t-128)] = (&pd0T[0][0])[t-128];

    // pair phase: 2 sequential px[32] passes; means -> ws (transposed [f][j])
    const int i1 = t & 15;
    const int jj = t >> 4;
#pragma unroll 1
    for (int h=0; h<2; ++h){
        float px[32];
        float* pmg = wsw + h*3072;
        const int ii = i1 + h*16;
        {
            float dx = rs[jj][0]-rs[ii][0];
            float dy = rs[jj][1]-rs[ii][1];
            float dz = rs[jj][2]-rs[ii][2];
            float ln = sqrtf(dx*dx+dy*dy+dz*dz);
#pragma unroll
            for (int c=0; c<8; c++){
                float4 w0 = ((const float4*)wp0s[0])[c];
                float4 w1 = ((const float4*)wp0s[1])[c];
                float4 w2 = ((const float4*)wp0s[2])[c];
                float4 w3 = ((const float4*)wp0s[3])[c];
                float4 bb = ((const float4*)bp0s)[c];
                px[c*4+0] = tanh_fast(bb.x + dx*w0.x + dy*w1.x + dz*w2.x + ln*w3.x);
                px[c*4+1] = tanh_fast(bb.y + dx*w0.y + dy*w1.y + dz*w2.y + ln*w3.y);
                px[c*4+2] = tanh_fast(bb.z + dx*w0.z + dy*w1.z + dz*w2.z + ln*w3.z);
                px[c*4+3] = tanh_fast(bb.w + dx*w0.w + dy*w1.w + dz*w2.w + ln*w3.w);
            }
        }
#pragma unroll 1
        for (int s=0; s<3; ++s){
#pragma unroll
            for (int f=0; f<32; f++){
                float a_ = px[f];
                a_ += __shfl_xor(a_,1); a_ += __shfl_xor(a_,2);
                a_ += __shfl_xor(a_,4); a_ += __shfl_xor(a_,8);
                if (i1 == 0) pmg[s*1024 + f*32 + jj] = a_*(1.f/16.f);
            }
            if (s == 0)      pair_update(px, wp1s, bp1s);
            else if (s == 1) pair_update(px, wp2s, bp2s);
        }
    }
}

// ---------------- kernel 2: single-stream phase (64-VGPR cap, 16 waves/CU) ---
// waves_per_eu(4,4) -> 64-VGPR allocator tier; live set ~45 regs (acc[4][4] +
// one activation float4 + one weight float4). LDS ~70 KB -> 2 blocks/CU.
// Col-block wave mapping (round 11): weights read ONCE per block.
__global__ __launch_bounds__(512) __attribute__((amdgpu_waves_per_eu(4,4)))
void fermi_smain(const float* __restrict__ Ws0,
                 const float* __restrict__ Ws1, const float* __restrict__ bs1,
                 const float* __restrict__ Ws2, const float* __restrict__ bs2,
                 const float* __restrict__ Ws3, const float* __restrict__ bs3,
                 const float* __restrict__ ws,  float* __restrict__ out)
{
    __shared__ __align__(16) float svT[256][36];      // [feat][electron], pad 36
    __shared__ __align__(16) float pmT[2][3][32][32]; // [h][s][f][j]
    __shared__ __align__(16) float su[256], sd[256];
    __shared__ __align__(16) float cpart[512];
    __shared__ __align__(16) float csh[256];
    __shared__ __align__(16) float s0T[16][32];
    __shared__ __align__(16) float pu0T[4][32];
    __shared__ __align__(16) float pd0T[4][32];
    __shared__ float envs[32];
    __shared__ float orb[2][16][17];
    __shared__ float red[2];

    const int t = threadIdx.x;
    const int b = blockIdx.x;
    const float* wsw = ws + 8224 + (size_t)b*7232;

    const int ln  = t & 63;
    const int wv  = t >> 6;
    const int e0  = ((ln >> 3) & 7) * 4;         // electron base
    const int n0g = wv*32 + (ln & 7)*4;          // col base

    // stage per-walker data
    {
        float* pmf = &pmT[0][0][0][0];
#pragma unroll
        for (int i=0;i<12;i++) pmf[t + i*512] = wsw[t + i*512];
        if (t < 256) csh[t] = wsw[6144+t];
        (&s0T[0][0])[t] = wsw[6400+t];
        if (t < 128) (&pu0T[0][0])[t] = wsw[6912+t];
        else if (t < 256) (&pd0T[0][0])[t-128] = wsw[7040+(t-128)];
        else if (t < 288) envs[t-256] = wsw[7168+(t-256)];
    }
    __syncthreads();

    // layer-0 GEMM (K=24) -> svT
    {
        float acc[4][4];
#pragma unroll
        for (int e=0;e<4;e++)
#pragma unroll
            for (int n=0;n<4;n++) acc[e][n] = csh[n0g+n];
#pragma unroll
        for (int rr=0; rr<4; ++rr){
            float4 w  = *(const float4*)(Ws0 + (32+rr)*256 + n0g);
            float4 Av = *(const float4*)&pu0T[rr][e0];
            ROWT(acc, Av, w);
        }
#pragma unroll
        for (int rr=0; rr<4; ++rr){
            float4 w  = *(const float4*)(Ws0 + (36+rr)*256 + n0g);
            float4 Av = *(const float4*)&pd0T[rr][e0];
            ROWT(acc, Av, w);
        }
#pragma unroll 2
        for (int rr=0; rr<16; ++rr){
            float4 w  = *(const float4*)(Ws0 + (40+rr)*256 + n0g);
            float4 Av = *(const float4*)&s0T[rr][e0];
            ROWT(acc, Av, w);
        }
#pragma unroll
        for (int n=0;n<4;n++){
            float4 v = { tanh_fast(acc[0][n]), tanh_fast(acc[1][n]),
                         tanh_fast(acc[2][n]), tanh_fast(acc[3][n]) };
            *(float4*)&svT[n0g+n][e0] = v;
        }
    }
    __syncthreads();

    // S loop: layers 1..3
#pragma unroll 1
    for (int l=1; l<=3; l++){
        const float* Wl = (l==1)?Ws1:(l==2)?Ws2:Ws3;
        const float* bl = (l==1)?bs1:(l==2)?bs2:bs3;

        if (t < 256){
            const float4* rowp = (const float4*)&svT[t][0];
            float4 a0=rowp[0], a1=rowp[1], a2=rowp[2], a3=rowp[3];
            float4 a4=rowp[4], a5=rowp[5], a6=rowp[6], a7=rowp[7];
            float s1 = (a0.x+a0.y+a0.z+a0.w)+(a1.x+a1.y+a1.z+a1.w)
                     + (a2.x+a2.y+a2.z+a2.w)+(a3.x+a3.y+a3.z+a3.w);
            float s2 = (a4.x+a4.y+a4.z+a4.w)+(a5.x+a5.y+a5.z+a5.w)
                     + (a6.x+a6.y+a6.z+a6.w)+(a7.x+a7.y+a7.z+a7.w);
            su[t] = s1*(1.f/16.f);
            sd[t] = s2*(1.f/16.f);
        }
        __syncthreads();

        {
            int h = t >> 8, n = t & 255;
            const float* Wb  = Wl + h*65536;
            const float* src = h ? sd : su;
            float a0 = h ? 0.f : bl[n];
#pragma unroll 8
            for (int k=0;k<256;k++) a0 += src[k]*Wb[k*256+n];
            cpart[h*256+n] = a0;
        }
        __syncthreads();
        if (t < 256) csh[t] = cpart[t] + cpart[256+t];
        __syncthreads();

        float acc[4][4];
#pragma unroll
        for (int e=0;e<4;e++)
#pragma unroll
            for (int n=0;n<4;n++) acc[e][n] = csh[n0g+n];
        {
            const float (*puA)[32] = pmT[0][l-1];
            const float (*pdA)[32] = pmT[1][l-1];
#pragma unroll 2
            for (int R=0; R<32; ++R){
                float4 w  = *(const float4*)(Wl + (512+R)*256 + n0g);
                float4 Av = *(const float4*)&puA[R][e0];
                ROWT(acc, Av, w);
            }
#pragma unroll 2
            for (int R=0; R<32; ++R){
                float4 w  = *(const float4*)(Wl + (544+R)*256 + n0g);
                float4 Av = *(const float4*)&pdA[R][e0];
                ROWT(acc, Av, w);
            }
        }
#pragma unroll 2
        for (int R=0; R<256; ++R){
            float4 w  = *(const float4*)(Wl + (576+R)*256 + n0g);
            float4 Av = *(const float4*)&svT[R][e0];
            ROWT(acc, Av, w);
        }
        __syncthreads();

#pragma unroll
        for (int n=0;n<4;n++){
            float4 o = *(const float4*)&svT[n0g+n][e0];
            float4 v = { tanh_fast(acc[0][n])+o.x, tanh_fast(acc[1][n])+o.y,
                         tanh_fast(acc[2][n])+o.z, tanh_fast(acc[3][n])+o.w };
            *(float4*)&svT[n0g+n][e0] = v;
        }
        __syncthreads();
    }

    // F1: orbitals via folded weights (2 halves x 16x16; Wc in ws[0..8224))
    {
        int half = t >> 8, il = (t >> 4) & 15, k16 = t & 15;
        int row = half*16 + il;
        const float* WcT = ws + half*4112;
        float a0 = WcT[4096 + k16];
#pragma unroll 8
        for (int m=0;m<256;m++) a0 += svT[m][row]*WcT[m*16+k16];
        orb[half][il][k16] = a0 * envs[row];
    }
    __syncthreads();

    // F2: 16x16 LU with partial pivoting, one wave per matrix
    {
        int w = t >> 6;
        if (w < 2){
            int lane = t & 63;
            float* M = &orb[w][0][0];   // row stride 17
            float ld_ = 0.f;
            for (int k=0;k<16;k++){
                float v = (lane>=k && lane<16) ? fabsf(M[lane*17+k]) : -1.f;
                int idx = lane;
                for (int off=32; off; off>>=1){
                    float ov = __shfl_xor(v, off);
                    int   oi = __shfl_xor(idx, off);
                    if (ov > v || (ov == v && oi < idx)){ v=ov; idx=oi; }
                }
                int p = idx;
                if (p != k && lane >= k && lane < 16){
                    float t1 = M[k*17+lane], t2 = M[p*17+lane];
                    M[k*17+lane] = t2; M[p*17+lane] = t1;
                }
                float piv = M[k*17+k];
                ld_ += logf(fabsf(piv));
                float inv = 1.f/piv;
                float rowkj = (lane<16) ? M[k*17+lane] : 0.f;
                if (lane > k && lane < 16){
                    for (int i=k+1;i<16;i++){
                        float mik = M[i*17+k]*inv;
                        M[i*17+lane] -= mik*rowkj;
                    }
                }
            }
            if (lane == 0) red[w] = ld_;
        }
    }
    __syncthreads();
    if (t == 0) out[b] = red[0] + red[1];
}

// ---------------- fused fallback: round-13 2-walker kernel (1443 us) --------
__global__ __launch_bounds__(512) __attribute__((amdgpu_waves_per_eu(2,2))) void fermi_fused(
    const float* __restrict__ r,   const float* __restrict__ A,
    const float* __restrict__ Ws0, const float* __restrict__ bs0,
    const float* __restrict__ Wp0, const float* __restrict__ bp0,
    const float* __restrict__ Ws1, const float* __restrict__ bs1,
    const float* __restrict__ Wp1, const float* __restrict__ bp1,
    const float* __restrict__ Ws2, const float* __restrict__ bs2,
    const float* __restrict__ Wp2, const float* __restrict__ bp2,
    const float* __restrict__ Ws3, const float* __restrict__ bs3,
    const float* __restrict__ Wc,  float* __restrict__ out)
{
    __shared__ __align__(16) float sv2[2][32][256];
    __shared__ __align__(16) float pmu2[2][3][32][32];
    __shared__ __align__(16) float pmd2[2][3][32][32];
    __shared__ __align__(16) float su2[2][256];
    __shared__ __align__(16) float sd2[2][256];
    __shared__ __align__(16) float pool[1536];
    __shared__ __align__(16) float wp0s[4][32];
    __shared__ __align__(16) float wp1s[32][32];
    __shared__ __align__(16) float wp2s[32][32];
    __shared__ __align__(16) float bp0s[32], bp1s[32], bp2s[32];
    __shared__ float rs2[2][32][3];
    __shared__ __align__(16) float s02[2][32][16];
    __shared__ float ralen2[2][32][4];
    __shared__ float envs2[2][32];
    __shared__ __align__(16) float pu02[2][32][4];
    __shared__ __align__(16) float pd02[2][32][4];
    __shared__ float su02[2][16], sd02[2][16];
    __shared__ float rbar2[2][2][3];
    __shared__ float red2[2][2];

    const int t = threadIdx.x;
    const int b = blockIdx.x;
    const int n0 = (t & 63) * 4;
    const int j0 = (t >> 6) * 4;
    float* cpart = pool;
    float* cshf  = pool + 1024;

    if (t < 192) (&rs2[0][0][0])[t] = r[(size_t)b*192 + t];
    if (t < 128) (&wp0s[0][0])[t] = Wp0[t];
    {
        float* w1 = &wp1s[0][0];
        w1[t]     = Wp1[t];
        w1[t+512] = Wp1[t+512];
        float* w2 = &wp2s[0][0];
        w2[t]     = Wp2[t];
        w2[t+512] = Wp2[t+512];
    }
    if (t >= 192 && t < 224) bp0s[t-192] = bp0[t-192];
    else if (t >= 224 && t < 256) bp1s[t-224] = bp1[t-224];
    else if (t >= 256 && t < 288) bp2s[t-256] = bp2[t-256];
    __syncthreads();

    if (t < 256){
        int wk = t >> 7, q = t & 127;
        int e = q >> 2, aa = q & 3;
        float dx = rs2[wk][e][0]-A[aa*3+0];
        float dy = rs2[wk][e][1]-A[aa*3+1];
        float dz = rs2[wk][e][2]-A[aa*3+2];
        float ln = sqrtf(dx*dx+dy*dy+dz*dz);
        s02[wk][e][aa*4+0]=dx; s02[wk][e][aa*4+1]=dy;
        s02[wk][e][aa*4+2]=dz; s02[wk][e][aa*4+3]=ln;
        ralen2[wk][e][aa]=ln;
    }
    __syncthreads();

    if (t < 64){
        int wk = t >> 5, e = t & 31;
        envs2[wk][e] = expf(-ralen2[wk][e][0])+expf(-ralen2[wk][e][1])
                     + expf(-ralen2[wk][e][2])+expf(-ralen2[wk][e][3]);
    } else if (t < 128){
        int q = t-64; int wk = q >> 5, half = (q >> 4) & 1, k = q & 15;
        float s = 0.f; int jb = half*16;
        for (int j=jb; j<jb+16; j++) s += s02[wk][j][k];
        (half ? sd02 : su02)[wk][k] = s*(1.f/16.f);
    } else if (t < 140){
        int q = t-128; int wk = q/6, rr_ = q%6, half = rr_/3, c = rr_%3;
        float s=0.f;
        for (int i=half*16;i<half*16+16;i++) s += rs2[wk][i][c];
        rbar2[wk][half][c] = s*(1.f/16.f);
    }
    __syncthreads();

    if (t < 128){
        int wk = t >> 6, q = t & 63;
        int j = q & 31, half = q >> 5;
        float* dst = (half ? pd02 : pu02)[wk][j];
        dst[0] = rs2[wk][j][0]-rbar2[wk][half][0];
        dst[1] = rs2[wk][j][1]-rbar2[wk][half][1];
        dst[2] = rs2[wk][j][2]-rbar2[wk][half][2];
        float s=0.f; int base = half*16;
        for (int i=base;i<base+16;i++){
            if (i != j){
                float dx=rs2[wk][j][0]-rs2[wk][i][0];
                float dy=rs2[wk][j][1]-rs2[wk][i][1];
                float dz=rs2[wk][j][2]-rs2[wk][i][2];
                s += sqrtf(dx*dx+dy*dy+dz*dz);
            }
        }
        dst[3] = s*(1.f/16.f);
    }
    {
        int wk = t >> 8, n = t & 255;
        float a0 = bs0[n];
        for (int k=0;k<16;k++){
            a0 += su02[wk][k]*Ws0[k*256+n] + sd02[wk][k]*Ws0[(16+k)*256+n];
        }
        cshf[wk*256+n] = a0;
    }
    __syncthreads();

    {
        const int i1  = t & 15;
        const int jj4 = (t >> 4) & 15;
        const int wkp = t >> 8;
#pragma unroll 1
        for (int pass=0; pass<4; ++pass){
            const int h   = pass >> 1;
            const int jjs = jj4 + (pass & 1)*16;
            const int ii  = i1 + h*16;
            float px[32];
            {
                float dx = rs2[wkp][jjs][0]-rs2[wkp][ii][0];
                float dy = rs2[wkp][jjs][1]-rs2[wkp][ii][1];
                float dz = rs2[wkp][jjs][2]-rs2[wkp][ii][2];
                float ln = sqrtf(dx*dx+dy*dy+dz*dz);
#pragma unroll
                for (int c=0; c<8; c++){
                    float4 w0 = ((const float4*)wp0s[0])[c];
                    float4 w1 = ((const float4*)wp0s[1])[c];
                    float4 w2 = ((const float4*)wp0s[2])[c];
                    float4 w3 = ((const float4*)wp0s[3])[c];
                    float4 bb = ((const float4*)bp0s)[c];
                    px[c*4+0] = tanh_fast(bb.x + dx*w0.x + dy*w1.x + dz*w2.x + ln*w3.x);
                    px[c*4+1] = tanh_fast(bb.y + dx*w0.y + dy*w1.y + dz*w2.y + ln*w3.y);
                    px[c*4+2] = tanh_fast(bb.z + dx*w0.z + dy*w1.z + dz*w2.z + ln*w3.z);
                    px[c*4+3] = tanh_fast(bb.w + dx*w0.w + dy*w1.w + dz*w2.w + ln*w3.w);
                }
            }
            float (*pm)[32][32] = h ? pmd2[wkp] : pmu2[wkp];
#pragma unroll 1
            for (int s=0; s<3; ++s){
#pragma unroll
                for (int f=0; f<32; f++){
                    float a_ = px[f];
                    a_ += __shfl_xor(a_,1); a_ += __shfl_xor(a_,2);
                    a_ += __shfl_xor(a_,4); a_ += __shfl_xor(a_,8);
                    if (i1 == 0) pm[s][jjs][f] = a_*(1.f/16.f);
                }
                if (s == 0)      pair_update(px, wp1s, bp1s);
                else if (s == 1) pair_update(px, wp2s, bp2s);
            }
        }
    }
    __syncthreads();

    {
        float acc0[4][4], acc1[4][4];
#pragma unroll
        for (int e=0;e<4;e++)
#pragma unroll
            for (int n=0;n<4;n++){ acc0[e][n] = cshf[n0+n]; acc1[e][n] = cshf[256+n0+n]; }
        {
            float4 A0 = *(const float4*)pu02[0][j0+0];
            float4 A1 = *(const float4*)pu02[0][j0+1];
            float4 A2 = *(const float4*)pu02[0][j0+2];
            float4 A3 = *(const float4*)pu02[0][j0+3];
            float4 B0 = *(const float4*)pu02[1][j0+0];
            float4 B1 = *(const float4*)pu02[1][j0+1];
            float4 B2 = *(const float4*)pu02[1][j0+2];
            float4 B3 = *(const float4*)pu02[1][j0+3];
            G4D(Ws0, 32, A0,A1,A2,A3, B0,B1,B2,B3);
            A0 = *(const float4*)pd02[0][j0+0];
            A1 = *(const float4*)pd02[0][j0+1];
            A2 = *(const float4*)pd02[0][j0+2];
            A3 = *(const float4*)pd02[0][j0+3];
            B0 = *(const float4*)pd02[1][j0+0];
            B1 = *(const float4*)pd02[1][j0+1];
            B2 = *(const float4*)pd02[1][j0+2];
            B3 = *(const float4*)pd02[1][j0+3];
            G4D(Ws0, 36, A0,A1,A2,A3, B0,B1,B2,B3);
        }
#pragma unroll
        for (int k4=0;k4<4;k4++){
            float4 A0 = ((const float4*)s02[0][j0+0])[k4];
            float4 A1 = ((const float4*)s02[0][j0+1])[k4];
            float4 A2 = ((const float4*)s02[0][j0+2])[k4];
            float4 A3 = ((const float4*)s02[0][j0+3])[k4];
            float4 B0 = ((const float4*)s02[1][j0+0])[k4];
            float4 B1 = ((const float4*)s02[1][j0+1])[k4];
            float4 B2 = ((const float4*)s02[1][j0+2])[k4];
            float4 B3 = ((const float4*)s02[1][j0+3])[k4];
            G4D(Ws0, 40+k4*4, A0,A1,A2,A3, B0,B1,B2,B3);
        }
#pragma unroll
        for (int e=0;e<4;e++)
#pragma unroll
            for (int n=0;n<4;n++){
                sv2[0][j0+e][n0+n] = tanh_fast(acc0[e][n]);
                sv2[1][j0+e][n0+n] = tanh_fast(acc1[e][n]);
            }
    }
    __syncthreads();

#pragma unroll 1
    for (int l=1; l<=3; l++){
        const float* Wl  = (l==1)?Ws1:(l==2)?Ws2:Ws3;
        const float* bl  = (l==1)?bs1:(l==2)?bs2:bs3;

        {
            int wk = t >> 8, k = t & 255;
            float s1=0.f, s2=0.f;
            for (int j=0;j<16;j++)  s1 += sv2[wk][j][k];
            for (int j=16;j<32;j++) s2 += sv2[wk][j][k];
            su2[wk][k] = s1*(1.f/16.f);
            sd2[wk][k] = s2*(1.f/16.f);
        }
        __syncthreads();

        {
            int h = t >> 8, n = t & 255;
            const float* Wb = Wl + h*65536;
            const float* sA = h ? sd2[0] : su2[0];
            const float* sB = h ? sd2[1] : su2[1];
            float a0 = h ? 0.f : bl[n];
            float a1 = a0;
#pragma unroll 8
            for (int k=0;k<256;k++){
                float wv = Wb[k*256+n];
                a0 += sA[k]*wv; a1 += sB[k]*wv;
            }
            cpart[(0*2+h)*256+n] = a0;
            cpart[(1*2+h)*256+n] = a1;
        }
        __syncthreads();
        {
            int wk = t >> 8, n = t & 255;
            cshf[wk*256+n] = cpart[(wk*2+0)*256+n] + cpart[(wk*2+1)*256+n];
        }
        __syncthreads();

        float acc0[4][4], acc1[4][4];
#pragma unroll
        for (int e=0;e<4;e++)
#pragma unroll
            for (int n=0;n<4;n++){ acc0[e][n] = cshf[n0+n]; acc1[e][n] = cshf[256+n0+n]; }
        const float* puA = &pmu2[0][l-1][0][0];
        const float* puB = &pmu2[1][l-1][0][0];
        const float* pdA = &pmd2[0][l-1][0][0];
        const float* pdB = &pmd2[1][l-1][0][0];
#pragma unroll
        for (int k4=0;k4<8;k4++){
            float4 A0 = ((const float4*)(puA + (j0+0)*32))[k4];
            float4 A1 = ((const float4*)(puA + (j0+1)*32))[k4];
            float4 A2 = ((const float4*)(puA + (j0+2)*32))[k4];
            float4 A3 = ((const float4*)(puA + (j0+3)*32))[k4];
            float4 B0 = ((const float4*)(puB + (j0+0)*32))[k4];
            float4 B1 = ((const float4*)(puB + (j0+1)*32))[k4];
            float4 B2 = ((const float4*)(puB + (j0+2)*32))[k4];
            float4 B3 = ((const float4*)(puB + (j0+3)*32))[k4];
            G4D(Wl, 512+k4*4, A0,A1,A2,A3, B0,B1,B2,B3);
        }
#pragma unroll
        for (int k4=0;k4<8;k4++){
            float4 A0 = ((const float4*)(pdA + (j0+0)*32))[k4];
            float4 A1 = ((const float4*)(pdA + (j0+1)*32))[k4];
            float4 A2 = ((const float4*)(pdA + (j0+2)*32))[k4];
            float4 A3 = ((const float4*)(pdA + (j0+3)*32))[k4];
            float4 B0 = ((const float4*)(pdB + (j0+0)*32))[k4];
            float4 B1 = ((const float4*)(pdB + (j0+1)*32))[k4];
            float4 B2 = ((const float4*)(pdB + (j0+2)*32))[k4];
            float4 B3 = ((const float4*)(pdB + (j0+3)*32))[k4];
            G4D(Wl, 544+k4*4, A0,A1,A2,A3, B0,B1,B2,B3);
        }
        {
            const float* WbP = Wl + 576*256 + n0;
            float4 wn0 = *(const float4*)(WbP);
            float4 wn1 = *(const float4*)(WbP + 256);
            float4 wn2 = *(const float4*)(WbP + 512);
            float4 wn3 = *(const float4*)(WbP + 768);
#pragma unroll 1
            for (int k4=0;k4<64;k4++){
                float4 w0=wn0, w1=wn1, w2=wn2, w3=wn3;
                {
                    int kn = (k4 < 63) ? (k4+1) : 63;
                    const float* Wn = WbP + kn*1024;
                    wn0 = *(const float4*)(Wn);
                    wn1 = *(const float4*)(Wn + 256);
                    wn2 = *(const float4*)(Wn + 512);
                    wn3 = *(const float4*)(Wn + 768);
                }
                float4 A0 = ((const float4*)sv2[0][j0+0])[k4];
                float4 A1 = ((const float4*)sv2[0][j0+1])[k4];
                float4 A2 = ((const float4*)sv2[0][j0+2])[k4];
                float4 A3 = ((const float4*)sv2[0][j0+3])[k4];
                float4 B0 = ((const float4*)sv2[1][j0+0])[k4];
                float4 B1 = ((const float4*)sv2[1][j0+1])[k4];
                float4 B2 = ((const float4*)sv2[1][j0+2])[k4];
                float4 B3 = ((const float4*)sv2[1][j0+3])[k4];
                G4P(w0,w1,w2,w3, A0,A1,A2,A3, B0,B1,B2,B3);
            }
        }
        __syncthreads();

#pragma unroll
        for (int e=0;e<4;e++)
#pragma unroll
            for (int n=0;n<4;n++){
                float o0 = sv2[0][j0+e][n0+n];
                float o1 = sv2[1][j0+e][n0+n];
                sv2[0][j0+e][n0+n] = tanh_fast(acc0[e][n]) + o0;
                sv2[1][j0+e][n0+n] = tanh_fast(acc1[e][n]) + o1;
            }
        __syncthreads();
    }

#pragma unroll 1
    for (int rep=0; rep<2; ++rep){
        int idx = t + rep*512;
        int wk = idx >> 9, rem = idx & 511;
        int half = rem >> 8, il = (rem >> 4) & 15, k16 = rem & 15;
        int row = half*16 + il;
        const float* WcT = Wc + half*4112;
        float a0 = WcT[4096 + k16];
#pragma unroll 8
        for (int m=0;m<256;m++) a0 += sv2[wk][row][m]*WcT[m*16+k16];
        pool[(wk*2+half)*272 + il*17 + k16] = a0 * envs2[wk][row];
    }
    __syncthreads();

    {
        int w = t >> 6;
        if (w < 4){
            int lane = t & 63;
            float* M = pool + w*272;
            float ld_ = 0.f;
            for (int k=0;k<16;k++){
                float v = (lane>=k && lane<16) ? fabsf(M[lane*17+k]) : -1.f;
                int idx = lane;
                for (int off=32; off; off>>=1){
                    float ov = __shfl_xor(v, off);
                    int   oi = __shfl_xor(idx, off);
                    if (ov > v || (ov == v && oi < idx)){ v=ov; idx=oi; }
                }
                int p = idx;
                if (p != k && lane >= k && lane < 16){
                    float t1 = M[k*17+lane], t2 = M[p*17+lane];
                    M[k*17+lane] = t2; M[p*17+lane] = t1;
                }
                float piv = M[k*17+k];
                ld_ += logf(fabsf(piv));
                float inv = 1.f/piv;
                float rowkj = (lane<16) ? M[k*17+lane] : 0.f;
                if (lane > k && lane < 16){
                    for (int i=k+1;i<16;i++){
                        float mik = M[i*17+k]*inv;
                        M[i*17+lane] -= mik*rowkj;
                    }
                }
            }
            if (lane == 0) red2[w>>1][w&1] = ld_;
        }
    }
    __syncthreads();
    if (t < 2) out[2*b + t] = red2[t][0] + red2[t][1];
}

extern "C" void kernel_launch(void* const* d_in, const int* in_sizes, int n_in,
                              void* d_out, int out_size, void* d_ws, size_t ws_size,
                              hipStream_t stream) {
    const float* r   = (const float*)d_in[0];
    const float* a   = (const float*)d_in[1];
    const float* Ws0 = (const float*)d_in[2];  const float* bs0 = (const float*)d_in[3];
    const float* Wp0 = (const float*)d_in[4];  const float* bp0 = (const float*)d_in[5];
    const float* Ws1 = (const float*)d_in[6];  const float* bs1 = (const float*)d_in[7];
    const float* Wp1 = (const float*)d_in[8];  const float* bp1 = (const float*)d_in[9];
    const float* Ws2 = (const float*)d_in[10]; const float* bs2 = (const float*)d_in[11];
    const float* Wp2 = (const float*)d_in[12]; const float* bp2 = (const float*)d_in[13];
    const float* Ws3 = (const float*)d_in[14]; const float* bs3 = (const float*)d_in[15];
    const float* Wu  = (const float*)d_in[16]; const float* bu  = (const float*)d_in[17];
    const float* Wd  = (const float*)d_in[18]; const float* bd  = (const float*)d_in[19];
    const float* Wwu = (const float*)d_in[20]; const float* bwu = (const float*)d_in[21];
    const float* Wwd = (const float*)d_in[22]; const float* bwd = (const float*)d_in[23];
    float* ws = (float*)d_ws;
    float* out = (float*)d_out;

    const int B = out_size;
    const size_t need = ((size_t)8224 + (size_t)B*7232) * 4;

    fermi_prep<<<1, 512, 0, stream>>>(Wu, bu, Wd, bd, Wwu, bwu, Wwd, bwd, ws);
    if (ws_size >= need){
        fermi_pair<<<B, 512, 0, stream>>>(r, a, Ws0, bs0, Wp0, bp0,
                                          Wp1, bp1, Wp2, bp2, ws);
        fermi_smain<<<B, 512, 0, stream>>>(Ws0, Ws1, bs1, Ws2, bs2, Ws3, bs3, ws, out);
    } else {
        fermi_fused<<<B/2, 512, 0, stream>>>(r, a, Ws0, bs0, Wp0, bp0,
                                             Ws1, bs1, Wp1, bp1,
                                             Ws2, bs2, Wp2, bp2,
                                             Ws3, bs3, ws, out);
    }
}

// Round 16
// 1105.459 us; speedup vs baseline: 1.6230x; 1.4074x over previous
//
#include <hip/hip_runtime.h>
#include <hip/hip_bf16.h>

__device__ __forceinline__ float tanh_fast(float x){
    float e = __expf(2.0f*x);
    return 1.0f - 2.0f/(e + 1.0f);
}

// one GEMM row: A_ = 4 electrons (transposed activations), W_ = 4 cols; acc[e][n]
#define ROWT(ACC, A_, W_) do{                                     \
    ACC[0][0] += (A_).x*(W_).x; ACC[0][1] += (A_).x*(W_).y;       \
    ACC[0][2] += (A_).x*(W_).z; ACC[0][3] += (A_).x*(W_).w;       \
    ACC[1][0] += (A_).y*(W_).x; ACC[1][1] += (A_).y*(W_).y;       \
    ACC[1][2] += (A_).y*(W_).z; ACC[1][3] += (A_).y*(W_).w;       \
    ACC[2][0] += (A_).z*(W_).x; ACC[2][1] += (A_).z*(W_).y;       \
    ACC[2][2] += (A_).z*(W_).z; ACC[2][3] += (A_).z*(W_).w;       \
    ACC[3][0] += (A_).w*(W_).x; ACC[3][1] += (A_).w*(W_).y;       \
    ACC[3][2] += (A_).w*(W_).z; ACC[3][3] += (A_).w*(W_).w;       \
}while(0)

// ---- macros for the fused fallback (round-13 2-walker kernel) ----
#define FMA16A(ACC, W_, A_, B_, C_, D_) do{                      \
    ACC[0][0] += (A_)*(W_).x; ACC[0][1] += (A_)*(W_).y;          \
    ACC[0][2] += (A_)*(W_).z; ACC[0][3] += (A_)*(W_).w;          \
    ACC[1][0] += (B_)*(W_).x; ACC[1][1] += (B_)*(W_).y;          \
    ACC[1][2] += (B_)*(W_).z; ACC[1][3] += (B_)*(W_).w;          \
    ACC[2][0] += (C_)*(W_).x; ACC[2][1] += (C_)*(W_).y;          \
    ACC[2][2] += (C_)*(W_).z; ACC[2][3] += (C_)*(W_).w;          \
    ACC[3][0] += (D_)*(W_).x; ACC[3][1] += (D_)*(W_).y;          \
    ACC[3][2] += (D_)*(W_).z; ACC[3][3] += (D_)*(W_).w;          \
}while(0)

#define ROW2(Wb, R_, c_, A0,A1,A2,A3, B0,B1,B2,B3) do{                        \
    float4 w_ = *(const float4*)((Wb) + (R_)*256 + n0);                       \
    FMA16A(acc0, w_, (A0).c_,(A1).c_,(A2).c_,(A3).c_);                        \
    FMA16A(acc1, w_, (B0).c_,(B1).c_,(B2).c_,(B3).c_);                        \
}while(0)

#define G4D(Wb, R0, A0,A1,A2,A3, B0,B1,B2,B3) do{                \
    ROW2(Wb, (R0)+0, x, A0,A1,A2,A3, B0,B1,B2,B3);               \
    ROW2(Wb, (R0)+1, y, A0,A1,A2,A3, B0,B1,B2,B3);               \
    ROW2(Wb, (R0)+2, z, A0,A1,A2,A3, B0,B1,B2,B3);               \
    ROW2(Wb, (R0)+3, w, A0,A1,A2,A3, B0,B1,B2,B3);               \
}while(0)

#define G4P(w0,w1,w2,w3, A0,A1,A2,A3, B0,B1,B2,B3) do{                                   \
    FMA16A(acc0, w0, (A0).x,(A1).x,(A2).x,(A3).x);                                       \
    FMA16A(acc1, w0, (B0).x,(B1).x,(B2).x,(B3).x);                                       \
    FMA16A(acc0, w1, (A0).y,(A1).y,(A2).y,(A3).y);                                       \
    FMA16A(acc1, w1, (B0).y,(B1).y,(B2).y,(B3).y);                                       \
    FMA16A(acc0, w2, (A0).z,(A1).z,(A2).z,(A3).z);                                       \
    FMA16A(acc1, w2, (B0).z,(B1).z,(B2).z,(B3).z);                                       \
    FMA16A(acc0, w3, (A0).w,(A1).w,(A2).w,(A3).w);                                       \
    FMA16A(acc1, w3, (B0).w,(B1).w,(B2).w,(B3).w);                                       \
}while(0)

// register-array pair update (used only by the fused fallback)
__device__ __forceinline__ void pair_update(float (&px)[32], const float (*wp)[32], const float* bpb){
    float a2[32];
#pragma unroll
    for (int f=0;f<32;f++) a2[f] = bpb[f];
#pragma unroll 4
    for (int k=0;k<32;k++){
        float xk = px[k];
        const float4* wr = (const float4*)wp[k];
#pragma unroll
        for (int c=0;c<8;c++){
            float4 w = wr[c];
            a2[c*4+0] += xk*w.x; a2[c*4+1] += xk*w.y;
            a2[c*4+2] += xk*w.z; a2[c*4+3] += xk*w.w;
        }
    }
#pragma unroll
    for (int f=0;f<32;f++) px[f] = tanh_fast(a2[f]) + px[f];
}

// ---------------- prep: Wcu = Wu@Wwu, bcu = bu@Wwu+bwu; same for down spin ----
// ws layout (floats): [0,4096) Wcu  [4096,4112) bcu  [4112,8208) Wcd  [8208,8224) bcd
__global__ __launch_bounds__(512) void fermi_prep(
    const float* __restrict__ Wu, const float* __restrict__ bu,
    const float* __restrict__ Wd, const float* __restrict__ bd,
    const float* __restrict__ Wwu, const float* __restrict__ bwu,
    const float* __restrict__ Wwd, const float* __restrict__ bwd,
    float* __restrict__ ws)
{
    const int t = threadIdx.x;
    const int m = t & 255;
    const int half = t >> 8;
    const float* Wbig = half ? Wd : Wu;
    const float* Wsm  = half ? Wwd : Wwu;
    float acc[16];
#pragma unroll
    for (int k=0;k<16;k++) acc[k]=0.f;
    for (int h=0; h<128; h++){
        float wv = Wbig[m*128+h];
        const float4* wr = (const float4*)(Wsm + h*16);
        float4 a0=wr[0], a1=wr[1], a2=wr[2], a3=wr[3];
        acc[0]+=wv*a0.x; acc[1]+=wv*a0.y; acc[2]+=wv*a0.z; acc[3]+=wv*a0.w;
        acc[4]+=wv*a1.x; acc[5]+=wv*a1.y; acc[6]+=wv*a1.z; acc[7]+=wv*a1.w;
        acc[8]+=wv*a2.x; acc[9]+=wv*a2.y; acc[10]+=wv*a2.z; acc[11]+=wv*a2.w;
        acc[12]+=wv*a3.x; acc[13]+=wv*a3.y; acc[14]+=wv*a3.z; acc[15]+=wv*a3.w;
    }
    float* dst = ws + half*4112;
#pragma unroll
    for (int k=0;k<16;k++) dst[m*16+k]=acc[k];
    if (m < 16){
        const float* bbig = half ? bd : bu;
        float b2 = half ? bwd[m] : bwu[m];
        for (int h=0;h<128;h++) b2 += bbig[h]*Wsm[h*16+m];
        dst[4096+m] = b2;
    }
}

// ---------------- kernel 1: features + pair phase, LDS-resident pair state ---
// Pair state lives in pxQ[256][36] LDS (one quarter = 256 pairs at a time);
// each update is a (256x32)@(32x32) tiled GEMM: thread = 4 pairs x 4 features,
// acc[4][4] only -> ~50 VGPR -> 64-tier -> 16 waves/CU (2 blocks x 73.6KB).
// This removes the px[32]+a2[32] register arrays whose spill dominated the
// old pair kernel (~620us for a ~100us VALU floor).
// per-walker ws block (stride 7232 floats, base 8224 + b*7232):
//  +0 pmuT[3][32][32]  +3072 pmdT[3][32][32]  +6144 csh[256]  +6400 s0T[16][32]
//  +6912 pu0T[4][32]   +7040 pd0T[4][32]      +7168 envs[32]
__global__ __launch_bounds__(512) __attribute__((amdgpu_waves_per_eu(4,4)))
void fermi_pair(const float* __restrict__ r,   const float* __restrict__ A,
                const float* __restrict__ Ws0, const float* __restrict__ bs0,
                const float* __restrict__ Wp0, const float* __restrict__ bp0,
                const float* __restrict__ Wp1, const float* __restrict__ bp1,
                const float* __restrict__ Wp2, const float* __restrict__ bp2,
                float* __restrict__ ws)
{
    __shared__ __align__(16) float pxQ[256][36];      // quarter pair state [p][f]
    __shared__ __align__(16) float pm[6][32][33];     // means acc [(h*3+s)][f][j]
    __shared__ __align__(16) float wp0s[4][32];
    __shared__ __align__(16) float wp1s[32][32];
    __shared__ __align__(16) float wp2s[32][32];
    __shared__ __align__(16) float bp0s[32], bp1s[32], bp2s[32];
    __shared__ float rs[32][3];
    __shared__ __align__(16) float s0T[16][32];
    __shared__ float ralen[32][4];
    __shared__ __align__(16) float pu0T[4][32];
    __shared__ __align__(16) float pd0T[4][32];
    __shared__ float su0[16], sd0[16];
    __shared__ float rbar[2][3];

    const int t = threadIdx.x;
    const int b = blockIdx.x;
    float* wsw = ws + 8224 + (size_t)b*7232;

    // A1 staging
    if (t < 96) rs[t/3][t%3] = r[(size_t)b*96 + t];
    if (t < 128) (&wp0s[0][0])[t] = Wp0[t];
    {
        float* w1 = &wp1s[0][0];
        w1[t]     = Wp1[t];
        w1[t+512] = Wp1[t+512];
        float* w2 = &wp2s[0][0];
        w2[t]     = Wp2[t];
        w2[t+512] = Wp2[t+512];
    }
    if (t >= 128 && t < 160) bp0s[t-128] = bp0[t-128];
    else if (t >= 160 && t < 192) bp1s[t-160] = bp1[t-160];
    else if (t >= 192 && t < 224) bp2s[t-192] = bp2[t-192];
    {   // zero the means accumulator (6*32*33 = 6336 floats)
        float* pmf = &pm[0][0][0];
        for (int i = t; i < 6336; i += 512) pmf[i] = 0.f;
    }
    __syncthreads();

    // A2: electron-atom features (transposed)
    if (t < 128){
        int e = t >> 2, aa = t & 3;
        float dx = rs[e][0]-A[aa*3+0];
        float dy = rs[e][1]-A[aa*3+1];
        float dz = rs[e][2]-A[aa*3+2];
        float ln = sqrtf(dx*dx+dy*dy+dz*dz);
        s0T[aa*4+0][e]=dx; s0T[aa*4+1][e]=dy;
        s0T[aa*4+2][e]=dz; s0T[aa*4+3][e]=ln;
        ralen[e][aa]=ln;
    }
    __syncthreads();

    // A3: envs -> ws, su0/sd0, rbar
    if (t < 32){
        wsw[7168+t] = expf(-ralen[t][0])+expf(-ralen[t][1])+expf(-ralen[t][2])+expf(-ralen[t][3]);
    } else if (t < 48){
        int k = t-32; float s=0.f;
        for (int j=0;j<16;j++) s += s0T[k][j];
        su0[k] = s*(1.f/16.f);
    } else if (t < 64){
        int k = t-48; float s=0.f;
        for (int j=16;j<32;j++) s += s0T[k][j];
        sd0[k] = s*(1.f/16.f);
    } else if (t < 70){
        int q = t-64; int half=q/3, c=q%3; float s=0.f;
        for (int i=half*16;i<half*16+16;i++) s += rs[i][c];
        rbar[half][c] = s*(1.f/16.f);
    }
    __syncthreads();

    // A4: pu0/pd0 (transposed) + layer-0 shared GEMV -> ws
    if (t < 64){
        int j = t & 31, half = t >> 5;
        float vx = rs[j][0]-rbar[half][0];
        float vy = rs[j][1]-rbar[half][1];
        float vz = rs[j][2]-rbar[half][2];
        float s=0.f; int base = half*16;
        for (int i=base;i<base+16;i++){
            if (i != j){
                float dx=rs[j][0]-rs[i][0];
                float dy=rs[j][1]-rs[i][1];
                float dz=rs[j][2]-rs[i][2];
                s += sqrtf(dx*dx+dy*dy+dz*dz);
            }
        }
        float (*dst)[32] = half ? pd0T : pu0T;
        dst[0][j]=vx; dst[1][j]=vy; dst[2][j]=vz; dst[3][j]=s*(1.f/16.f);
    }
    if (t >= 128 && t < 384){
        int n = t-128;
        float a0 = bs0[n];
        for (int k=0;k<16;k++){
            a0 += su0[k]*Ws0[k*256+n] + sd0[k]*Ws0[(16+k)*256+n];
        }
        wsw[6144+n] = a0;
    }
    __syncthreads();

    // export transposed feature blocks
    wsw[6400+t] = (&s0T[0][0])[t];
    if (t < 128) wsw[6912+t] = (&pu0T[0][0])[t];
    else if (t < 256) wsw[7040+(t-128)] = (&pd0T[0][0])[t-128];

    // ===== quarter loop: 4 x (256 pairs) through build + 2 updates + 3 means =====
    const int bpair = t >> 1;             // build: pair 0..255
    const int bfq   = (t & 1) * 16;       // build: feature half
    const int mf    = t & 31;             // means: feature
    const int mj0   = t >> 5;             // means: j base (0..15)
    const int ug    = t >> 3;             // update: pair group 0..63
    const int uf4   = (t & 7) * 4;        // update: feature base
#pragma unroll 1
    for (int qq = 0; qq < 4; ++qq){
        const int h = qq >> 1, q = qq & 1;
        // BUILD: px = tanh(wp0 . [dx,dy,dz,ln] + b)
        {
            const int jj = bpair & 31;
            const int ii = h*16 + q*8 + (bpair >> 5);
            float dx = rs[jj][0]-rs[ii][0];
            float dy = rs[jj][1]-rs[ii][1];
            float dz = rs[jj][2]-rs[ii][2];
            float ln = sqrtf(dx*dx+dy*dy+dz*dz);
#pragma unroll
            for (int c = 0; c < 4; ++c){
                int f0 = bfq + c*4;
                float4 w0 = *(const float4*)&wp0s[0][f0];
                float4 w1 = *(const float4*)&wp0s[1][f0];
                float4 w2 = *(const float4*)&wp0s[2][f0];
                float4 w3 = *(const float4*)&wp0s[3][f0];
                float4 bb = *(const float4*)&bp0s[f0];
                float4 v;
                v.x = tanh_fast(bb.x + dx*w0.x + dy*w1.x + dz*w2.x + ln*w3.x);
                v.y = tanh_fast(bb.y + dx*w0.y + dy*w1.y + dz*w2.y + ln*w3.y);
                v.z = tanh_fast(bb.z + dx*w0.z + dy*w1.z + dz*w2.z + ln*w3.z);
                v.w = tanh_fast(bb.w + dx*w0.w + dy*w1.w + dz*w2.w + ln*w3.w);
                *(float4*)&pxQ[bpair][f0] = v;
            }
        }
        __syncthreads();
#pragma unroll 1
        for (int s = 0; s < 3; ++s){
            // MEANS partial: pm[h*3+s][f][j] += (1/16) * sum_{iq} pxQ[iq*32+j][f]
            {
#pragma unroll
                for (int jr = 0; jr < 2; ++jr){
                    const int j = mj0 + jr*16;
                    float sacc = 0.f;
#pragma unroll
                    for (int iq = 0; iq < 8; ++iq)
                        sacc += pxQ[iq*32 + j][mf];
                    pm[h*3+s][mf][j] += sacc * (1.f/16.f);
                }
            }
            if (s < 2){
                const float (*wps)[32] = (s == 0) ? wp1s : wp2s;
                const float* bps = (s == 0) ? bp1s : bp2s;
                float acc[4][4];
                {
                    float4 bb = *(const float4*)&bps[uf4];
#pragma unroll
                    for (int j = 0; j < 4; ++j){
                        acc[j][0]=bb.x; acc[j][1]=bb.y; acc[j][2]=bb.z; acc[j][3]=bb.w;
                    }
                }
#pragma unroll
                for (int k4 = 0; k4 < 8; ++k4){
                    float4 w0 = *(const float4*)&wps[k4*4+0][uf4];
                    float4 w1 = *(const float4*)&wps[k4*4+1][uf4];
                    float4 w2 = *(const float4*)&wps[k4*4+2][uf4];
                    float4 w3 = *(const float4*)&wps[k4*4+3][uf4];
#pragma unroll
                    for (int j = 0; j < 4; ++j){
                        float4 p4 = *(const float4*)&pxQ[j*64 + ug][k4*4];
                        acc[j][0] += p4.x*w0.x + p4.y*w1.x + p4.z*w2.x + p4.w*w3.x;
                        acc[j][1] += p4.x*w0.y + p4.y*w1.y + p4.z*w2.y + p4.w*w3.y;
                        acc[j][2] += p4.x*w0.z + p4.y*w1.z + p4.z*w2.z + p4.w*w3.z;
                        acc[j][3] += p4.x*w0.w + p4.y*w1.w + p4.z*w2.w + p4.w*w3.w;
                    }
                }
                __syncthreads();
#pragma unroll
                for (int j = 0; j < 4; ++j){
                    float4 o = *(const float4*)&pxQ[j*64 + ug][uf4];
                    float4 v;
                    v.x = tanh_fast(acc[j][0]) + o.x;
                    v.y = tanh_fast(acc[j][1]) + o.y;
                    v.z = tanh_fast(acc[j][2]) + o.z;
                    v.w = tanh_fast(acc[j][3]) + o.w;
                    *(float4*)&pxQ[j*64 + ug][uf4] = v;
                }
                __syncthreads();
            } else {
                __syncthreads();   // pxQ reads done before next quarter's build
            }
        }
    }

    // export means -> ws (layout [h][s][f][j], j inner)
    {
        const float* pmf = &pm[0][0][0];
#pragma unroll
        for (int i = 0; i < 12; ++i){
            int idx = t + i*512;            // 0..6143
            int j  = idx & 31;
            int f  = (idx >> 5) & 31;
            int hs = idx >> 10;             // 0..5
            wsw[idx] = pmf[hs*1056 + f*33 + j];
        }
    }
}

// ---------------- kernel 2: single-stream phase (64-VGPR cap, 16 waves/CU) ---
__global__ __launch_bounds__(512) __attribute__((amdgpu_waves_per_eu(4,4)))
void fermi_smain(const float* __restrict__ Ws0,
                 const float* __restrict__ Ws1, const float* __restrict__ bs1,
                 const float* __restrict__ Ws2, const float* __restrict__ bs2,
                 const float* __restrict__ Ws3, const float* __restrict__ bs3,
                 const float* __restrict__ ws,  float* __restrict__ out)
{
    __shared__ __align__(16) float svT[256][36];      // [feat][electron], pad 36
    __shared__ __align__(16) float pmT[2][3][32][32]; // [h][s][f][j]
    __shared__ __align__(16) float su[256], sd[256];
    __shared__ __align__(16) float cpart[512];
    __shared__ __align__(16) float csh[256];
    __shared__ __align__(16) float s0T[16][32];
    __shared__ __align__(16) float pu0T[4][32];
    __shared__ __align__(16) float pd0T[4][32];
    __shared__ float envs[32];
    __shared__ float orb[2][16][17];
    __shared__ float red[2];

    const int t = threadIdx.x;
    const int b = blockIdx.x;
    const float* wsw = ws + 8224 + (size_t)b*7232;

    const int ln  = t & 63;
    const int wv  = t >> 6;
    const int e0  = ((ln >> 3) & 7) * 4;         // electron base
    const int n0g = wv*32 + (ln & 7)*4;          // col base

    // stage per-walker data
    {
        float* pmf = &pmT[0][0][0][0];
#pragma unroll
        for (int i=0;i<12;i++) pmf[t + i*512] = wsw[t + i*512];
        if (t < 256) csh[t] = wsw[6144+t];
        (&s0T[0][0])[t] = wsw[6400+t];
        if (t < 128) (&pu0T[0][0])[t] = wsw[6912+t];
        else if (t < 256) (&pd0T[0][0])[t-128] = wsw[7040+(t-128)];
        else if (t < 288) envs[t-256] = wsw[7168+(t-256)];
    }
    __syncthreads();

    // layer-0 GEMM (K=24) -> svT
    {
        float acc[4][4];
#pragma unroll
        for (int e=0;e<4;e++)
#pragma unroll
            for (int n=0;n<4;n++) acc[e][n] = csh[n0g+n];
#pragma unroll
        for (int rr=0; rr<4; ++rr){
            float4 w  = *(const float4*)(Ws0 + (32+rr)*256 + n0g);
            float4 Av = *(const float4*)&pu0T[rr][e0];
            ROWT(acc, Av, w);
        }
#pragma unroll
        for (int rr=0; rr<4; ++rr){
            float4 w  = *(const float4*)(Ws0 + (36+rr)*256 + n0g);
            float4 Av = *(const float4*)&pd0T[rr][e0];
            ROWT(acc, Av, w);
        }
#pragma unroll 2
        for (int rr=0; rr<16; ++rr){
            float4 w  = *(const float4*)(Ws0 + (40+rr)*256 + n0g);
            float4 Av = *(const float4*)&s0T[rr][e0];
            ROWT(acc, Av, w);
        }
#pragma unroll
        for (int n=0;n<4;n++){
            float4 v = { tanh_fast(acc[0][n]), tanh_fast(acc[1][n]),
                         tanh_fast(acc[2][n]), tanh_fast(acc[3][n]) };
            *(float4*)&svT[n0g+n][e0] = v;
        }
    }
    __syncthreads();

    // S loop: layers 1..3
#pragma unroll 1
    for (int l=1; l<=3; l++){
        const float* Wl = (l==1)?Ws1:(l==2)?Ws2:Ws3;
        const float* bl = (l==1)?bs1:(l==2)?bs2:bs3;

        if (t < 256){
            const float4* rowp = (const float4*)&svT[t][0];
            float4 a0=rowp[0], a1=rowp[1], a2=rowp[2], a3=rowp[3];
            float4 a4=rowp[4], a5=rowp[5], a6=rowp[6], a7=rowp[7];
            float s1 = (a0.x+a0.y+a0.z+a0.w)+(a1.x+a1.y+a1.z+a1.w)
                     + (a2.x+a2.y+a2.z+a2.w)+(a3.x+a3.y+a3.z+a3.w);
            float s2 = (a4.x+a4.y+a4.z+a4.w)+(a5.x+a5.y+a5.z+a5.w)
                     + (a6.x+a6.y+a6.z+a6.w)+(a7.x+a7.y+a7.z+a7.w);
            su[t] = s1*(1.f/16.f);
            sd[t] = s2*(1.f/16.f);
        }
        __syncthreads();

        {
            int h = t >> 8, n = t & 255;
            const float* Wb  = Wl + h*65536;
            const float* src = h ? sd : su;
            float a0 = h ? 0.f : bl[n];
#pragma unroll 8
            for (int k=0;k<256;k++) a0 += src[k]*Wb[k*256+n];
            cpart[h*256+n] = a0;
        }
        __syncthreads();
        if (t < 256) csh[t] = cpart[t] + cpart[256+t];
        __syncthreads();

        float acc[4][4];
#pragma unroll
        for (int e=0;e<4;e++)
#pragma unroll
            for (int n=0;n<4;n++) acc[e][n] = csh[n0g+n];
        {
            const float (*puA)[32] = pmT[0][l-1];
            const float (*pdA)[32] = pmT[1][l-1];
#pragma unroll 2
            for (int R=0; R<32; ++R){
                float4 w  = *(const float4*)(Wl + (512+R)*256 + n0g);
                float4 Av = *(const float4*)&puA[R][e0];
                ROWT(acc, Av, w);
            }
#pragma unroll 2
            for (int R=0; R<32; ++R){
                float4 w  = *(const float4*)(Wl + (544+R)*256 + n0g);
                float4 Av = *(const float4*)&pdA[R][e0];
                ROWT(acc, Av, w);
            }
        }
#pragma unroll 2
        for (int R=0; R<256; ++R){
            float4 w  = *(const float4*)(Wl + (576+R)*256 + n0g);
            float4 Av = *(const float4*)&svT[R][e0];
            ROWT(acc, Av, w);
        }
        __syncthreads();

#pragma unroll
        for (int n=0;n<4;n++){
            float4 o = *(const float4*)&svT[n0g+n][e0];
            float4 v = { tanh_fast(acc[0][n])+o.x, tanh_fast(acc[1][n])+o.y,
                         tanh_fast(acc[2][n])+o.z, tanh_fast(acc[3][n])+o.w };
            *(float4*)&svT[n0g+n][e0] = v;
        }
        __syncthreads();
    }

    // F1: orbitals via folded weights (2 halves x 16x16; Wc in ws[0..8224))
    {
        int half = t >> 8, il = (t >> 4) & 15, k16 = t & 15;
        int row = half*16 + il;
        const float* WcT = ws + half*4112;
        float a0 = WcT[4096 + k16];
#pragma unroll 8
        for (int m=0;m<256;m++) a0 += svT[m][row]*WcT[m*16+k16];
        orb[half][il][k16] = a0 * envs[row];
    }
    __syncthreads();

    // F2: 16x16 LU with partial pivoting, one wave per matrix
    {
        int w = t >> 6;
        if (w < 2){
            int lane = t & 63;
            float* M = &orb[w][0][0];   // row stride 17
            float ld_ = 0.f;
            for (int k=0;k<16;k++){
                float v = (lane>=k && lane<16) ? fabsf(M[lane*17+k]) : -1.f;
                int idx = lane;
                for (int off=32; off; off>>=1){
                    float ov = __shfl_xor(v, off);
                    int   oi = __shfl_xor(idx, off);
                    if (ov > v || (ov == v && oi < idx)){ v=ov; idx=oi; }
                }
                int p = idx;
                if (p != k && lane >= k && lane < 16){
                    float t1 = M[k*17+lane], t2 = M[p*17+lane];
                    M[k*17+lane] = t2; M[p*17+lane] = t1;
                }
                float piv = M[k*17+k];
                ld_ += logf(fabsf(piv));
                float inv = 1.f/piv;
                float rowkj = (lane<16) ? M[k*17+lane] : 0.f;
                if (lane > k && lane < 16){
                    for (int i=k+1;i<16;i++){
                        float mik = M[i*17+k]*inv;
                        M[i*17+lane] -= mik*rowkj;
                    }
                }
            }
            if (lane == 0) red[w] = ld_;
        }
    }
    __syncthreads();
    if (t == 0) out[b] = red[0] + red[1];
}

// ---------------- fused fallback: round-13 2-walker kernel (1443 us) --------
__global__ __launch_bounds__(512) __attribute__((amdgpu_waves_per_eu(2,2))) void fermi_fused(
    const float* __restrict__ r,   const float* __restrict__ A,
    const float* __restrict__ Ws0, const float* __restrict__ bs0,
    const float* __restrict__ Wp0, const float* __restrict__ bp0,
    const float* __restrict__ Ws1, const float* __restrict__ bs1,
    const float* __restrict__ Wp1, const float* __restrict__ bp1,
    const float* __restrict__ Ws2, const float* __restrict__ bs2,
    const float* __restrict__ Wp2, const float* __restrict__ bp2,
    const float* __restrict__ Ws3, const float* __restrict__ bs3,
    const float* __restrict__ Wc,  float* __restrict__ out)
{
    __shared__ __align__(16) float sv2[2][32][256];
    __shared__ __align__(16) float pmu2[2][3][32][32];
    __shared__ __align__(16) float pmd2[2][3][32][32];
    __shared__ __align__(16) float su2[2][256];
    __shared__ __align__(16) float sd2[2][256];
    __shared__ __align__(16) float pool[1536];
    __shared__ __align__(16) float wp0s[4][32];
    __shared__ __align__(16) float wp1s[32][32];
    __shared__ __align__(16) float wp2s[32][32];
    __shared__ __align__(16) float bp0s[32], bp1s[32], bp2s[32];
    __shared__ float rs2[2][32][3];
    __shared__ __align__(16) float s02[2][32][16];
    __shared__ float ralen2[2][32][4];
    __shared__ float envs2[2][32];
    __shared__ __align__(16) float pu02[2][32][4];
    __shared__ __align__(16) float pd02[2][32][4];
    __shared__ float su02[2][16], sd02[2][16];
    __shared__ float rbar2[2][2][3];
    __shared__ float red2[2][2];

    const int t = threadIdx.x;
    const int b = blockIdx.x;
    const int n0 = (t & 63) * 4;
    const int j0 = (t >> 6) * 4;
    float* cpart = pool;
    float* cshf  = pool + 1024;

    if (t < 192) (&rs2[0][0][0])[t] = r[(size_t)b*192 + t];
    if (t < 128) (&wp0s[0][0])[t] = Wp0[t];
    {
        float* w1 = &wp1s[0][0];
        w1[t]     = Wp1[t];
        w1[t+512] = Wp1[t+512];
        float* w2 = &wp2s[0][0];
        w2[t]     = Wp2[t];
        w2[t+512] = Wp2[t+512];
    }
    if (t >= 192 && t < 224) bp0s[t-192] = bp0[t-192];
    else if (t >= 224 && t < 256) bp1s[t-224] = bp1[t-224];
    else if (t >= 256 && t < 288) bp2s[t-256] = bp2[t-256];
    __syncthreads();

    if (t < 256){
        int wk = t >> 7, q = t & 127;
        int e = q >> 2, aa = q & 3;
        float dx = rs2[wk][e][0]-A[aa*3+0];
        float dy = rs2[wk][e][1]-A[aa*3+1];
        float dz = rs2[wk][e][2]-A[aa*3+2];
        float ln = sqrtf(dx*dx+dy*dy+dz*dz);
        s02[wk][e][aa*4+0]=dx; s02[wk][e][aa*4+1]=dy;
        s02[wk][e][aa*4+2]=dz; s02[wk][e][aa*4+3]=ln;
        ralen2[wk][e][aa]=ln;
    }
    __syncthreads();

    if (t < 64){
        int wk = t >> 5, e = t & 31;
        envs2[wk][e] = expf(-ralen2[wk][e][0])+expf(-ralen2[wk][e][1])
                     + expf(-ralen2[wk][e][2])+expf(-ralen2[wk][e][3]);
    } else if (t < 128){
        int q = t-64; int wk = q >> 5, half = (q >> 4) & 1, k = q & 15;
        float s = 0.f; int jb = half*16;
        for (int j=jb; j<jb+16; j++) s += s02[wk][j][k];
        (half ? sd02 : su02)[wk][k] = s*(1.f/16.f);
    } else if (t < 140){
        int q = t-128; int wk = q/6, rr_ = q%6, half = rr_/3, c = rr_%3;
        float s=0.f;
        for (int i=half*16;i<half*16+16;i++) s += rs2[wk][i][c];
        rbar2[wk][half][c] = s*(1.f/16.f);
    }
    __syncthreads();

    if (t < 128){
        int wk = t >> 6, q = t & 63;
        int j = q & 31, half = q >> 5;
        float* dst = (half ? pd02 : pu02)[wk][j];
        dst[0] = rs2[wk][j][0]-rbar2[wk][half][0];
        dst[1] = rs2[wk][j][1]-rbar2[wk][half][1];
        dst[2] = rs2[wk][j][2]-rbar2[wk][half][2];
        float s=0.f; int base = half*16;
        for (int i=base;i<base+16;i++){
            if (i != j){
                float dx=rs2[wk][j][0]-rs2[wk][i][0];
                float dy=rs2[wk][j][1]-rs2[wk][i][1];
                float dz=rs2[wk][j][2]-rs2[wk][i][2];
                s += sqrtf(dx*dx+dy*dy+dz*dz);
            }
        }
        dst[3] = s*(1.f/16.f);
    }
    {
        int wk = t >> 8, n = t & 255;
        float a0 = bs0[n];
        for (int k=0;k<16;k++){
            a0 += su02[wk][k]*Ws0[k*256+n] + sd02[wk][k]*Ws0[(16+k)*256+n];
        }
        cshf[wk*256+n] = a0;
    }
    __syncthreads();

    {
        const int i1  = t & 15;
        const int jj4 = (t >> 4) & 15;
        const int wkp = t >> 8;
#pragma unroll 1
        for (int pass=0; pass<4; ++pass){
            const int h   = pass >> 1;
            const int jjs = jj4 + (pass & 1)*16;
            const int ii  = i1 + h*16;
            float px[32];
            {
                float dx = rs2[wkp][jjs][0]-rs2[wkp][ii][0];
                float dy = rs2[wkp][jjs][1]-rs2[wkp][ii][1];
                float dz = rs2[wkp][jjs][2]-rs2[wkp][ii][2];
                float ln = sqrtf(dx*dx+dy*dy+dz*dz);
#pragma unroll
                for (int c=0; c<8; c++){
                    float4 w0 = ((const float4*)wp0s[0])[c];
                    float4 w1 = ((const float4*)wp0s[1])[c];
                    float4 w2 = ((const float4*)wp0s[2])[c];
                    float4 w3 = ((const float4*)wp0s[3])[c];
                    float4 bb = ((const float4*)bp0s)[c];
                    px[c*4+0] = tanh_fast(bb.x + dx*w0.x + dy*w1.x + dz*w2.x + ln*w3.x);
                    px[c*4+1] = tanh_fast(bb.y + dx*w0.y + dy*w1.y + dz*w2.y + ln*w3.y);
                    px[c*4+2] = tanh_fast(bb.z + dx*w0.z + dy*w1.z + dz*w2.z + ln*w3.z);
                    px[c*4+3] = tanh_fast(bb.w + dx*w0.w + dy*w1.w + dz*w2.w + ln*w3.w);
                }
            }
            float (*pm)[32][32] = h ? pmd2[wkp] : pmu2[wkp];
#pragma unroll 1
            for (int s=0; s<3; ++s){
#pragma unroll
                for (int f=0; f<32; f++){
                    float a_ = px[f];
                    a_ += __shfl_xor(a_,1); a_ += __shfl_xor(a_,2);
                    a_ += __shfl_xor(a_,4); a_ += __shfl_xor(a_,8);
                    if (i1 == 0) pm[s][jjs][f] = a_*(1.f/16.f);
                }
                if (s == 0)      pair_update(px, wp1s, bp1s);
                else if (s == 1) pair_update(px, wp2s, bp2s);
            }
        }
    }
    __syncthreads();

    {
        float acc0[4][4], acc1[4][4];
#pragma unroll
        for (int e=0;e<4;e++)
#pragma unroll
            for (int n=0;n<4;n++){ acc0[e][n] = cshf[n0+n]; acc1[e][n] = cshf[256+n0+n]; }
        {
            float4 A0 = *(const float4*)pu02[0][j0+0];
            float4 A1 = *(const float4*)pu02[0][j0+1];
            float4 A2 = *(const float4*)pu02[0][j0+2];
            float4 A3 = *(const float4*)pu02[0][j0+3];
            float4 B0 = *(const float4*)pu02[1][j0+0];
            float4 B1 = *(const float4*)pu02[1][j0+1];
            float4 B2 = *(const float4*)pu02[1][j0+2];
            float4 B3 = *(const float4*)pu02[1][j0+3];
            G4D(Ws0, 32, A0,A1,A2,A3, B0,B1,B2,B3);
            A0 = *(const float4*)pd02[0][j0+0];
            A1 = *(const float4*)pd02[0][j0+1];
            A2 = *(const float4*)pd02[0][j0+2];
            A3 = *(const float4*)pd02[0][j0+3];
            B0 = *(const float4*)pd02[1][j0+0];
            B1 = *(const float4*)pd02[1][j0+1];
            B2 = *(const float4*)pd02[1][j0+2];
            B3 = *(const float4*)pd02[1][j0+3];
            G4D(Ws0, 36, A0,A1,A2,A3, B0,B1,B2,B3);
        }
#pragma unroll
        for (int k4=0;k4<4;k4++){
            float4 A0 = ((const float4*)s02[0][j0+0])[k4];
            float4 A1 = ((const float4*)s02[0][j0+1])[k4];
            float4 A2 = ((const float4*)s02[0][j0+2])[k4];
            float4 A3 = ((const float4*)s02[0][j0+3])[k4];
            float4 B0 = ((const float4*)s02[1][j0+0])[k4];
            float4 B1 = ((const float4*)s02[1][j0+1])[k4];
            float4 B2 = ((const float4*)s02[1][j0+2])[k4];
            float4 B3 = ((const float4*)s02[1][j0+3])[k4];
            G4D(Ws0, 40+k4*4, A0,A1,A2,A3, B0,B1,B2,B3);
        }
#pragma unroll
        for (int e=0;e<4;e++)
#pragma unroll
            for (int n=0;n<4;n++){
                sv2[0][j0+e][n0+n] = tanh_fast(acc0[e][n]);
                sv2[1][j0+e][n0+n] = tanh_fast(acc1[e][n]);
            }
    }
    __syncthreads();

#pragma unroll 1
    for (int l=1; l<=3; l++){
        const float* Wl  = (l==1)?Ws1:(l==2)?Ws2:Ws3;
        const float* bl  = (l==1)?bs1:(l==2)?bs2:bs3;

        {
            int wk = t >> 8, k = t & 255;
            float s1=0.f, s2=0.f;
            for (int j=0;j<16;j++)  s1 += sv2[wk][j][k];
            for (int j=16;j<32;j++) s2 += sv2[wk][j][k];
            su2[wk][k] = s1*(1.f/16.f);
            sd2[wk][k] = s2*(1.f/16.f);
        }
        __syncthreads();

        {
            int h = t >> 8, n = t & 255;
            const float* Wb = Wl + h*65536;
            const float* sA = h ? sd2[0] : su2[0];
            const float* sB = h ? sd2[1] : su2[1];
            float a0 = h ? 0.f : bl[n];
            float a1 = a0;
#pragma unroll 8
            for (int k=0;k<256;k++){
                float wv = Wb[k*256+n];
                a0 += sA[k]*wv; a1 += sB[k]*wv;
            }
            cpart[(0*2+h)*256+n] = a0;
            cpart[(1*2+h)*256+n] = a1;
        }
        __syncthreads();
        {
            int wk = t >> 8, n = t & 255;
            cshf[wk*256+n] = cpart[(wk*2+0)*256+n] + cpart[(wk*2+1)*256+n];
        }
        __syncthreads();

        float acc0[4][4], acc1[4][4];
#pragma unroll
        for (int e=0;e<4;e++)
#pragma unroll
            for (int n=0;n<4;n++){ acc0[e][n] = cshf[n0+n]; acc1[e][n] = cshf[256+n0+n]; }
        const float* puA = &pmu2[0][l-1][0][0];
        const float* puB = &pmu2[1][l-1][0][0];
        const float* pdA = &pmd2[0][l-1][0][0];
        const float* pdB = &pmd2[1][l-1][0][0];
#pragma unroll
        for (int k4=0;k4<8;k4++){
            float4 A0 = ((const float4*)(puA + (j0+0)*32))[k4];
            float4 A1 = ((const float4*)(puA + (j0+1)*32))[k4];
            float4 A2 = ((const float4*)(puA + (j0+2)*32))[k4];
            float4 A3 = ((const float4*)(puA + (j0+3)*32))[k4];
            float4 B0 = ((const float4*)(puB + (j0+0)*32))[k4];
            float4 B1 = ((const float4*)(puB + (j0+1)*32))[k4];
            float4 B2 = ((const float4*)(puB + (j0+2)*32))[k4];
            float4 B3 = ((const float4*)(puB + (j0+3)*32))[k4];
            G4D(Wl, 512+k4*4, A0,A1,A2,A3, B0,B1,B2,B3);
        }
#pragma unroll
        for (int k4=0;k4<8;k4++){
            float4 A0 = ((const float4*)(pdA + (j0+0)*32))[k4];
            float4 A1 = ((const float4*)(pdA + (j0+1)*32))[k4];
            float4 A2 = ((const float4*)(pdA + (j0+2)*32))[k4];
            float4 A3 = ((const float4*)(pdA + (j0+3)*32))[k4];
            float4 B0 = ((const float4*)(pdB + (j0+0)*32))[k4];
            float4 B1 = ((const float4*)(pdB + (j0+1)*32))[k4];
            float4 B2 = ((const float4*)(pdB + (j0+2)*32))[k4];
            float4 B3 = ((const float4*)(pdB + (j0+3)*32))[k4];
            G4D(Wl, 544+k4*4, A0,A1,A2,A3, B0,B1,B2,B3);
        }
        {
            const float* WbP = Wl + 576*256 + n0;
            float4 wn0 = *(const float4*)(WbP);
            float4 wn1 = *(const float4*)(WbP + 256);
            float4 wn2 = *(const float4*)(WbP + 512);
            float4 wn3 = *(const float4*)(WbP + 768);
#pragma unroll 1
            for (int k4=0;k4<64;k4++){
                float4 w0=wn0, w1=wn1, w2=wn2, w3=wn3;
                {
                    int kn = (k4 < 63) ? (k4+1) : 63;
                    const float* Wn = WbP + kn*1024;
                    wn0 = *(const float4*)(Wn);
                    wn1 = *(const float4*)(Wn + 256);
                    wn2 = *(const float4*)(Wn + 512);
                    wn3 = *(const float4*)(Wn + 768);
                }
                float4 A0 = ((const float4*)sv2[0][j0+0])[k4];
                float4 A1 = ((const float4*)sv2[0][j0+1])[k4];
                float4 A2 = ((const float4*)sv2[0][j0+2])[k4];
                float4 A3 = ((const float4*)sv2[0][j0+3])[k4];
                float4 B0 = ((const float4*)sv2[1][j0+0])[k4];
                float4 B1 = ((const float4*)sv2[1][j0+1])[k4];
                float4 B2 = ((const float4*)sv2[1][j0+2])[k4];
                float4 B3 = ((const float4*)sv2[1][j0+3])[k4];
                G4P(w0,w1,w2,w3, A0,A1,A2,A3, B0,B1,B2,B3);
            }
        }
        __syncthreads();

#pragma unroll
        for (int e=0;e<4;e++)
#pragma unroll
            for (int n=0;n<4;n++){
                float o0 = sv2[0][j0+e][n0+n];
                float o1 = sv2[1][j0+e][n0+n];
                sv2[0][j0+e][n0+n] = tanh_fast(acc0[e][n]) + o0;
                sv2[1][j0+e][n0+n] = tanh_fast(acc1[e][n]) + o1;
            }
        __syncthreads();
    }

#pragma unroll 1
    for (int rep=0; rep<2; ++rep){
        int idx = t + rep*512;
        int wk = idx >> 9, rem = idx & 511;
        int half = rem >> 8, il = (rem >> 4) & 15, k16 = rem & 15;
        int row = half*16 + il;
        const float* WcT = Wc + half*4112;
        float a0 = WcT[4096 + k16];
#pragma unroll 8
        for (int m=0;m<256;m++) a0 += sv2[wk][row][m]*WcT[m*16+k16];
        pool[(wk*2+half)*272 + il*17 + k16] = a0 * envs2[wk][row];
    }
    __syncthreads();

    {
        int w = t >> 6;
        if (w < 4){
            int lane = t & 63;
            float* M = pool + w*272;
            float ld_ = 0.f;
            for (int k=0;k<16;k++){
                float v = (lane>=k && lane<16) ? fabsf(M[lane*17+k]) : -1.f;
                int idx = lane;
                for (int off=32; off; off>>=1){
                    float ov = __shfl_xor(v, off);
                    int   oi = __shfl_xor(idx, off);
                    if (ov > v || (ov == v && oi < idx)){ v=ov; idx=oi; }
                }
                int p = idx;
                if (p != k && lane >= k && lane < 16){
                    float t1 = M[k*17+lane], t2 = M[p*17+lane];
                    M[k*17+lane] = t2; M[p*17+lane] = t1;
                }
                float piv = M[k*17+k];
                ld_ += logf(fabsf(piv));
                float inv = 1.f/piv;
                float rowkj = (lane<16) ? M[k*17+lane] : 0.f;
                if (lane > k && lane < 16){
                    for (int i=k+1;i<16;i++){
                        float mik = M[i*17+k]*inv;
                        M[i*17+lane] -= mik*rowkj;
                    }
                }
            }
            if (lane == 0) red2[w>>1][w&1] = ld_;
        }
    }
    __syncthreads();
    if (t < 2) out[2*b + t] = red2[t][0] + red2[t][1];
}

extern "C" void kernel_launch(void* const* d_in, const int* in_sizes, int n_in,
                              void* d_out, int out_size, void* d_ws, size_t ws_size,
                              hipStream_t stream) {
    const float* r   = (const float*)d_in[0];
    const float* a   = (const float*)d_in[1];
    const float* Ws0 = (const float*)d_in[2];  const float* bs0 = (const float*)d_in[3];
    const float* Wp0 = (const float*)d_in[4];  const float* bp0 = (const float*)d_in[5];
    const float* Ws1 = (const float*)d_in[6];  const float* bs1 = (const float*)d_in[7];
    const float* Wp1 = (const float*)d_in[8];  const float* bp1 = (const float*)d_in[9];
    const float* Ws2 = (const float*)d_in[10]; const float* bs2 = (const float*)d_in[11];
    const float* Wp2 = (const float*)d_in[12]; const float* bp2 = (const float*)d_in[13];
    const float* Ws3 = (const float*)d_in[14]; const float* bs3 = (const float*)d_in[15];
    const float* Wu  = (const float*)d_in[16]; const float* bu  = (const float*)d_in[17];
    const float* Wd  = (const float*)d_in[18]; const float* bd  = (const float*)d_in[19];
    const float* Wwu = (const float*)d_in[20]; const float* bwu = (const float*)d_in[21];
    const float* Wwd = (const float*)d_in[22]; const float* bwd = (const float*)d_in[23];
    float* ws = (float*)d_ws;
    float* out = (float*)d_out;

    const int B = out_size;
    const size_t need = ((size_t)8224 + (size_t)B*7232) * 4;

    fermi_prep<<<1, 512, 0, stream>>>(Wu, bu, Wd, bd, Wwu, bwu, Wwd, bwd, ws);
    if (ws_size >= need){
        fermi_pair<<<B, 512, 0, stream>>>(r, a, Ws0, bs0, Wp0, bp0,
                                          Wp1, bp1, Wp2, bp2, ws);
        fermi_smain<<<B, 512, 0, stream>>>(Ws0, Ws1, bs1, Ws2, bs2, Ws3, bs3, ws, out);
    } else {
        fermi_fused<<<B/2, 512, 0, stream>>>(r, a, Ws0, bs0, Wp0, bp0,
                                             Ws1, bs1, Wp1, bp1,
                                             Ws2, bs2, Wp2, bp2,
                                             Ws3, bs3, ws, out);
    }
}

// Round 17
// 1077.607 us; speedup vs baseline: 1.6649x; 1.0258x over previous
//
#include <hip/hip_runtime.h>
#include <hip/hip_bf16.h>

__device__ __forceinline__ float tanh_fast(float x){
    float e = __expf(2.0f*x);
    return 1.0f - 2.0f/(e + 1.0f);
}

// one GEMM row: A_ = 4 electrons (transposed activations), W_ = 4 cols; acc[e][n]
#define ROWT(ACC, A_, W_) do{                                     \
    ACC[0][0] += (A_).x*(W_).x; ACC[0][1] += (A_).x*(W_).y;       \
    ACC[0][2] += (A_).x*(W_).z; ACC[0][3] += (A_).x*(W_).w;       \
    ACC[1][0] += (A_).y*(W_).x; ACC[1][1] += (A_).y*(W_).y;       \
    ACC[1][2] += (A_).y*(W_).z; ACC[1][3] += (A_).y*(W_).w;       \
    ACC[2][0] += (A_).z*(W_).x; ACC[2][1] += (A_).z*(W_).y;       \
    ACC[2][2] += (A_).z*(W_).z; ACC[2][3] += (A_).z*(W_).w;       \
    ACC[3][0] += (A_).w*(W_).x; ACC[3][1] += (A_).w*(W_).y;       \
    ACC[3][2] += (A_).w*(W_).z; ACC[3][3] += (A_).w*(W_).w;       \
}while(0)

// ---- macros for the fused fallback (round-13 2-walker kernel) ----
#define FMA16A(ACC, W_, A_, B_, C_, D_) do{                      \
    ACC[0][0] += (A_)*(W_).x; ACC[0][1] += (A_)*(W_).y;          \
    ACC[0][2] += (A_)*(W_).z; ACC[0][3] += (A_)*(W_).w;          \
    ACC[1][0] += (B_)*(W_).x; ACC[1][1] += (B_)*(W_).y;          \
    ACC[1][2] += (B_)*(W_).z; ACC[1][3] += (B_)*(W_).w;          \
    ACC[2][0] += (C_)*(W_).x; ACC[2][1] += (C_)*(W_).y;          \
    ACC[2][2] += (C_)*(W_).z; ACC[2][3] += (C_)*(W_).w;          \
    ACC[3][0] += (D_)*(W_).x; ACC[3][1] += (D_)*(W_).y;          \
    ACC[3][2] += (D_)*(W_).z; ACC[3][3] += (D_)*(W_).w;          \
}while(0)

#define ROW2(Wb, R_, c_, A0,A1,A2,A3, B0,B1,B2,B3) do{                        \
    float4 w_ = *(const float4*)((Wb) + (R_)*256 + n0);                       \
    FMA16A(acc0, w_, (A0).c_,(A1).c_,(A2).c_,(A3).c_);                        \
    FMA16A(acc1, w_, (B0).c_,(B1).c_,(B2).c_,(B3).c_);                        \
}while(0)

#define G4D(Wb, R0, A0,A1,A2,A3, B0,B1,B2,B3) do{                \
    ROW2(Wb, (R0)+0, x, A0,A1,A2,A3, B0,B1,B2,B3);               \
    ROW2(Wb, (R0)+1, y, A0,A1,A2,A3, B0,B1,B2,B3);               \
    ROW2(Wb, (R0)+2, z, A0,A1,A2,A3, B0,B1,B2,B3);               \
    ROW2(Wb, (R0)+3, w, A0,A1,A2,A3, B0,B1,B2,B3);               \
}while(0)

#define G4P(w0,w1,w2,w3, A0,A1,A2,A3, B0,B1,B2,B3) do{                                   \
    FMA16A(acc0, w0, (A0).x,(A1).x,(A2).x,(A3).x);                                       \
    FMA16A(acc1, w0, (B0).x,(B1).x,(B2).x,(B3).x);                                       \
    FMA16A(acc0, w1, (A0).y,(A1).y,(A2).y,(A3).y);                                       \
    FMA16A(acc1, w1, (B0).y,(B1).y,(B2).y,(B3).y);                                       \
    FMA16A(acc0, w2, (A0).z,(A1).z,(A2).z,(A3).z);                                       \
    FMA16A(acc1, w2, (B0).z,(B1).z,(B2).z,(B3).z);                                       \
    FMA16A(acc0, w3, (A0).w,(A1).w,(A2).w,(A3).w);                                       \
    FMA16A(acc1, w3, (B0).w,(B1).w,(B2).w,(B3).w);                                       \
}while(0)

// register-array pair update (used only by the fused fallback)
__device__ __forceinline__ void pair_update(float (&px)[32], const float (*wp)[32], const float* bpb){
    float a2[32];
#pragma unroll
    for (int f=0;f<32;f++) a2[f] = bpb[f];
#pragma unroll 4
    for (int k=0;k<32;k++){
        float xk = px[k];
        const float4* wr = (const float4*)wp[k];
#pragma unroll
        for (int c=0;c<8;c++){
            float4 w = wr[c];
            a2[c*4+0] += xk*w.x; a2[c*4+1] += xk*w.y;
            a2[c*4+2] += xk*w.z; a2[c*4+3] += xk*w.w;
        }
    }
#pragma unroll
    for (int f=0;f<32;f++) px[f] = tanh_fast(a2[f]) + px[f];
}

// ---------------- prep: Wcu = Wu@Wwu, bcu = bu@Wwu+bwu; same for down spin ----
// ws layout (floats): [0,4096) Wcu  [4096,4112) bcu  [4112,8208) Wcd  [8208,8224) bcd
__global__ __launch_bounds__(512) void fermi_prep(
    const float* __restrict__ Wu, const float* __restrict__ bu,
    const float* __restrict__ Wd, const float* __restrict__ bd,
    const float* __restrict__ Wwu, const float* __restrict__ bwu,
    const float* __restrict__ Wwd, const float* __restrict__ bwd,
    float* __restrict__ ws)
{
    const int t = threadIdx.x;
    const int m = t & 255;
    const int half = t >> 8;
    const float* Wbig = half ? Wd : Wu;
    const float* Wsm  = half ? Wwd : Wwu;
    float acc[16];
#pragma unroll
    for (int k=0;k<16;k++) acc[k]=0.f;
    for (int h=0; h<128; h++){
        float wv = Wbig[m*128+h];
        const float4* wr = (const float4*)(Wsm + h*16);
        float4 a0=wr[0], a1=wr[1], a2=wr[2], a3=wr[3];
        acc[0]+=wv*a0.x; acc[1]+=wv*a0.y; acc[2]+=wv*a0.z; acc[3]+=wv*a0.w;
        acc[4]+=wv*a1.x; acc[5]+=wv*a1.y; acc[6]+=wv*a1.z; acc[7]+=wv*a1.w;
        acc[8]+=wv*a2.x; acc[9]+=wv*a2.y; acc[10]+=wv*a2.z; acc[11]+=wv*a2.w;
        acc[12]+=wv*a3.x; acc[13]+=wv*a3.y; acc[14]+=wv*a3.z; acc[15]+=wv*a3.w;
    }
    float* dst = ws + half*4112;
#pragma unroll
    for (int k=0;k<16;k++) dst[m*16+k]=acc[k];
    if (m < 16){
        const float* bbig = half ? bd : bu;
        float b2 = half ? bwd[m] : bwu[m];
        for (int h=0;h<128;h++) b2 += bbig[h]*Wsm[h*16+m];
        dst[4096+m] = b2;
    }
}

// ---------------- kernel 1: features + pair phase, LDS-resident pair state ---
// per-walker ws block (stride 7232 floats, base 8224 + b*7232):
//  +0 pmuT[3][32][32]  +3072 pmdT[3][32][32]  +6144 csh[256]  +6400 s0T[16][32]
//  +6912 pu0T[4][32]   +7040 pd0T[4][32]      +7168 envs[32]
__global__ __launch_bounds__(512) __attribute__((amdgpu_waves_per_eu(4,4)))
void fermi_pair(const float* __restrict__ r,   const float* __restrict__ A,
                const float* __restrict__ Ws0, const float* __restrict__ bs0,
                const float* __restrict__ Wp0, const float* __restrict__ bp0,
                const float* __restrict__ Wp1, const float* __restrict__ bp1,
                const float* __restrict__ Wp2, const float* __restrict__ bp2,
                float* __restrict__ ws)
{
    __shared__ __align__(16) float pxQ[256][36];      // quarter pair state [p][f]
    __shared__ __align__(16) float pm[6][32][33];     // means acc [(h*3+s)][f][j]
    __shared__ __align__(16) float wp0s[4][32];
    __shared__ __align__(16) float wp1s[32][32];
    __shared__ __align__(16) float wp2s[32][32];
    __shared__ __align__(16) float bp0s[32], bp1s[32], bp2s[32];
    __shared__ float rs[32][3];
    __shared__ __align__(16) float s0T[16][32];
    __shared__ float ralen[32][4];
    __shared__ __align__(16) float pu0T[4][32];
    __shared__ __align__(16) float pd0T[4][32];
    __shared__ float su0[16], sd0[16];
    __shared__ float rbar[2][3];

    const int t = threadIdx.x;
    const int b = blockIdx.x;
    float* wsw = ws + 8224 + (size_t)b*7232;

    // A1 staging
    if (t < 96) rs[t/3][t%3] = r[(size_t)b*96 + t];
    if (t < 128) (&wp0s[0][0])[t] = Wp0[t];
    {
        float* w1 = &wp1s[0][0];
        w1[t]     = Wp1[t];
        w1[t+512] = Wp1[t+512];
        float* w2 = &wp2s[0][0];
        w2[t]     = Wp2[t];
        w2[t+512] = Wp2[t+512];
    }
    if (t >= 128 && t < 160) bp0s[t-128] = bp0[t-128];
    else if (t >= 160 && t < 192) bp1s[t-160] = bp1[t-160];
    else if (t >= 192 && t < 224) bp2s[t-192] = bp2[t-192];
    {   // zero the means accumulator (6*32*33 = 6336 floats)
        float* pmf = &pm[0][0][0];
        for (int i = t; i < 6336; i += 512) pmf[i] = 0.f;
    }
    __syncthreads();

    // A2: electron-atom features (transposed)
    if (t < 128){
        int e = t >> 2, aa = t & 3;
        float dx = rs[e][0]-A[aa*3+0];
        float dy = rs[e][1]-A[aa*3+1];
        float dz = rs[e][2]-A[aa*3+2];
        float ln = sqrtf(dx*dx+dy*dy+dz*dz);
        s0T[aa*4+0][e]=dx; s0T[aa*4+1][e]=dy;
        s0T[aa*4+2][e]=dz; s0T[aa*4+3][e]=ln;
        ralen[e][aa]=ln;
    }
    __syncthreads();

    // A3: envs -> ws, su0/sd0, rbar
    if (t < 32){
        wsw[7168+t] = expf(-ralen[t][0])+expf(-ralen[t][1])+expf(-ralen[t][2])+expf(-ralen[t][3]);
    } else if (t < 48){
        int k = t-32; float s=0.f;
        for (int j=0;j<16;j++) s += s0T[k][j];
        su0[k] = s*(1.f/16.f);
    } else if (t < 64){
        int k = t-48; float s=0.f;
        for (int j=16;j<32;j++) s += s0T[k][j];
        sd0[k] = s*(1.f/16.f);
    } else if (t < 70){
        int q = t-64; int half=q/3, c=q%3; float s=0.f;
        for (int i=half*16;i<half*16+16;i++) s += rs[i][c];
        rbar[half][c] = s*(1.f/16.f);
    }
    __syncthreads();

    // A4: pu0/pd0 (transposed) + layer-0 shared GEMV -> ws
    if (t < 64){
        int j = t & 31, half = t >> 5;
        float vx = rs[j][0]-rbar[half][0];
        float vy = rs[j][1]-rbar[half][1];
        float vz = rs[j][2]-rbar[half][2];
        float s=0.f; int base = half*16;
        for (int i=base;i<base+16;i++){
            if (i != j){
                float dx=rs[j][0]-rs[i][0];
                float dy=rs[j][1]-rs[i][1];
                float dz=rs[j][2]-rs[i][2];
                s += sqrtf(dx*dx+dy*dy+dz*dz);
            }
        }
        float (*dst)[32] = half ? pd0T : pu0T;
        dst[0][j]=vx; dst[1][j]=vy; dst[2][j]=vz; dst[3][j]=s*(1.f/16.f);
    }
    if (t >= 128 && t < 384){
        int n = t-128;
        float a0 = bs0[n];
        for (int k=0;k<16;k++){
            a0 += su0[k]*Ws0[k*256+n] + sd0[k]*Ws0[(16+k)*256+n];
        }
        wsw[6144+n] = a0;
    }
    __syncthreads();

    // export transposed feature blocks
    wsw[6400+t] = (&s0T[0][0])[t];
    if (t < 128) wsw[6912+t] = (&pu0T[0][0])[t];
    else if (t < 256) wsw[7040+(t-128)] = (&pd0T[0][0])[t-128];

    // ===== quarter loop: 4 x (256 pairs) through build + 2 updates + 3 means =====
    const int bpair = t >> 1;             // build: pair 0..255
    const int bfq   = (t & 1) * 16;       // build: feature half
    const int mf    = t & 31;             // means: feature
    const int mj0   = t >> 5;             // means: j base (0..15)
    const int ug    = t >> 3;             // update: pair group 0..63
    const int uf4   = (t & 7) * 4;        // update: feature base
#pragma unroll 1
    for (int qq = 0; qq < 4; ++qq){
        const int h = qq >> 1, q = qq & 1;
        // BUILD: px = tanh(wp0 . [dx,dy,dz,ln] + b)
        {
            const int jj = bpair & 31;
            const int ii = h*16 + q*8 + (bpair >> 5);
            float dx = rs[jj][0]-rs[ii][0];
            float dy = rs[jj][1]-rs[ii][1];
            float dz = rs[jj][2]-rs[ii][2];
            float ln = sqrtf(dx*dx+dy*dy+dz*dz);
#pragma unroll
            for (int c = 0; c < 4; ++c){
                int f0 = bfq + c*4;
                float4 w0 = *(const float4*)&wp0s[0][f0];
                float4 w1 = *(const float4*)&wp0s[1][f0];
                float4 w2 = *(const float4*)&wp0s[2][f0];
                float4 w3 = *(const float4*)&wp0s[3][f0];
                float4 bb = *(const float4*)&bp0s[f0];
                float4 v;
                v.x = tanh_fast(bb.x + dx*w0.x + dy*w1.x + dz*w2.x + ln*w3.x);
                v.y = tanh_fast(bb.y + dx*w0.y + dy*w1.y + dz*w2.y + ln*w3.y);
                v.z = tanh_fast(bb.z + dx*w0.z + dy*w1.z + dz*w2.z + ln*w3.z);
                v.w = tanh_fast(bb.w + dx*w0.w + dy*w1.w + dz*w2.w + ln*w3.w);
                *(float4*)&pxQ[bpair][f0] = v;
            }
        }
        __syncthreads();
#pragma unroll 1
        for (int s = 0; s < 3; ++s){
            // MEANS partial: pm[h*3+s][f][j] += (1/16) * sum_{iq} pxQ[iq*32+j][f]
            {
#pragma unroll
                for (int jr = 0; jr < 2; ++jr){
                    const int j = mj0 + jr*16;
                    float sacc = 0.f;
#pragma unroll
                    for (int iq = 0; iq < 8; ++iq)
                        sacc += pxQ[iq*32 + j][mf];
                    pm[h*3+s][mf][j] += sacc * (1.f/16.f);
                }
            }
            if (s < 2){
                const float (*wps)[32] = (s == 0) ? wp1s : wp2s;
                const float* bps = (s == 0) ? bp1s : bp2s;
                float acc[4][4];
                {
                    float4 bb = *(const float4*)&bps[uf4];
#pragma unroll
                    for (int j = 0; j < 4; ++j){
                        acc[j][0]=bb.x; acc[j][1]=bb.y; acc[j][2]=bb.z; acc[j][3]=bb.w;
                    }
                }
#pragma unroll
                for (int k4 = 0; k4 < 8; ++k4){
                    float4 w0 = *(const float4*)&wps[k4*4+0][uf4];
                    float4 w1 = *(const float4*)&wps[k4*4+1][uf4];
                    float4 w2 = *(const float4*)&wps[k4*4+2][uf4];
                    float4 w3 = *(const float4*)&wps[k4*4+3][uf4];
#pragma unroll
                    for (int j = 0; j < 4; ++j){
                        float4 p4 = *(const float4*)&pxQ[j*64 + ug][k4*4];
                        acc[j][0] += p4.x*w0.x + p4.y*w1.x + p4.z*w2.x + p4.w*w3.x;
                        acc[j][1] += p4.x*w0.y + p4.y*w1.y + p4.z*w2.y + p4.w*w3.y;
                        acc[j][2] += p4.x*w0.z + p4.y*w1.z + p4.z*w2.z + p4.w*w3.z;
                        acc[j][3] += p4.x*w0.w + p4.y*w1.w + p4.z*w2.w + p4.w*w3.w;
                    }
                }
                __syncthreads();
#pragma unroll
                for (int j = 0; j < 4; ++j){
                    float4 o = *(const float4*)&pxQ[j*64 + ug][uf4];
                    float4 v;
                    v.x = tanh_fast(acc[j][0]) + o.x;
                    v.y = tanh_fast(acc[j][1]) + o.y;
                    v.z = tanh_fast(acc[j][2]) + o.z;
                    v.w = tanh_fast(acc[j][3]) + o.w;
                    *(float4*)&pxQ[j*64 + ug][uf4] = v;
                }
                __syncthreads();
            } else {
                __syncthreads();   // pxQ reads done before next quarter's build
            }
        }
    }

    // export means -> ws (layout [h][s][f][j], j inner)
    {
        const float* pmf = &pm[0][0][0];
#pragma unroll
        for (int i = 0; i < 12; ++i){
            int idx = t + i*512;            // 0..6143
            int j  = idx & 31;
            int f  = (idx >> 5) & 31;
            int hs = idx >> 10;             // 0..5
            wsw[idx] = pmf[hs*1056 + f*33 + j];
        }
    }
}

// ---------------- kernel 2: single-stream phase (64-VGPR cap, 16 waves/CU) ---
// NEW (round 17): depth-2 rolling weight prefetch (w0/w1) across the unified
// contiguous 320-row weight stream (rows 512..831) — keeps 2 global loads in
// flight so the ~200-cycle L2 latency is covered by 2 rows x 16 FMA x 4 waves.
__global__ __launch_bounds__(512) __attribute__((amdgpu_waves_per_eu(4,4)))
void fermi_smain(const float* __restrict__ Ws0,
                 const float* __restrict__ Ws1, const float* __restrict__ bs1,
                 const float* __restrict__ Ws2, const float* __restrict__ bs2,
                 const float* __restrict__ Ws3, const float* __restrict__ bs3,
                 const float* __restrict__ ws,  float* __restrict__ out)
{
    __shared__ __align__(16) float svT[256][36];      // [feat][electron], pad 36
    __shared__ __align__(16) float pmT[2][3][32][32]; // [h][s][f][j]
    __shared__ __align__(16) float su[256], sd[256];
    __shared__ __align__(16) float cpart[512];
    __shared__ __align__(16) float csh[256];
    __shared__ __align__(16) float s0T[16][32];
    __shared__ __align__(16) float pu0T[4][32];
    __shared__ __align__(16) float pd0T[4][32];
    __shared__ float envs[32];
    __shared__ float orb[2][16][17];
    __shared__ float red[2];

    const int t = threadIdx.x;
    const int b = blockIdx.x;
    const float* wsw = ws + 8224 + (size_t)b*7232;

    const int ln  = t & 63;
    const int wv  = t >> 6;
    const int e0  = ((ln >> 3) & 7) * 4;         // electron base
    const int n0g = wv*32 + (ln & 7)*4;          // col base

    // stage per-walker data
    {
        float* pmf = &pmT[0][0][0][0];
#pragma unroll
        for (int i=0;i<12;i++) pmf[t + i*512] = wsw[t + i*512];
        if (t < 256) csh[t] = wsw[6144+t];
        (&s0T[0][0])[t] = wsw[6400+t];
        if (t < 128) (&pu0T[0][0])[t] = wsw[6912+t];
        else if (t < 256) (&pd0T[0][0])[t-128] = wsw[7040+(t-128)];
        else if (t < 288) envs[t-256] = wsw[7168+(t-256)];
    }
    __syncthreads();

    // layer-0 GEMM (K=24) -> svT
    {
        float acc[4][4];
#pragma unroll
        for (int e=0;e<4;e++)
#pragma unroll
            for (int n=0;n<4;n++) acc[e][n] = csh[n0g+n];
#pragma unroll
        for (int rr=0; rr<4; ++rr){
            float4 w  = *(const float4*)(Ws0 + (32+rr)*256 + n0g);
            float4 Av = *(const float4*)&pu0T[rr][e0];
            ROWT(acc, Av, w);
        }
#pragma unroll
        for (int rr=0; rr<4; ++rr){
            float4 w  = *(const float4*)(Ws0 + (36+rr)*256 + n0g);
            float4 Av = *(const float4*)&pd0T[rr][e0];
            ROWT(acc, Av, w);
        }
#pragma unroll 2
        for (int rr=0; rr<16; ++rr){
            float4 w  = *(const float4*)(Ws0 + (40+rr)*256 + n0g);
            float4 Av = *(const float4*)&s0T[rr][e0];
            ROWT(acc, Av, w);
        }
#pragma unroll
        for (int n=0;n<4;n++){
            float4 v = { tanh_fast(acc[0][n]), tanh_fast(acc[1][n]),
                         tanh_fast(acc[2][n]), tanh_fast(acc[3][n]) };
            *(float4*)&svT[n0g+n][e0] = v;
        }
    }
    __syncthreads();

    // S loop: layers 1..3
#pragma unroll 1
    for (int l=1; l<=3; l++){
        const float* Wl = (l==1)?Ws1:(l==2)?Ws2:Ws3;
        const float* bl = (l==1)?bs1:(l==2)?bs2:bs3;

        if (t < 256){
            const float4* rowp = (const float4*)&svT[t][0];
            float4 a0=rowp[0], a1=rowp[1], a2=rowp[2], a3=rowp[3];
            float4 a4=rowp[4], a5=rowp[5], a6=rowp[6], a7=rowp[7];
            float s1 = (a0.x+a0.y+a0.z+a0.w)+(a1.x+a1.y+a1.z+a1.w)
                     + (a2.x+a2.y+a2.z+a2.w)+(a3.x+a3.y+a3.z+a3.w);
            float s2 = (a4.x+a4.y+a4.z+a4.w)+(a5.x+a5.y+a5.z+a5.w)
                     + (a6.x+a6.y+a6.z+a6.w)+(a7.x+a7.y+a7.z+a7.w);
            su[t] = s1*(1.f/16.f);
            sd[t] = s2*(1.f/16.f);
        }
        __syncthreads();

        {
            int h = t >> 8, n = t & 255;
            const float* Wb  = Wl + h*65536;
            const float* src = h ? sd : su;
            float a0 = h ? 0.f : bl[n];
#pragma unroll 8
            for (int k=0;k<256;k++) a0 += src[k]*Wb[k*256+n];
            cpart[h*256+n] = a0;
        }
        __syncthreads();
        if (t < 256) csh[t] = cpart[t] + cpart[256+t];
        __syncthreads();

        // per-electron GEMM with depth-2 rolling weight prefetch over the
        // contiguous 320-row stream (rows 512..831 of Wl)
        float acc[4][4];
#pragma unroll
        for (int e=0;e<4;e++)
#pragma unroll
            for (int n=0;n<4;n++) acc[e][n] = csh[n0g+n];
        {
            const float (*puA)[32] = pmT[0][l-1];
            const float (*pdA)[32] = pmT[1][l-1];
            const float* Wp = Wl + 512*256 + n0g;
            float4 w0 = *(const float4*)(Wp);
            float4 w1 = *(const float4*)(Wp + 256);
#pragma unroll 2
            for (int R=0; R<32; ++R){
                float4 wc = w0; w0 = w1;
                w1 = *(const float4*)(Wp + (R+2)*256);
                float4 Av = *(const float4*)&puA[R][e0];
                ROWT(acc, Av, wc);
            }
#pragma unroll 2
            for (int R=0; R<32; ++R){
                float4 wc = w0; w0 = w1;
                w1 = *(const float4*)(Wp + (R+34)*256);
                float4 Av = *(const float4*)&pdA[R][e0];
                ROWT(acc, Av, wc);
            }
#pragma unroll 2
            for (int R=0; R<254; ++R){
                float4 wc = w0; w0 = w1;
                w1 = *(const float4*)(Wp + (R+66)*256);
                float4 Av = *(const float4*)&svT[R][e0];
                ROWT(acc, Av, wc);
            }
            {
                float4 Av = *(const float4*)&svT[254][e0];
                ROWT(acc, Av, w0);
                Av = *(const float4*)&svT[255][e0];
                ROWT(acc, Av, w1);
            }
        }
        __syncthreads();

#pragma unroll
        for (int n=0;n<4;n++){
            float4 o = *(const float4*)&svT[n0g+n][e0];
            float4 v = { tanh_fast(acc[0][n])+o.x, tanh_fast(acc[1][n])+o.y,
                         tanh_fast(acc[2][n])+o.z, tanh_fast(acc[3][n])+o.w };
            *(float4*)&svT[n0g+n][e0] = v;
        }
        __syncthreads();
    }

    // F1: orbitals via folded weights (2 halves x 16x16; Wc in ws[0..8224))
    {
        int half = t >> 8, il = (t >> 4) & 15, k16 = t & 15;
        int row = half*16 + il;
        const float* WcT = ws + half*4112;
        float a0 = WcT[4096 + k16];
#pragma unroll 8
        for (int m=0;m<256;m++) a0 += svT[m][row]*WcT[m*16+k16];
        orb[half][il][k16] = a0 * envs[row];
    }
    __syncthreads();

    // F2: 16x16 LU with partial pivoting, one wave per matrix
    {
        int w = t >> 6;
        if (w < 2){
            int lane = t & 63;
            float* M = &orb[w][0][0];   // row stride 17
            float ld_ = 0.f;
            for (int k=0;k<16;k++){
                float v = (lane>=k && lane<16) ? fabsf(M[lane*17+k]) : -1.f;
                int idx = lane;
                for (int off=32; off; off>>=1){
                    float ov = __shfl_xor(v, off);
                    int   oi = __shfl_xor(idx, off);
                    if (ov > v || (ov == v && oi < idx)){ v=ov; idx=oi; }
                }
                int p = idx;
                if (p != k && lane >= k && lane < 16){
                    float t1 = M[k*17+lane], t2 = M[p*17+lane];
                    M[k*17+lane] = t2; M[p*17+lane] = t1;
                }
                float piv = M[k*17+k];
                ld_ += logf(fabsf(piv));
                float inv = 1.f/piv;
                float rowkj = (lane<16) ? M[k*17+lane] : 0.f;
                if (lane > k && lane < 16){
                    for (int i=k+1;i<16;i++){
                        float mik = M[i*17+k]*inv;
                        M[i*17+lane] -= mik*rowkj;
                    }
                }
            }
            if (lane == 0) red[w] = ld_;
        }
    }
    __syncthreads();
    if (t == 0) out[b] = red[0] + red[1];
}

// ---------------- fused fallback: round-13 2-walker kernel (1443 us) --------
__global__ __launch_bounds__(512) __attribute__((amdgpu_waves_per_eu(2,2))) void fermi_fused(
    const float* __restrict__ r,   const float* __restrict__ A,
    const float* __restrict__ Ws0, const float* __restrict__ bs0,
    const float* __restrict__ Wp0, const float* __restrict__ bp0,
    const float* __restrict__ Ws1, const float* __restrict__ bs1,
    const float* __restrict__ Wp1, const float* __restrict__ bp1,
    const float* __restrict__ Ws2, const float* __restrict__ bs2,
    const float* __restrict__ Wp2, const float* __restrict__ bp2,
    const float* __restrict__ Ws3, const float* __restrict__ bs3,
    const float* __restrict__ Wc,  float* __restrict__ out)
{
    __shared__ __align__(16) float sv2[2][32][256];
    __shared__ __align__(16) float pmu2[2][3][32][32];
    __shared__ __align__(16) float pmd2[2][3][32][32];
    __shared__ __align__(16) float su2[2][256];
    __shared__ __align__(16) float sd2[2][256];
    __shared__ __align__(16) float pool[1536];
    __shared__ __align__(16) float wp0s[4][32];
    __shared__ __align__(16) float wp1s[32][32];
    __shared__ __align__(16) float wp2s[32][32];
    __shared__ __align__(16) float bp0s[32], bp1s[32], bp2s[32];
    __shared__ float rs2[2][32][3];
    __shared__ __align__(16) float s02[2][32][16];
    __shared__ float ralen2[2][32][4];
    __shared__ float envs2[2][32];
    __shared__ __align__(16) float pu02[2][32][4];
    __shared__ __align__(16) float pd02[2][32][4];
    __shared__ float su02[2][16], sd02[2][16];
    __shared__ float rbar2[2][2][3];
    __shared__ float red2[2][2];

    const int t = threadIdx.x;
    const int b = blockIdx.x;
    const int n0 = (t & 63) * 4;
    const int j0 = (t >> 6) * 4;
    float* cpart = pool;
    float* cshf  = pool + 1024;

    if (t < 192) (&rs2[0][0][0])[t] = r[(size_t)b*192 + t];
    if (t < 128) (&wp0s[0][0])[t] = Wp0[t];
    {
        float* w1 = &wp1s[0][0];
        w1[t]     = Wp1[t];
        w1[t+512] = Wp1[t+512];
        float* w2 = &wp2s[0][0];
        w2[t]     = Wp2[t];
        w2[t+512] = Wp2[t+512];
    }
    if (t >= 192 && t < 224) bp0s[t-192] = bp0[t-192];
    else if (t >= 224 && t < 256) bp1s[t-224] = bp1[t-224];
    else if (t >= 256 && t < 288) bp2s[t-256] = bp2[t-256];
    __syncthreads();

    if (t < 256){
        int wk = t >> 7, q = t & 127;
        int e = q >> 2, aa = q & 3;
        float dx = rs2[wk][e][0]-A[aa*3+0];
        float dy = rs2[wk][e][1]-A[aa*3+1];
        float dz = rs2[wk][e][2]-A[aa*3+2];
        float ln = sqrtf(dx*dx+dy*dy+dz*dz);
        s02[wk][e][aa*4+0]=dx; s02[wk][e][aa*4+1]=dy;
        s02[wk][e][aa*4+2]=dz; s02[wk][e][aa*4+3]=ln;
        ralen2[wk][e][aa]=ln;
    }
    __syncthreads();

    if (t < 64){
        int wk = t >> 5, e = t & 31;
        envs2[wk][e] = expf(-ralen2[wk][e][0])+expf(-ralen2[wk][e][1])
                     + expf(-ralen2[wk][e][2])+expf(-ralen2[wk][e][3]);
    } else if (t < 128){
        int q = t-64; int wk = q >> 5, half = (q >> 4) & 1, k = q & 15;
        float s = 0.f; int jb = half*16;
        for (int j=jb; j<jb+16; j++) s += s02[wk][j][k];
        (half ? sd02 : su02)[wk][k] = s*(1.f/16.f);
    } else if (t < 140){
        int q = t-128; int wk = q/6, rr_ = q%6, half = rr_/3, c = rr_%3;
        float s=0.f;
        for (int i=half*16;i<half*16+16;i++) s += rs2[wk][i][c];
        rbar2[wk][half][c] = s*(1.f/16.f);
    }
    __syncthreads();

    if (t < 128){
        int wk = t >> 6, q = t & 63;
        int j = q & 31, half = q >> 5;
        float* dst = (half ? pd02 : pu02)[wk][j];
        dst[0] = rs2[wk][j][0]-rbar2[wk][half][0];
        dst[1] = rs2[wk][j][1]-rbar2[wk][half][1];
        dst[2] = rs2[wk][j][2]-rbar2[wk][half][2];
        float s=0.f; int base = half*16;
        for (int i=base;i<base+16;i++){
            if (i != j){
                float dx=rs2[wk][j][0]-rs2[wk][i][0];
                float dy=rs2[wk][j][1]-rs2[wk][i][1];
                float dz=rs2[wk][j][2]-rs2[wk][i][2];
                s += sqrtf(dx*dx+dy*dy+dz*dz);
            }
        }
        dst[3] = s*(1.f/16.f);
    }
    {
        int wk = t >> 8, n = t & 255;
        float a0 = bs0[n];
        for (int k=0;k<16;k++){
            a0 += su02[wk][k]*Ws0[k*256+n] + sd02[wk][k]*Ws0[(16+k)*256+n];
        }
        cshf[wk*256+n] = a0;
    }
    __syncthreads();

    {
        const int i1  = t & 15;
        const int jj4 = (t >> 4) & 15;
        const int wkp = t >> 8;
#pragma unroll 1
        for (int pass=0; pass<4; ++pass){
            const int h   = pass >> 1;
            const int jjs = jj4 + (pass & 1)*16;
            const int ii  = i1 + h*16;
            float px[32];
            {
                float dx = rs2[wkp][jjs][0]-rs2[wkp][ii][0];
                float dy = rs2[wkp][jjs][1]-rs2[wkp][ii][1];
                float dz = rs2[wkp][jjs][2]-rs2[wkp][ii][2];
                float ln = sqrtf(dx*dx+dy*dy+dz*dz);
#pragma unroll
                for (int c=0; c<8; c++){
                    float4 w0 = ((const float4*)wp0s[0])[c];
                    float4 w1 = ((const float4*)wp0s[1])[c];
                    float4 w2 = ((const float4*)wp0s[2])[c];
                    float4 w3 = ((const float4*)wp0s[3])[c];
                    float4 bb = ((const float4*)bp0s)[c];
                    px[c*4+0] = tanh_fast(bb.x + dx*w0.x + dy*w1.x + dz*w2.x + ln*w3.x);
                    px[c*4+1] = tanh_fast(bb.y + dx*w0.y + dy*w1.y + dz*w2.y + ln*w3.y);
                    px[c*4+2] = tanh_fast(bb.z + dx*w0.z + dy*w1.z + dz*w2.z + ln*w3.z);
                    px[c*4+3] = tanh_fast(bb.w + dx*w0.w + dy*w1.w + dz*w2.w + ln*w3.w);
                }
            }
            float (*pm)[32][32] = h ? pmd2[wkp] : pmu2[wkp];
#pragma unroll 1
            for (int s=0; s<3; ++s){
#pragma unroll
                for (int f=0; f<32; f++){
                    float a_ = px[f];
                    a_ += __shfl_xor(a_,1); a_ += __shfl_xor(a_,2);
                    a_ += __shfl_xor(a_,4); a_ += __shfl_xor(a_,8);
                    if (i1 == 0) pm[s][jjs][f] = a_*(1.f/16.f);
                }
                if (s == 0)      pair_update(px, wp1s, bp1s);
                else if (s == 1) pair_update(px, wp2s, bp2s);
            }
        }
    }
    __syncthreads();

    {
        float acc0[4][4], acc1[4][4];
#pragma unroll
        for (int e=0;e<4;e++)
#pragma unroll
            for (int n=0;n<4;n++){ acc0[e][n] = cshf[n0+n]; acc1[e][n] = cshf[256+n0+n]; }
        {
            float4 A0 = *(const float4*)pu02[0][j0+0];
            float4 A1 = *(const float4*)pu02[0][j0+1];
            float4 A2 = *(const float4*)pu02[0][j0+2];
            float4 A3 = *(const float4*)pu02[0][j0+3];
            float4 B0 = *(const float4*)pu02[1][j0+0];
            float4 B1 = *(const float4*)pu02[1][j0+1];
            float4 B2 = *(const float4*)pu02[1][j0+2];
            float4 B3 = *(const float4*)pu02[1][j0+3];
            G4D(Ws0, 32, A0,A1,A2,A3, B0,B1,B2,B3);
            A0 = *(const float4*)pd02[0][j0+0];
            A1 = *(const float4*)pd02[0][j0+1];
            A2 = *(const float4*)pd02[0][j0+2];
            A3 = *(const float4*)pd02[0][j0+3];
            B0 = *(const float4*)pd02[1][j0+0];
            B1 = *(const float4*)pd02[1][j0+1];
            B2 = *(const float4*)pd02[1][j0+2];
            B3 = *(const float4*)pd02[1][j0+3];
            G4D(Ws0, 36, A0,A1,A2,A3, B0,B1,B2,B3);
        }
#pragma unroll
        for (int k4=0;k4<4;k4++){
            float4 A0 = ((const float4*)s02[0][j0+0])[k4];
            float4 A1 = ((const float4*)s02[0][j0+1])[k4];
            float4 A2 = ((const float4*)s02[0][j0+2])[k4];
            float4 A3 = ((const float4*)s02[0][j0+3])[k4];
            float4 B0 = ((const float4*)s02[1][j0+0])[k4];
            float4 B1 = ((const float4*)s02[1][j0+1])[k4];
            float4 B2 = ((const float4*)s02[1][j0+2])[k4];
            float4 B3 = ((const float4*)s02[1][j0+3])[k4];
            G4D(Ws0, 40+k4*4, A0,A1,A2,A3, B0,B1,B2,B3);
        }
#pragma unroll
        for (int e=0;e<4;e++)
#pragma unroll
            for (int n=0;n<4;n++){
                sv2[0][j0+e][n0+n] = tanh_fast(acc0[e][n]);
                sv2[1][j0+e][n0+n] = tanh_fast(acc1[e][n]);
            }
    }
    __syncthreads();

#pragma unroll 1
    for (int l=1; l<=3; l++){
        const float* Wl  = (l==1)?Ws1:(l==2)?Ws2:Ws3;
        const float* bl  = (l==1)?bs1:(l==2)?bs2:bs3;

        {
            int wk = t >> 8, k = t & 255;
            float s1=0.f, s2=0.f;
            for (int j=0;j<16;j++)  s1 += sv2[wk][j][k];
            for (int j=16;j<32;j++) s2 += sv2[wk][j][k];
            su2[wk][k] = s1*(1.f/16.f);
            sd2[wk][k] = s2*(1.f/16.f);
        }
        __syncthreads();

        {
            int h = t >> 8, n = t & 255;
            const float* Wb = Wl + h*65536;
            const float* sA = h ? sd2[0] : su2[0];
            const float* sB = h ? sd2[1] : su2[1];
            float a0 = h ? 0.f : bl[n];
            float a1 = a0;
#pragma unroll 8
            for (int k=0;k<256;k++){
                float wv = Wb[k*256+n];
                a0 += sA[k]*wv; a1 += sB[k]*wv;
            }
            cpart[(0*2+h)*256+n] = a0;
            cpart[(1*2+h)*256+n] = a1;
        }
        __syncthreads();
        {
            int wk = t >> 8, n = t & 255;
            cshf[wk*256+n] = cpart[(wk*2+0)*256+n] + cpart[(wk*2+1)*256+n];
        }
        __syncthreads();

        float acc0[4][4], acc1[4][4];
#pragma unroll
        for (int e=0;e<4;e++)
#pragma unroll
            for (int n=0;n<4;n++){ acc0[e][n] = cshf[n0+n]; acc1[e][n] = cshf[256+n0+n]; }
        const float* puA = &pmu2[0][l-1][0][0];
        const float* puB = &pmu2[1][l-1][0][0];
        const float* pdA = &pmd2[0][l-1][0][0];
        const float* pdB = &pmd2[1][l-1][0][0];
#pragma unroll
        for (int k4=0;k4<8;k4++){
            float4 A0 = ((const float4*)(puA + (j0+0)*32))[k4];
            float4 A1 = ((const float4*)(puA + (j0+1)*32))[k4];
            float4 A2 = ((const float4*)(puA + (j0+2)*32))[k4];
            float4 A3 = ((const float4*)(puA + (j0+3)*32))[k4];
            float4 B0 = ((const float4*)(puB + (j0+0)*32))[k4];
            float4 B1 = ((const float4*)(puB + (j0+1)*32))[k4];
            float4 B2 = ((const float4*)(puB + (j0+2)*32))[k4];
            float4 B3 = ((const float4*)(puB + (j0+3)*32))[k4];
            G4D(Wl, 512+k4*4, A0,A1,A2,A3, B0,B1,B2,B3);
        }
#pragma unroll
        for (int k4=0;k4<8;k4++){
            float4 A0 = ((const float4*)(pdA + (j0+0)*32))[k4];
            float4 A1 = ((const float4*)(pdA + (j0+1)*32))[k4];
            float4 A2 = ((const float4*)(pdA + (j0+2)*32))[k4];
            float4 A3 = ((const float4*)(pdA + (j0+3)*32))[k4];
            float4 B0 = ((const float4*)(pdB + (j0+0)*32))[k4];
            float4 B1 = ((const float4*)(pdB + (j0+1)*32))[k4];
            float4 B2 = ((const float4*)(pdB + (j0+2)*32))[k4];
            float4 B3 = ((const float4*)(pdB + (j0+3)*32))[k4];
            G4D(Wl, 544+k4*4, A0,A1,A2,A3, B0,B1,B2,B3);
        }
        {
            const float* WbP = Wl + 576*256 + n0;
            float4 wn0 = *(const float4*)(WbP);
            float4 wn1 = *(const float4*)(WbP + 256);
            float4 wn2 = *(const float4*)(WbP + 512);
            float4 wn3 = *(const float4*)(WbP + 768);
#pragma unroll 1
            for (int k4=0;k4<64;k4++){
                float4 w0=wn0, w1=wn1, w2=wn2, w3=wn3;
                {
                    int kn = (k4 < 63) ? (k4+1) : 63;
                    const float* Wn = WbP + kn*1024;
                    wn0 = *(const float4*)(Wn);
                    wn1 = *(const float4*)(Wn + 256);
                    wn2 = *(const float4*)(Wn + 512);
                    wn3 = *(const float4*)(Wn + 768);
                }
                float4 A0 = ((const float4*)sv2[0][j0+0])[k4];
                float4 A1 = ((const float4*)sv2[0][j0+1])[k4];
                float4 A2 = ((const float4*)sv2[0][j0+2])[k4];
                float4 A3 = ((const float4*)sv2[0][j0+3])[k4];
                float4 B0 = ((const float4*)sv2[1][j0+0])[k4];
                float4 B1 = ((const float4*)sv2[1][j0+1])[k4];
                float4 B2 = ((const float4*)sv2[1][j0+2])[k4];
                float4 B3 = ((const float4*)sv2[1][j0+3])[k4];
                G4P(w0,w1,w2,w3, A0,A1,A2,A3, B0,B1,B2,B3);
            }
        }
        __syncthreads();

#pragma unroll
        for (int e=0;e<4;e++)
#pragma unroll
            for (int n=0;n<4;n++){
                float o0 = sv2[0][j0+e][n0+n];
                float o1 = sv2[1][j0+e][n0+n];
                sv2[0][j0+e][n0+n] = tanh_fast(acc0[e][n]) + o0;
                sv2[1][j0+e][n0+n] = tanh_fast(acc1[e][n]) + o1;
            }
        __syncthreads();
    }

#pragma unroll 1
    for (int rep=0; rep<2; ++rep){
        int idx = t + rep*512;
        int wk = idx >> 9, rem = idx & 511;
        int half = rem >> 8, il = (rem >> 4) & 15, k16 = rem & 15;
        int row = half*16 + il;
        const float* WcT = Wc + half*4112;
        float a0 = WcT[4096 + k16];
#pragma unroll 8
        for (int m=0;m<256;m++) a0 += sv2[wk][row][m]*WcT[m*16+k16];
        pool[(wk*2+half)*272 + il*17 + k16] = a0 * envs2[wk][row];
    }
    __syncthreads();

    {
        int w = t >> 6;
        if (w < 4){
            int lane = t & 63;
            float* M = pool + w*272;
            float ld_ = 0.f;
            for (int k=0;k<16;k++){
                float v = (lane>=k && lane<16) ? fabsf(M[lane*17+k]) : -1.f;
                int idx = lane;
                for (int off=32; off; off>>=1){
                    float ov = __shfl_xor(v, off);
                    int   oi = __shfl_xor(idx, off);
                    if (ov > v || (ov == v && oi < idx)){ v=ov; idx=oi; }
                }
                int p = idx;
                if (p != k && lane >= k && lane < 16){
                    float t1 = M[k*17+lane], t2 = M[p*17+lane];
                    M[k*17+lane] = t2; M[p*17+lane] = t1;
                }
                float piv = M[k*17+k];
                ld_ += logf(fabsf(piv));
                float inv = 1.f/piv;
                float rowkj = (lane<16) ? M[k*17+lane] : 0.f;
                if (lane > k && lane < 16){
                    for (int i=k+1;i<16;i++){
                        float mik = M[i*17+k]*inv;
                        M[i*17+lane] -= mik*rowkj;
                    }
                }
            }
            if (lane == 0) red2[w>>1][w&1] = ld_;
        }
    }
    __syncthreads();
    if (t < 2) out[2*b + t] = red2[t][0] + red2[t][1];
}

extern "C" void kernel_launch(void* const* d_in, const int* in_sizes, int n_in,
                              void* d_out, int out_size, void* d_ws, size_t ws_size,
                              hipStream_t stream) {
    const float* r   = (const float*)d_in[0];
    const float* a   = (const float*)d_in[1];
    const float* Ws0 = (const float*)d_in[2];  const float* bs0 = (const float*)d_in[3];
    const float* Wp0 = (const float*)d_in[4];  const float* bp0 = (const float*)d_in[5];
    const float* Ws1 = (const float*)d_in[6];  const float* bs1 = (const float*)d_in[7];
    const float* Wp1 = (const float*)d_in[8];  const float* bp1 = (const float*)d_in[9];
    const float* Ws2 = (const float*)d_in[10]; const float* bs2 = (const float*)d_in[11];
    const float* Wp2 = (const float*)d_in[12]; const float* bp2 = (const float*)d_in[13];
    const float* Ws3 = (const float*)d_in[14]; const float* bs3 = (const float*)d_in[15];
    const float* Wu  = (const float*)d_in[16]; const float* bu  = (const float*)d_in[17];
    const float* Wd  = (const float*)d_in[18]; const float* bd  = (const float*)d_in[19];
    const float* Wwu = (const float*)d_in[20]; const float* bwu = (const float*)d_in[21];
    const float* Wwd = (const float*)d_in[22]; const float* bwd = (const float*)d_in[23];
    float* ws = (float*)d_ws;
    float* out = (float*)d_out;

    const int B = out_size;
    const size_t need = ((size_t)8224 + (size_t)B*7232) * 4;

    fermi_prep<<<1, 512, 0, stream>>>(Wu, bu, Wd, bd, Wwu, bwu, Wwd, bwd, ws);
    if (ws_size >= need){
        fermi_pair<<<B, 512, 0, stream>>>(r, a, Ws0, bs0, Wp0, bp0,
                                          Wp1, bp1, Wp2, bp2, ws);
        fermi_smain<<<B, 512, 0, stream>>>(Ws0, Ws1, bs1, Ws2, bs2, Ws3, bs3, ws, out);
    } else {
        fermi_fused<<<B/2, 512, 0, stream>>>(r, a, Ws0, bs0, Wp0, bp0,
                                             Ws1, bs1, Wp1, bp1,
                                             Ws2, bs2, Wp2, bp2,
                                             Ws3, bs3, ws, out);
    }
}

// Round 18
// 1073.332 us; speedup vs baseline: 1.6716x; 1.0040x over previous
//
#include <hip/hip_runtime.h>
#include <hip/hip_bf16.h>

__device__ __forceinline__ float tanh_fast(float x){
    float e = __expf(2.0f*x);
    return 1.0f - 2.0f/(e + 1.0f);
}

// one GEMM row: A_ = 4 electrons (transposed activations), W_ = 4 cols; acc[e][n]
#define ROWT(ACC, A_, W_) do{                                     \
    ACC[0][0] += (A_).x*(W_).x; ACC[0][1] += (A_).x*(W_).y;       \
    ACC[0][2] += (A_).x*(W_).z; ACC[0][3] += (A_).x*(W_).w;       \
    ACC[1][0] += (A_).y*(W_).x; ACC[1][1] += (A_).y*(W_).y;       \
    ACC[1][2] += (A_).y*(W_).z; ACC[1][3] += (A_).y*(W_).w;       \
    ACC[2][0] += (A_).z*(W_).x; ACC[2][1] += (A_).z*(W_).y;       \
    ACC[2][2] += (A_).z*(W_).z; ACC[2][3] += (A_).z*(W_).w;       \
    ACC[3][0] += (A_).w*(W_).x; ACC[3][1] += (A_).w*(W_).y;       \
    ACC[3][2] += (A_).w*(W_).z; ACC[3][3] += (A_).w*(W_).w;       \
}while(0)

// ---- macros for the fused fallback (round-13 2-walker kernel) ----
#define FMA16A(ACC, W_, A_, B_, C_, D_) do{                      \
    ACC[0][0] += (A_)*(W_).x; ACC[0][1] += (A_)*(W_).y;          \
    ACC[0][2] += (A_)*(W_).z; ACC[0][3] += (A_)*(W_).w;          \
    ACC[1][0] += (B_)*(W_).x; ACC[1][1] += (B_)*(W_).y;          \
    ACC[1][2] += (B_)*(W_).z; ACC[1][3] += (B_)*(W_).w;          \
    ACC[2][0] += (C_)*(W_).x; ACC[2][1] += (C_)*(W_).y;          \
    ACC[2][2] += (C_)*(W_).z; ACC[2][3] += (C_)*(W_).w;          \
    ACC[3][0] += (D_)*(W_).x; ACC[3][1] += (D_)*(W_).y;          \
    ACC[3][2] += (D_)*(W_).z; ACC[3][3] += (D_)*(W_).w;          \
}while(0)

#define ROW2(Wb, R_, c_, A0,A1,A2,A3, B0,B1,B2,B3) do{                        \
    float4 w_ = *(const float4*)((Wb) + (R_)*256 + n0);                       \
    FMA16A(acc0, w_, (A0).c_,(A1).c_,(A2).c_,(A3).c_);                        \
    FMA16A(acc1, w_, (B0).c_,(B1).c_,(B2).c_,(B3).c_);                        \
}while(0)

#define G4D(Wb, R0, A0,A1,A2,A3, B0,B1,B2,B3) do{                \
    ROW2(Wb, (R0)+0, x, A0,A1,A2,A3, B0,B1,B2,B3);               \
    ROW2(Wb, (R0)+1, y, A0,A1,A2,A3, B0,B1,B2,B3);               \
    ROW2(Wb, (R0)+2, z, A0,A1,A2,A3, B0,B1,B2,B3);               \
    ROW2(Wb, (R0)+3, w, A0,A1,A2,A3, B0,B1,B2,B3);               \
}while(0)

#define G4P(w0,w1,w2,w3, A0,A1,A2,A3, B0,B1,B2,B3) do{                                   \
    FMA16A(acc0, w0, (A0).x,(A1).x,(A2).x,(A3).x);                                       \
    FMA16A(acc1, w0, (B0).x,(B1).x,(B2).x,(B3).x);                                       \
    FMA16A(acc0, w1, (A0).y,(A1).y,(A2).y,(A3).y);                                       \
    FMA16A(acc1, w1, (B0).y,(B1).y,(B2).y,(B3).y);                                       \
    FMA16A(acc0, w2, (A0).z,(A1).z,(A2).z,(A3).z);                                       \
    FMA16A(acc1, w2, (B0).z,(B1).z,(B2).z,(B3).z);                                       \
    FMA16A(acc0, w3, (A0).w,(A1).w,(A2).w,(A3).w);                                       \
    FMA16A(acc1, w3, (B0).w,(B1).w,(B2).w,(B3).w);                                       \
}while(0)

// register-array pair update (used only by the fused fallback)
__device__ __forceinline__ void pair_update(float (&px)[32], const float (*wp)[32], const float* bpb){
    float a2[32];
#pragma unroll
    for (int f=0;f<32;f++) a2[f] = bpb[f];
#pragma unroll 4
    for (int k=0;k<32;k++){
        float xk = px[k];
        const float4* wr = (const float4*)wp[k];
#pragma unroll
        for (int c=0;c<8;c++){
            float4 w = wr[c];
            a2[c*4+0] += xk*w.x; a2[c*4+1] += xk*w.y;
            a2[c*4+2] += xk*w.z; a2[c*4+3] += xk*w.w;
        }
    }
#pragma unroll
    for (int f=0;f<32;f++) px[f] = tanh_fast(a2[f]) + px[f];
}

// ---------------- prep: Wcu = Wu@Wwu, bcu = bu@Wwu+bwu; same for down spin ----
// ws layout (floats): [0,4096) Wcu  [4096,4112) bcu  [4112,8208) Wcd  [8208,8224) bcd
__global__ __launch_bounds__(512) void fermi_prep(
    const float* __restrict__ Wu, const float* __restrict__ bu,
    const float* __restrict__ Wd, const float* __restrict__ bd,
    const float* __restrict__ Wwu, const float* __restrict__ bwu,
    const float* __restrict__ Wwd, const float* __restrict__ bwd,
    float* __restrict__ ws)
{
    const int t = threadIdx.x;
    const int m = t & 255;
    const int half = t >> 8;
    const float* Wbig = half ? Wd : Wu;
    const float* Wsm  = half ? Wwd : Wwu;
    float acc[16];
#pragma unroll
    for (int k=0;k<16;k++) acc[k]=0.f;
    for (int h=0; h<128; h++){
        float wv = Wbig[m*128+h];
        const float4* wr = (const float4*)(Wsm + h*16);
        float4 a0=wr[0], a1=wr[1], a2=wr[2], a3=wr[3];
        acc[0]+=wv*a0.x; acc[1]+=wv*a0.y; acc[2]+=wv*a0.z; acc[3]+=wv*a0.w;
        acc[4]+=wv*a1.x; acc[5]+=wv*a1.y; acc[6]+=wv*a1.z; acc[7]+=wv*a1.w;
        acc[8]+=wv*a2.x; acc[9]+=wv*a2.y; acc[10]+=wv*a2.z; acc[11]+=wv*a2.w;
        acc[12]+=wv*a3.x; acc[13]+=wv*a3.y; acc[14]+=wv*a3.z; acc[15]+=wv*a3.w;
    }
    float* dst = ws + half*4112;
#pragma unroll
    for (int k=0;k<16;k++) dst[m*16+k]=acc[k];
    if (m < 16){
        const float* bbig = half ? bd : bu;
        float b2 = half ? bwd[m] : bwu[m];
        for (int h=0;h<128;h++) b2 += bbig[h]*Wsm[h*16+m];
        dst[4096+m] = b2;
    }
}

// ---------------- kernel 1: features + pair phase, LDS-resident pair state ---
// per-walker ws block (stride 7232 floats, base 8224 + b*7232):
//  +0 pmuT[3][32][32]  +3072 pmdT[3][32][32]  +6144 csh[256]  +6400 s0T[16][32]
//  +6912 pu0T[4][32]   +7040 pd0T[4][32]      +7168 envs[32]
__global__ __launch_bounds__(512) __attribute__((amdgpu_waves_per_eu(4,4)))
void fermi_pair(const float* __restrict__ r,   const float* __restrict__ A,
                const float* __restrict__ Ws0, const float* __restrict__ bs0,
                const float* __restrict__ Wp0, const float* __restrict__ bp0,
                const float* __restrict__ Wp1, const float* __restrict__ bp1,
                const float* __restrict__ Wp2, const float* __restrict__ bp2,
                float* __restrict__ ws)
{
    __shared__ __align__(16) float pxQ[256][36];      // quarter pair state [p][f]
    __shared__ __align__(16) float pm[6][32][33];     // means acc [(h*3+s)][f][j]
    __shared__ __align__(16) float wp0s[4][32];
    __shared__ __align__(16) float wp1s[32][32];
    __shared__ __align__(16) float wp2s[32][32];
    __shared__ __align__(16) float bp0s[32], bp1s[32], bp2s[32];
    __shared__ float rs[32][3];
    __shared__ __align__(16) float s0T[16][32];
    __shared__ float ralen[32][4];
    __shared__ __align__(16) float pu0T[4][32];
    __shared__ __align__(16) float pd0T[4][32];
    __shared__ float su0[16], sd0[16];
    __shared__ float rbar[2][3];

    const int t = threadIdx.x;
    const int b = blockIdx.x;
    float* wsw = ws + 8224 + (size_t)b*7232;

    // A1 staging
    if (t < 96) rs[t/3][t%3] = r[(size_t)b*96 + t];
    if (t < 128) (&wp0s[0][0])[t] = Wp0[t];
    {
        float* w1 = &wp1s[0][0];
        w1[t]     = Wp1[t];
        w1[t+512] = Wp1[t+512];
        float* w2 = &wp2s[0][0];
        w2[t]     = Wp2[t];
        w2[t+512] = Wp2[t+512];
    }
    if (t >= 128 && t < 160) bp0s[t-128] = bp0[t-128];
    else if (t >= 160 && t < 192) bp1s[t-160] = bp1[t-160];
    else if (t >= 192 && t < 224) bp2s[t-192] = bp2[t-192];
    {   // zero the means accumulator (6*32*33 = 6336 floats)
        float* pmf = &pm[0][0][0];
        for (int i = t; i < 6336; i += 512) pmf[i] = 0.f;
    }
    __syncthreads();

    // A2: electron-atom features (transposed)
    if (t < 128){
        int e = t >> 2, aa = t & 3;
        float dx = rs[e][0]-A[aa*3+0];
        float dy = rs[e][1]-A[aa*3+1];
        float dz = rs[e][2]-A[aa*3+2];
        float ln = sqrtf(dx*dx+dy*dy+dz*dz);
        s0T[aa*4+0][e]=dx; s0T[aa*4+1][e]=dy;
        s0T[aa*4+2][e]=dz; s0T[aa*4+3][e]=ln;
        ralen[e][aa]=ln;
    }
    __syncthreads();

    // A3: envs -> ws, su0/sd0, rbar
    if (t < 32){
        wsw[7168+t] = expf(-ralen[t][0])+expf(-ralen[t][1])+expf(-ralen[t][2])+expf(-ralen[t][3]);
    } else if (t < 48){
        int k = t-32; float s=0.f;
        for (int j=0;j<16;j++) s += s0T[k][j];
        su0[k] = s*(1.f/16.f);
    } else if (t < 64){
        int k = t-48; float s=0.f;
        for (int j=16;j<32;j++) s += s0T[k][j];
        sd0[k] = s*(1.f/16.f);
    } else if (t < 70){
        int q = t-64; int half=q/3, c=q%3; float s=0.f;
        for (int i=half*16;i<half*16+16;i++) s += rs[i][c];
        rbar[half][c] = s*(1.f/16.f);
    }
    __syncthreads();

    // A4: pu0/pd0 (transposed) + layer-0 shared GEMV -> ws
    if (t < 64){
        int j = t & 31, half = t >> 5;
        float vx = rs[j][0]-rbar[half][0];
        float vy = rs[j][1]-rbar[half][1];
        float vz = rs[j][2]-rbar[half][2];
        float s=0.f; int base = half*16;
        for (int i=base;i<base+16;i++){
            if (i != j){
                float dx=rs[j][0]-rs[i][0];
                float dy=rs[j][1]-rs[i][1];
                float dz=rs[j][2]-rs[i][2];
                s += sqrtf(dx*dx+dy*dy+dz*dz);
            }
        }
        float (*dst)[32] = half ? pd0T : pu0T;
        dst[0][j]=vx; dst[1][j]=vy; dst[2][j]=vz; dst[3][j]=s*(1.f/16.f);
    }
    if (t >= 128 && t < 384){
        int n = t-128;
        float a0 = bs0[n];
        for (int k=0;k<16;k++){
            a0 += su0[k]*Ws0[k*256+n] + sd0[k]*Ws0[(16+k)*256+n];
        }
        wsw[6144+n] = a0;
    }
    __syncthreads();

    // export transposed feature blocks
    wsw[6400+t] = (&s0T[0][0])[t];
    if (t < 128) wsw[6912+t] = (&pu0T[0][0])[t];
    else if (t < 256) wsw[7040+(t-128)] = (&pd0T[0][0])[t-128];

    // ===== quarter loop: 4 x (256 pairs) through build + 2 updates + 3 means =====
    const int bpair = t >> 1;             // build: pair 0..255
    const int bfq   = (t & 1) * 16;       // build: feature half
    const int mf    = t & 31;             // means: feature
    const int mj0   = t >> 5;             // means: j base (0..15)
    const int ug    = t >> 3;             // update: pair group 0..63
    const int uf4   = (t & 7) * 4;        // update: feature base
#pragma unroll 1
    for (int qq = 0; qq < 4; ++qq){
        const int h = qq >> 1, q = qq & 1;
        // BUILD: px = tanh(wp0 . [dx,dy,dz,ln] + b)
        {
            const int jj = bpair & 31;
            const int ii = h*16 + q*8 + (bpair >> 5);
            float dx = rs[jj][0]-rs[ii][0];
            float dy = rs[jj][1]-rs[ii][1];
            float dz = rs[jj][2]-rs[ii][2];
            float ln = sqrtf(dx*dx+dy*dy+dz*dz);
#pragma unroll
            for (int c = 0; c < 4; ++c){
                int f0 = bfq + c*4;
                float4 w0 = *(const float4*)&wp0s[0][f0];
                float4 w1 = *(const float4*)&wp0s[1][f0];
                float4 w2 = *(const float4*)&wp0s[2][f0];
                float4 w3 = *(const float4*)&wp0s[3][f0];
                float4 bb = *(const float4*)&bp0s[f0];
                float4 v;
                v.x = tanh_fast(bb.x + dx*w0.x + dy*w1.x + dz*w2.x + ln*w3.x);
                v.y = tanh_fast(bb.y + dx*w0.y + dy*w1.y + dz*w2.y + ln*w3.y);
                v.z = tanh_fast(bb.z + dx*w0.z + dy*w1.z + dz*w2.z + ln*w3.z);
                v.w = tanh_fast(bb.w + dx*w0.w + dy*w1.w + dz*w2.w + ln*w3.w);
                *(float4*)&pxQ[bpair][f0] = v;
            }
        }
        __syncthreads();
#pragma unroll 1
        for (int s = 0; s < 3; ++s){
            // MEANS partial: pm[h*3+s][f][j] += (1/16) * sum_{iq} pxQ[iq*32+j][f]
            {
#pragma unroll
                for (int jr = 0; jr < 2; ++jr){
                    const int j = mj0 + jr*16;
                    float sacc = 0.f;
#pragma unroll
                    for (int iq = 0; iq < 8; ++iq)
                        sacc += pxQ[iq*32 + j][mf];
                    pm[h*3+s][mf][j] += sacc * (1.f/16.f);
                }
            }
            if (s < 2){
                const float (*wps)[32] = (s == 0) ? wp1s : wp2s;
                const float* bps = (s == 0) ? bp1s : bp2s;
                float acc[4][4];
                {
                    float4 bb = *(const float4*)&bps[uf4];
#pragma unroll
                    for (int j = 0; j < 4; ++j){
                        acc[j][0]=bb.x; acc[j][1]=bb.y; acc[j][2]=bb.z; acc[j][3]=bb.w;
                    }
                }
#pragma unroll
                for (int k4 = 0; k4 < 8; ++k4){
                    float4 w0 = *(const float4*)&wps[k4*4+0][uf4];
                    float4 w1 = *(const float4*)&wps[k4*4+1][uf4];
                    float4 w2 = *(const float4*)&wps[k4*4+2][uf4];
                    float4 w3 = *(const float4*)&wps[k4*4+3][uf4];
#pragma unroll
                    for (int j = 0; j < 4; ++j){
                        float4 p4 = *(const float4*)&pxQ[j*64 + ug][k4*4];
                        acc[j][0] += p4.x*w0.x + p4.y*w1.x + p4.z*w2.x + p4.w*w3.x;
                        acc[j][1] += p4.x*w0.y + p4.y*w1.y + p4.z*w2.y + p4.w*w3.y;
                        acc[j][2] += p4.x*w0.z + p4.y*w1.z + p4.z*w2.z + p4.w*w3.z;
                        acc[j][3] += p4.x*w0.w + p4.y*w1.w + p4.z*w2.w + p4.w*w3.w;
                    }
                }
                __syncthreads();
#pragma unroll
                for (int j = 0; j < 4; ++j){
                    float4 o = *(const float4*)&pxQ[j*64 + ug][uf4];
                    float4 v;
                    v.x = tanh_fast(acc[j][0]) + o.x;
                    v.y = tanh_fast(acc[j][1]) + o.y;
                    v.z = tanh_fast(acc[j][2]) + o.z;
                    v.w = tanh_fast(acc[j][3]) + o.w;
                    *(float4*)&pxQ[j*64 + ug][uf4] = v;
                }
                __syncthreads();
            } else {
                __syncthreads();   // pxQ reads done before next quarter's build
            }
        }
    }

    // export means -> ws (layout [h][s][f][j], j inner)
    {
        const float* pmf = &pm[0][0][0];
#pragma unroll
        for (int i = 0; i < 12; ++i){
            int idx = t + i*512;            // 0..6143
            int j  = idx & 31;
            int f  = (idx >> 5) & 31;
            int hs = idx >> 10;             // 0..5
            wsw[idx] = pmf[hs*1056 + f*33 + j];
        }
    }
}

// ---------------- kernel 2: single-stream phase (64-VGPR cap, 16 waves/CU) ---
// Round 18: dual-stream software pipeline — weights (global, depth 2) AND
// activations (LDS ds_read, depth 1) both rolled ahead, peeled section
// boundaries so all addresses are compile-time affine.
__global__ __launch_bounds__(512) __attribute__((amdgpu_waves_per_eu(4,4)))
void fermi_smain(const float* __restrict__ Ws0,
                 const float* __restrict__ Ws1, const float* __restrict__ bs1,
                 const float* __restrict__ Ws2, const float* __restrict__ bs2,
                 const float* __restrict__ Ws3, const float* __restrict__ bs3,
                 const float* __restrict__ ws,  float* __restrict__ out)
{
    __shared__ __align__(16) float svT[256][36];      // [feat][electron], pad 36
    __shared__ __align__(16) float pmT[2][3][32][32]; // [h][s][f][j]
    __shared__ __align__(16) float su[256], sd[256];
    __shared__ __align__(16) float cpart[512];
    __shared__ __align__(16) float csh[256];
    __shared__ __align__(16) float s0T[16][32];
    __shared__ __align__(16) float pu0T[4][32];
    __shared__ __align__(16) float pd0T[4][32];
    __shared__ float envs[32];
    __shared__ float orb[2][16][17];
    __shared__ float red[2];

    const int t = threadIdx.x;
    const int b = blockIdx.x;
    const float* wsw = ws + 8224 + (size_t)b*7232;

    const int ln  = t & 63;
    const int wv  = t >> 6;
    const int e0  = ((ln >> 3) & 7) * 4;         // electron base
    const int n0g = wv*32 + (ln & 7)*4;          // col base

    // stage per-walker data
    {
        float* pmf = &pmT[0][0][0][0];
#pragma unroll
        for (int i=0;i<12;i++) pmf[t + i*512] = wsw[t + i*512];
        if (t < 256) csh[t] = wsw[6144+t];
        (&s0T[0][0])[t] = wsw[6400+t];
        if (t < 128) (&pu0T[0][0])[t] = wsw[6912+t];
        else if (t < 256) (&pd0T[0][0])[t-128] = wsw[7040+(t-128)];
        else if (t < 288) envs[t-256] = wsw[7168+(t-256)];
    }
    __syncthreads();

    // layer-0 GEMM (K=24) -> svT
    {
        float acc[4][4];
#pragma unroll
        for (int e=0;e<4;e++)
#pragma unroll
            for (int n=0;n<4;n++) acc[e][n] = csh[n0g+n];
#pragma unroll
        for (int rr=0; rr<4; ++rr){
            float4 w  = *(const float4*)(Ws0 + (32+rr)*256 + n0g);
            float4 Av = *(const float4*)&pu0T[rr][e0];
            ROWT(acc, Av, w);
        }
#pragma unroll
        for (int rr=0; rr<4; ++rr){
            float4 w  = *(const float4*)(Ws0 + (36+rr)*256 + n0g);
            float4 Av = *(const float4*)&pd0T[rr][e0];
            ROWT(acc, Av, w);
        }
#pragma unroll 2
        for (int rr=0; rr<16; ++rr){
            float4 w  = *(const float4*)(Ws0 + (40+rr)*256 + n0g);
            float4 Av = *(const float4*)&s0T[rr][e0];
            ROWT(acc, Av, w);
        }
#pragma unroll
        for (int n=0;n<4;n++){
            float4 v = { tanh_fast(acc[0][n]), tanh_fast(acc[1][n]),
                         tanh_fast(acc[2][n]), tanh_fast(acc[3][n]) };
            *(float4*)&svT[n0g+n][e0] = v;
        }
    }
    __syncthreads();

    // S loop: layers 1..3
#pragma unroll 1
    for (int l=1; l<=3; l++){
        const float* Wl = (l==1)?Ws1:(l==2)?Ws2:Ws3;
        const float* bl = (l==1)?bs1:(l==2)?bs2:bs3;

        if (t < 256){
            const float4* rowp = (const float4*)&svT[t][0];
            float4 a0=rowp[0], a1=rowp[1], a2=rowp[2], a3=rowp[3];
            float4 a4=rowp[4], a5=rowp[5], a6=rowp[6], a7=rowp[7];
            float s1 = (a0.x+a0.y+a0.z+a0.w)+(a1.x+a1.y+a1.z+a1.w)
                     + (a2.x+a2.y+a2.z+a2.w)+(a3.x+a3.y+a3.z+a3.w);
            float s2 = (a4.x+a4.y+a4.z+a4.w)+(a5.x+a5.y+a5.z+a5.w)
                     + (a6.x+a6.y+a6.z+a6.w)+(a7.x+a7.y+a7.z+a7.w);
            su[t] = s1*(1.f/16.f);
            sd[t] = s2*(1.f/16.f);
        }
        __syncthreads();

        {
            int h = t >> 8, n = t & 255;
            const float* Wb  = Wl + h*65536;
            const float* src = h ? sd : su;
            float a0 = h ? 0.f : bl[n];
#pragma unroll 8
            for (int k=0;k<256;k++) a0 += src[k]*Wb[k*256+n];
            cpart[h*256+n] = a0;
        }
        __syncthreads();
        if (t < 256) csh[t] = cpart[t] + cpart[256+t];
        __syncthreads();

        // per-electron GEMM: dual-stream pipeline (weights depth-2, acts depth-1)
        float acc[4][4];
#pragma unroll
        for (int e=0;e<4;e++)
#pragma unroll
            for (int n=0;n<4;n++) acc[e][n] = csh[n0g+n];
        {
            const float (*puA)[32] = pmT[0][l-1];
            const float (*pdA)[32] = pmT[1][l-1];
            const float* Wp = Wl + 512*256 + n0g;
            float4 w0 = *(const float4*)(Wp);
            float4 w1 = *(const float4*)(Wp + 256);
            float4 av = *(const float4*)&puA[0][e0];
            float4 wc, ac;
#pragma unroll 4
            for (int R=0; R<31; ++R){
                wc = w0; w0 = w1; w1 = *(const float4*)(Wp + (R+2)*256);
                ac = av; av = *(const float4*)&puA[R+1][e0];
                ROWT(acc, ac, wc);
            }
            // pu row 31 (peel): preload pd row 0
            wc = w0; w0 = w1; w1 = *(const float4*)(Wp + 33*256);
            ac = av; av = *(const float4*)&pdA[0][e0];
            ROWT(acc, ac, wc);
#pragma unroll 4
            for (int R=0; R<31; ++R){
                wc = w0; w0 = w1; w1 = *(const float4*)(Wp + (R+34)*256);
                ac = av; av = *(const float4*)&pdA[R+1][e0];
                ROWT(acc, ac, wc);
            }
            // pd row 31 (peel): preload sv row 0
            wc = w0; w0 = w1; w1 = *(const float4*)(Wp + 65*256);
            ac = av; av = *(const float4*)&svT[0][e0];
            ROWT(acc, ac, wc);
#pragma unroll 4
            for (int R=0; R<253; ++R){
                wc = w0; w0 = w1; w1 = *(const float4*)(Wp + (R+66)*256);
                ac = av; av = *(const float4*)&svT[R+1][e0];
                ROWT(acc, ac, wc);
            }
            // sv row 253
            wc = w0; w0 = w1; w1 = *(const float4*)(Wp + 319*256);
            ac = av; av = *(const float4*)&svT[254][e0];
            ROWT(acc, ac, wc);
            // sv row 254
            wc = w0; w0 = w1;
            ac = av; av = *(const float4*)&svT[255][e0];
            ROWT(acc, ac, wc);
            // sv row 255
            ROWT(acc, av, w0);
        }
        __syncthreads();

#pragma unroll
        for (int n=0;n<4;n++){
            float4 o = *(const float4*)&svT[n0g+n][e0];
            float4 v = { tanh_fast(acc[0][n])+o.x, tanh_fast(acc[1][n])+o.y,
                         tanh_fast(acc[2][n])+o.z, tanh_fast(acc[3][n])+o.w };
            *(float4*)&svT[n0g+n][e0] = v;
        }
        __syncthreads();
    }

    // F1: orbitals via folded weights (2 halves x 16x16; Wc in ws[0..8224))
    {
        int half = t >> 8, il = (t >> 4) & 15, k16 = t & 15;
        int row = half*16 + il;
        const float* WcT = ws + half*4112;
        float a0 = WcT[4096 + k16];
#pragma unroll 8
        for (int m=0;m<256;m++) a0 += svT[m][row]*WcT[m*16+k16];
        orb[half][il][k16] = a0 * envs[row];
    }
    __syncthreads();

    // F2: 16x16 LU with partial pivoting, one wave per matrix
    {
        int w = t >> 6;
        if (w < 2){
            int lane = t & 63;
            float* M = &orb[w][0][0];   // row stride 17
            float ld_ = 0.f;
            for (int k=0;k<16;k++){
                float v = (lane>=k && lane<16) ? fabsf(M[lane*17+k]) : -1.f;
                int idx = lane;
                for (int off=32; off; off>>=1){
                    float ov = __shfl_xor(v, off);
                    int   oi = __shfl_xor(idx, off);
                    if (ov > v || (ov == v && oi < idx)){ v=ov; idx=oi; }
                }
                int p = idx;
                if (p != k && lane >= k && lane < 16){
                    float t1 = M[k*17+lane], t2 = M[p*17+lane];
                    M[k*17+lane] = t2; M[p*17+lane] = t1;
                }
                float piv = M[k*17+k];
                ld_ += logf(fabsf(piv));
                float inv = 1.f/piv;
                float rowkj = (lane<16) ? M[k*17+lane] : 0.f;
                if (lane > k && lane < 16){
                    for (int i=k+1;i<16;i++){
                        float mik = M[i*17+k]*inv;
                        M[i*17+lane] -= mik*rowkj;
                    }
                }
            }
            if (lane == 0) red[w] = ld_;
        }
    }
    __syncthreads();
    if (t == 0) out[b] = red[0] + red[1];
}

// ---------------- fused fallback: round-13 2-walker kernel (1443 us) --------
__global__ __launch_bounds__(512) __attribute__((amdgpu_waves_per_eu(2,2))) void fermi_fused(
    const float* __restrict__ r,   const float* __restrict__ A,
    const float* __restrict__ Ws0, const float* __restrict__ bs0,
    const float* __restrict__ Wp0, const float* __restrict__ bp0,
    const float* __restrict__ Ws1, const float* __restrict__ bs1,
    const float* __restrict__ Wp1, const float* __restrict__ bp1,
    const float* __restrict__ Ws2, const float* __restrict__ bs2,
    const float* __restrict__ Wp2, const float* __restrict__ bp2,
    const float* __restrict__ Ws3, const float* __restrict__ bs3,
    const float* __restrict__ Wc,  float* __restrict__ out)
{
    __shared__ __align__(16) float sv2[2][32][256];
    __shared__ __align__(16) float pmu2[2][3][32][32];
    __shared__ __align__(16) float pmd2[2][3][32][32];
    __shared__ __align__(16) float su2[2][256];
    __shared__ __align__(16) float sd2[2][256];
    __shared__ __align__(16) float pool[1536];
    __shared__ __align__(16) float wp0s[4][32];
    __shared__ __align__(16) float wp1s[32][32];
    __shared__ __align__(16) float wp2s[32][32];
    __shared__ __align__(16) float bp0s[32], bp1s[32], bp2s[32];
    __shared__ float rs2[2][32][3];
    __shared__ __align__(16) float s02[2][32][16];
    __shared__ float ralen2[2][32][4];
    __shared__ float envs2[2][32];
    __shared__ __align__(16) float pu02[2][32][4];
    __shared__ __align__(16) float pd02[2][32][4];
    __shared__ float su02[2][16], sd02[2][16];
    __shared__ float rbar2[2][2][3];
    __shared__ float red2[2][2];

    const int t = threadIdx.x;
    const int b = blockIdx.x;
    const int n0 = (t & 63) * 4;
    const int j0 = (t >> 6) * 4;
    float* cpart = pool;
    float* cshf  = pool + 1024;

    if (t < 192) (&rs2[0][0][0])[t] = r[(size_t)b*192 + t];
    if (t < 128) (&wp0s[0][0])[t] = Wp0[t];
    {
        float* w1 = &wp1s[0][0];
        w1[t]     = Wp1[t];
        w1[t+512] = Wp1[t+512];
        float* w2 = &wp2s[0][0];
        w2[t]     = Wp2[t];
        w2[t+512] = Wp2[t+512];
    }
    if (t >= 192 && t < 224) bp0s[t-192] = bp0[t-192];
    else if (t >= 224 && t < 256) bp1s[t-224] = bp1[t-224];
    else if (t >= 256 && t < 288) bp2s[t-256] = bp2[t-256];
    __syncthreads();

    if (t < 256){
        int wk = t >> 7, q = t & 127;
        int e = q >> 2, aa = q & 3;
        float dx = rs2[wk][e][0]-A[aa*3+0];
        float dy = rs2[wk][e][1]-A[aa*3+1];
        float dz = rs2[wk][e][2]-A[aa*3+2];
        float ln = sqrtf(dx*dx+dy*dy+dz*dz);
        s02[wk][e][aa*4+0]=dx; s02[wk][e][aa*4+1]=dy;
        s02[wk][e][aa*4+2]=dz; s02[wk][e][aa*4+3]=ln;
        ralen2[wk][e][aa]=ln;
    }
    __syncthreads();

    if (t < 64){
        int wk = t >> 5, e = t & 31;
        envs2[wk][e] = expf(-ralen2[wk][e][0])+expf(-ralen2[wk][e][1])
                     + expf(-ralen2[wk][e][2])+expf(-ralen2[wk][e][3]);
    } else if (t < 128){
        int q = t-64; int wk = q >> 5, half = (q >> 4) & 1, k = q & 15;
        float s = 0.f; int jb = half*16;
        for (int j=jb; j<jb+16; j++) s += s02[wk][j][k];
        (half ? sd02 : su02)[wk][k] = s*(1.f/16.f);
    } else if (t < 140){
        int q = t-128; int wk = q/6, rr_ = q%6, half = rr_/3, c = rr_%3;
        float s=0.f;
        for (int i=half*16;i<half*16+16;i++) s += rs2[wk][i][c];
        rbar2[wk][half][c] = s*(1.f/16.f);
    }
    __syncthreads();

    if (t < 128){
        int wk = t >> 6, q = t & 63;
        int j = q & 31, half = q >> 5;
        float* dst = (half ? pd02 : pu02)[wk][j];
        dst[0] = rs2[wk][j][0]-rbar2[wk][half][0];
        dst[1] = rs2[wk][j][1]-rbar2[wk][half][1];
        dst[2] = rs2[wk][j][2]-rbar2[wk][half][2];
        float s=0.f; int base = half*16;
        for (int i=base;i<base+16;i++){
            if (i != j){
                float dx=rs2[wk][j][0]-rs2[wk][i][0];
                float dy=rs2[wk][j][1]-rs2[wk][i][1];
                float dz=rs2[wk][j][2]-rs2[wk][i][2];
                s += sqrtf(dx*dx+dy*dy+dz*dz);
            }
        }
        dst[3] = s*(1.f/16.f);
    }
    {
        int wk = t >> 8, n = t & 255;
        float a0 = bs0[n];
        for (int k=0;k<16;k++){
            a0 += su02[wk][k]*Ws0[k*256+n] + sd02[wk][k]*Ws0[(16+k)*256+n];
        }
        cshf[wk*256+n] = a0;
    }
    __syncthreads();

    {
        const int i1  = t & 15;
        const int jj4 = (t >> 4) & 15;
        const int wkp = t >> 8;
#pragma unroll 1
        for (int pass=0; pass<4; ++pass){
            const int h   = pass >> 1;
            const int jjs = jj4 + (pass & 1)*16;
            const int ii  = i1 + h*16;
            float px[32];
            {
                float dx = rs2[wkp][jjs][0]-rs2[wkp][ii][0];
                float dy = rs2[wkp][jjs][1]-rs2[wkp][ii][1];
                float dz = rs2[wkp][jjs][2]-rs2[wkp][ii][2];
                float ln = sqrtf(dx*dx+dy*dy+dz*dz);
#pragma unroll
                for (int c=0; c<8; c++){
                    float4 w0 = ((const float4*)wp0s[0])[c];
                    float4 w1 = ((const float4*)wp0s[1])[c];
                    float4 w2 = ((const float4*)wp0s[2])[c];
                    float4 w3 = ((const float4*)wp0s[3])[c];
                    float4 bb = ((const float4*)bp0s)[c];
                    px[c*4+0] = tanh_fast(bb.x + dx*w0.x + dy*w1.x + dz*w2.x + ln*w3.x);
                    px[c*4+1] = tanh_fast(bb.y + dx*w0.y + dy*w1.y + dz*w2.y + ln*w3.y);
                    px[c*4+2] = tanh_fast(bb.z + dx*w0.z + dy*w1.z + dz*w2.z + ln*w3.z);
                    px[c*4+3] = tanh_fast(bb.w + dx*w0.w + dy*w1.w + dz*w2.w + ln*w3.w);
                }
            }
            float (*pm)[32][32] = h ? pmd2[wkp] : pmu2[wkp];
#pragma unroll 1
            for (int s=0; s<3; ++s){
#pragma unroll
                for (int f=0; f<32; f++){
                    float a_ = px[f];
                    a_ += __shfl_xor(a_,1); a_ += __shfl_xor(a_,2);
                    a_ += __shfl_xor(a_,4); a_ += __shfl_xor(a_,8);
                    if (i1 == 0) pm[s][jjs][f] = a_*(1.f/16.f);
                }
                if (s == 0)      pair_update(px, wp1s, bp1s);
                else if (s == 1) pair_update(px, wp2s, bp2s);
            }
        }
    }
    __syncthreads();

    {
        float acc0[4][4], acc1[4][4];
#pragma unroll
        for (int e=0;e<4;e++)
#pragma unroll
            for (int n=0;n<4;n++){ acc0[e][n] = cshf[n0+n]; acc1[e][n] = cshf[256+n0+n]; }
        {
            float4 A0 = *(const float4*)pu02[0][j0+0];
            float4 A1 = *(const float4*)pu02[0][j0+1];
            float4 A2 = *(const float4*)pu02[0][j0+2];
            float4 A3 = *(const float4*)pu02[0][j0+3];
            float4 B0 = *(const float4*)pu02[1][j0+0];
            float4 B1 = *(const float4*)pu02[1][j0+1];
            float4 B2 = *(const float4*)pu02[1][j0+2];
            float4 B3 = *(const float4*)pu02[1][j0+3];
            G4D(Ws0, 32, A0,A1,A2,A3, B0,B1,B2,B3);
            A0 = *(const float4*)pd02[0][j0+0];
            A1 = *(const float4*)pd02[0][j0+1];
            A2 = *(const float4*)pd02[0][j0+2];
            A3 = *(const float4*)pd02[0][j0+3];
            B0 = *(const float4*)pd02[1][j0+0];
            B1 = *(const float4*)pd02[1][j0+1];
            B2 = *(const float4*)pd02[1][j0+2];
            B3 = *(const float4*)pd02[1][j0+3];
            G4D(Ws0, 36, A0,A1,A2,A3, B0,B1,B2,B3);
        }
#pragma unroll
        for (int k4=0;k4<4;k4++){
            float4 A0 = ((const float4*)s02[0][j0+0])[k4];
            float4 A1 = ((const float4*)s02[0][j0+1])[k4];
            float4 A2 = ((const float4*)s02[0][j0+2])[k4];
            float4 A3 = ((const float4*)s02[0][j0+3])[k4];
            float4 B0 = ((const float4*)s02[1][j0+0])[k4];
            float4 B1 = ((const float4*)s02[1][j0+1])[k4];
            float4 B2 = ((const float4*)s02[1][j0+2])[k4];
            float4 B3 = ((const float4*)s02[1][j0+3])[k4];
            G4D(Ws0, 40+k4*4, A0,A1,A2,A3, B0,B1,B2,B3);
        }
#pragma unroll
        for (int e=0;e<4;e++)
#pragma unroll
            for (int n=0;n<4;n++){
                sv2[0][j0+e][n0+n] = tanh_fast(acc0[e][n]);
                sv2[1][j0+e][n0+n] = tanh_fast(acc1[e][n]);
            }
    }
    __syncthreads();

#pragma unroll 1
    for (int l=1; l<=3; l++){
        const float* Wl  = (l==1)?Ws1:(l==2)?Ws2:Ws3;
        const float* bl  = (l==1)?bs1:(l==2)?bs2:bs3;

        {
            int wk = t >> 8, k = t & 255;
            float s1=0.f, s2=0.f;
            for (int j=0;j<16;j++)  s1 += sv2[wk][j][k];
            for (int j=16;j<32;j++) s2 += sv2[wk][j][k];
            su2[wk][k] = s1*(1.f/16.f);
            sd2[wk][k] = s2*(1.f/16.f);
        }
        __syncthreads();

        {
            int h = t >> 8, n = t & 255;
            const float* Wb = Wl + h*65536;
            const float* sA = h ? sd2[0] : su2[0];
            const float* sB = h ? sd2[1] : su2[1];
            float a0 = h ? 0.f : bl[n];
            float a1 = a0;
#pragma unroll 8
            for (int k=0;k<256;k++){
                float wv = Wb[k*256+n];
                a0 += sA[k]*wv; a1 += sB[k]*wv;
            }
            cpart[(0*2+h)*256+n] = a0;
            cpart[(1*2+h)*256+n] = a1;
        }
        __syncthreads();
        {
            int wk = t >> 8, n = t & 255;
            cshf[wk*256+n] = cpart[(wk*2+0)*256+n] + cpart[(wk*2+1)*256+n];
        }
        __syncthreads();

        float acc0[4][4], acc1[4][4];
#pragma unroll
        for (int e=0;e<4;e++)
#pragma unroll
            for (int n=0;n<4;n++){ acc0[e][n] = cshf[n0+n]; acc1[e][n] = cshf[256+n0+n]; }
        const float* puA = &pmu2[0][l-1][0][0];
        const float* puB = &pmu2[1][l-1][0][0];
        const float* pdA = &pmd2[0][l-1][0][0];
        const float* pdB = &pmd2[1][l-1][0][0];
#pragma unroll
        for (int k4=0;k4<8;k4++){
            float4 A0 = ((const float4*)(puA + (j0+0)*32))[k4];
            float4 A1 = ((const float4*)(puA + (j0+1)*32))[k4];
            float4 A2 = ((const float4*)(puA + (j0+2)*32))[k4];
            float4 A3 = ((const float4*)(puA + (j0+3)*32))[k4];
            float4 B0 = ((const float4*)(puB + (j0+0)*32))[k4];
            float4 B1 = ((const float4*)(puB + (j0+1)*32))[k4];
            float4 B2 = ((const float4*)(puB + (j0+2)*32))[k4];
            float4 B3 = ((const float4*)(puB + (j0+3)*32))[k4];
            G4D(Wl, 512+k4*4, A0,A1,A2,A3, B0,B1,B2,B3);
        }
#pragma unroll
        for (int k4=0;k4<8;k4++){
            float4 A0 = ((const float4*)(pdA + (j0+0)*32))[k4];
            float4 A1 = ((const float4*)(pdA + (j0+1)*32))[k4];
            float4 A2 = ((const float4*)(pdA + (j0+2)*32))[k4];
            float4 A3 = ((const float4*)(pdA + (j0+3)*32))[k4];
            float4 B0 = ((const float4*)(pdB + (j0+0)*32))[k4];
            float4 B1 = ((const float4*)(pdB + (j0+1)*32))[k4];
            float4 B2 = ((const float4*)(pdB + (j0+2)*32))[k4];
            float4 B3 = ((const float4*)(pdB + (j0+3)*32))[k4];
            G4D(Wl, 544+k4*4, A0,A1,A2,A3, B0,B1,B2,B3);
        }
        {
            const float* WbP = Wl + 576*256 + n0;
            float4 wn0 = *(const float4*)(WbP);
            float4 wn1 = *(const float4*)(WbP + 256);
            float4 wn2 = *(const float4*)(WbP + 512);
            float4 wn3 = *(const float4*)(WbP + 768);
#pragma unroll 1
            for (int k4=0;k4<64;k4++){
                float4 w0=wn0, w1=wn1, w2=wn2, w3=wn3;
                {
                    int kn = (k4 < 63) ? (k4+1) : 63;
                    const float* Wn = WbP + kn*1024;
                    wn0 = *(const float4*)(Wn);
                    wn1 = *(const float4*)(Wn + 256);
                    wn2 = *(const float4*)(Wn + 512);
                    wn3 = *(const float4*)(Wn + 768);
                }
                float4 A0 = ((const float4*)sv2[0][j0+0])[k4];
                float4 A1 = ((const float4*)sv2[0][j0+1])[k4];
                float4 A2 = ((const float4*)sv2[0][j0+2])[k4];
                float4 A3 = ((const float4*)sv2[0][j0+3])[k4];
                float4 B0 = ((const float4*)sv2[1][j0+0])[k4];
                float4 B1 = ((const float4*)sv2[1][j0+1])[k4];
                float4 B2 = ((const float4*)sv2[1][j0+2])[k4];
                float4 B3 = ((const float4*)sv2[1][j0+3])[k4];
                G4P(w0,w1,w2,w3, A0,A1,A2,A3, B0,B1,B2,B3);
            }
        }
        __syncthreads();

#pragma unroll
        for (int e=0;e<4;e++)
#pragma unroll
            for (int n=0;n<4;n++){
                float o0 = sv2[0][j0+e][n0+n];
                float o1 = sv2[1][j0+e][n0+n];
                sv2[0][j0+e][n0+n] = tanh_fast(acc0[e][n]) + o0;
                sv2[1][j0+e][n0+n] = tanh_fast(acc1[e][n]) + o1;
            }
        __syncthreads();
    }

#pragma unroll 1
    for (int rep=0; rep<2; ++rep){
        int idx = t + rep*512;
        int wk = idx >> 9, rem = idx & 511;
        int half = rem >> 8, il = (rem >> 4) & 15, k16 = rem & 15;
        int row = half*16 + il;
        const float* WcT = Wc + half*4112;
        float a0 = WcT[4096 + k16];
#pragma unroll 8
        for (int m=0;m<256;m++) a0 += sv2[wk][row][m]*WcT[m*16+k16];
        pool[(wk*2+half)*272 + il*17 + k16] = a0 * envs2[wk][row];
    }
    __syncthreads();

    {
        int w = t >> 6;
        if (w < 4){
            int lane = t & 63;
            float* M = pool + w*272;
            float ld_ = 0.f;
            for (int k=0;k<16;k++){
                float v = (lane>=k && lane<16) ? fabsf(M[lane*17+k]) : -1.f;
                int idx = lane;
                for (int off=32; off; off>>=1){
                    float ov = __shfl_xor(v, off);
                    int   oi = __shfl_xor(idx, off);
                    if (ov > v || (ov == v && oi < idx)){ v=ov; idx=oi; }
                }
                int p = idx;
                if (p != k && lane >= k && lane < 16){
                    float t1 = M[k*17+lane], t2 = M[p*17+lane];
                    M[k*17+lane] = t2; M[p*17+lane] = t1;
                }
                float piv = M[k*17+k];
                ld_ += logf(fabsf(piv));
                float inv = 1.f/piv;
                float rowkj = (lane<16) ? M[k*17+lane] : 0.f;
                if (lane > k && lane < 16){
                    for (int i=k+1;i<16;i++){
                        float mik = M[i*17+k]*inv;
                        M[i*17+lane] -= mik*rowkj;
                    }
                }
            }
            if (lane == 0) red2[w>>1][w&1] = ld_;
        }
    }
    __syncthreads();
    if (t < 2) out[2*b + t] = red2[t][0] + red2[t][1];
}

extern "C" void kernel_launch(void* const* d_in, const int* in_sizes, int n_in,
                              void* d_out, int out_size, void* d_ws, size_t ws_size,
                              hipStream_t stream) {
    const float* r   = (const float*)d_in[0];
    const float* a   = (const float*)d_in[1];
    const float* Ws0 = (const float*)d_in[2];  const float* bs0 = (const float*)d_in[3];
    const float* Wp0 = (const float*)d_in[4];  const float* bp0 = (const float*)d_in[5];
    const float* Ws1 = (const float*)d_in[6];  const float* bs1 = (const float*)d_in[7];
    const float* Wp1 = (const float*)d_in[8];  const float* bp1 = (const float*)d_in[9];
    const float* Ws2 = (const float*)d_in[10]; const float* bs2 = (const float*)d_in[11];
    const float* Wp2 = (const float*)d_in[12]; const float* bp2 = (const float*)d_in[13];
    const float* Ws3 = (const float*)d_in[14]; const float* bs3 = (const float*)d_in[15];
    const float* Wu  = (const float*)d_in[16]; const float* bu  = (const float*)d_in[17];
    const float* Wd  = (const float*)d_in[18]; const float* bd  = (const float*)d_in[19];
    const float* Wwu = (const float*)d_in[20]; const float* bwu = (const float*)d_in[21];
    const float* Wwd = (const float*)d_in[22]; const float* bwd = (const float*)d_in[23];
    float* ws = (float*)d_ws;
    float* out = (float*)d_out;

    const int B = out_size;
    const size_t need = ((size_t)8224 + (size_t)B*7232) * 4;

    fermi_prep<<<1, 512, 0, stream>>>(Wu, bu, Wd, bd, Wwu, bwu, Wwd, bwd, ws);
    if (ws_size >= need){
        fermi_pair<<<B, 512, 0, stream>>>(r, a, Ws0, bs0, Wp0, bp0,
                                          Wp1, bp1, Wp2, bp2, ws);
        fermi_smain<<<B, 512, 0, stream>>>(Ws0, Ws1, bs1, Ws2, bs2, Ws3, bs3, ws, out);
    } else {
        fermi_fused<<<B/2, 512, 0, stream>>>(r, a, Ws0, bs0, Wp0, bp0,
                                             Ws1, bs1, Wp1, bp1,
                                             Ws2, bs2, Wp2, bp2,
                                             Ws3, bs3, ws, out);
    }
}